// Round 11
// baseline (651.385 us; speedup 1.0000x reference)
//
#include <hip/hip_runtime.h>
#include <math.h>

#define NN 20000
#define NE 160000
#define TT 3
#define DD 128
#define NTOT 80000   // (TT+1)*NN
#define N3 60000     // TT*NN
#define NBLK1 79     // ceil(NTOT/1024) for the scan

__device__ __forceinline__ float waveReduceSum(float v) {
#pragma unroll
  for (int off = 32; off >= 1; off >>= 1)
    v += __shfl_xor(v, off, 64);
  return v;
}

__device__ __forceinline__ void atomAddF(float* p, float v) {
  unsafeAtomicAdd(p, v);
}

// ---------------------------------------------------------------------------
// copy features into all_features rows [0, NN)
__global__ __launch_bounds__(256) void k_copy_feat(const float* __restrict__ src,
                                                   float* __restrict__ dst, int n4) {
  int i = blockIdx.x * 256 + threadIdx.x;
  if (i < n4) ((float4*)dst)[i] = ((const float4*)src)[i];
}

// ---------------------------------------------------------------------------
// [M,128] @ [128,128] GEMM. 128x128 tile per block (grid = ceil(M/128)), 512
// threads, 8 rows x 4 cols per thread (tc=tid&31 covers 128 cols; R=8 keeps
// per-thread W-LDS reads at 4 ds_read_b128 per kq -> per-CU LDS demand 768cy
// < VALU 1024cy per SIMD: VALU-bound). W staged in LDS ONCE (full K, 67.6 KB,
// one barrier, zero re-fetch); X read directly from global (32-lane broadcast
// float4, each X row read exactly once per block -> no cross-block traffic
// duplication). 2 blocks/CU = 4 waves/SIMD.
// DO_ARGMAX: per-row argmax (first-max) via 32-lane shuffles, writes cls.
template <int RELU_IN, int TRANS_W, int DO_ARGMAX>
__global__ __launch_bounds__(512, 4) void gemm128(const float* __restrict__ X,
                                                  const float* __restrict__ W,
                                                  const float* __restrict__ bias,
                                                  float* __restrict__ out, int M,
                                                  float scale, int wStride, int bStride,
                                                  long oStride, int* __restrict__ cls) {
  __shared__ float Ws[128 * 132];
  const int tid = threadIdx.x;
  const int rbase = blockIdx.x * 128;
  W += (long)blockIdx.y * wStride;
  if (bias) bias += (long)blockIdx.y * bStride;
  out += (long)blockIdx.y * oStride;

  // stage all of W into LDS (row kl, padded stride 132)
#pragma unroll
  for (int it = 0; it < 8; ++it) {
    if (!TRANS_W) {
      int idx = (tid + it * 512) * 4;
      int kl = idx >> 7, c = idx & 127;
      *(float4*)&Ws[kl * 132 + c] = *(const float4*)&W[kl * 128 + c];
    } else {
      int e = tid + it * 512;
      int c = e & 127, klb = (e >> 7) * 4;
      float4 w = *(const float4*)&W[(long)c * 128 + klb];
      Ws[(klb + 0) * 132 + c] = w.x;
      Ws[(klb + 1) * 132 + c] = w.y;
      Ws[(klb + 2) * 132 + c] = w.z;
      Ws[(klb + 3) * 132 + c] = w.w;
    }
  }

  const int tc = tid & 31, tr = tid >> 5;  // tc in [0,32), tr in [0,16)
  const int c0 = tc * 4, r0 = tr * 8;
  const int grb = rbase + r0;
  const float* __restrict__ xb = X + (long)((grb < M) ? grb : 0) * 128;

  float acc[8][4];
#pragma unroll
  for (int i = 0; i < 8; ++i)
#pragma unroll
    for (int j = 0; j < 4; ++j) acc[i][j] = 0.f;

  float4 xc[8], xn[8];
#pragma unroll
  for (int i = 0; i < 8; ++i) {
    float4 v = *(const float4*)&xb[i * 128];
    if (RELU_IN) {
      v.x = fmaxf(v.x, 0.f);
      v.y = fmaxf(v.y, 0.f);
      v.z = fmaxf(v.z, 0.f);
      v.w = fmaxf(v.w, 0.f);
    }
    xc[i] = v;
  }

  __syncthreads();  // W staged

  for (int kq = 0; kq < 32; ++kq) {
    if (kq < 31) {
#pragma unroll
      for (int i = 0; i < 8; ++i) {
        float4 v = *(const float4*)&xb[i * 128 + (kq + 1) * 4];
        if (RELU_IN) {
          v.x = fmaxf(v.x, 0.f);
          v.y = fmaxf(v.y, 0.f);
          v.z = fmaxf(v.z, 0.f);
          v.w = fmaxf(v.w, 0.f);
        }
        xn[i] = v;
      }
    }
#pragma unroll
    for (int k = 0; k < 4; ++k) {
      const float4 w4 = *(const float4*)&Ws[(kq * 4 + k) * 132 + c0];
#pragma unroll
      for (int i = 0; i < 8; ++i) {
        float a = (k == 0) ? xc[i].x : (k == 1) ? xc[i].y : (k == 2) ? xc[i].z
                                                                     : xc[i].w;
        acc[i][0] = fmaf(a, w4.x, acc[i][0]);
        acc[i][1] = fmaf(a, w4.y, acc[i][1]);
        acc[i][2] = fmaf(a, w4.z, acc[i][2]);
        acc[i][3] = fmaf(a, w4.w, acc[i][3]);
      }
    }
    if (kq < 31) {
#pragma unroll
      for (int i = 0; i < 8; ++i) xc[i] = xn[i];
    }
  }

  float bb[4];
#pragma unroll
  for (int j = 0; j < 4; ++j) bb[j] = 0.f;
  if (bias) {
#pragma unroll
    for (int j = 0; j < 4; ++j) bb[j] = bias[c0 + j];
  }

  if (DO_ARGMAX) {
#pragma unroll
    for (int i = 0; i < 8; ++i) {
      float bv = acc[i][0] * scale + bb[0];
      int bc = c0;
#pragma unroll
      for (int j = 1; j < 4; ++j) {
        float v = acc[i][j] * scale + bb[j];
        if (v > bv) {
          bv = v;
          bc = c0 + j;
        }
      }
#pragma unroll
      for (int off = 1; off <= 16; off <<= 1) {
        float ov = __shfl_xor(bv, off, 64);
        int oc = __shfl_xor(bc, off, 64);
        if (ov > bv || (ov == bv && oc < bc)) {
          bv = ov;
          bc = oc;
        }
      }
      int gr = rbase + r0 + i;
      if (tc == 0 && gr < M) cls[gr] = bc;
    }
  } else {
#pragma unroll
    for (int i = 0; i < 8; ++i) {
      int gr = rbase + r0 + i;
      if (gr < M) {
        float4 v;
        v.x = acc[i][0] * scale + bb[0];
        v.y = acc[i][1] * scale + bb[1];
        v.z = acc[i][2] * scale + bb[2];
        v.w = acc[i][3] * scale + bb[3];
        *(float4*)&out[(long)gr * 128 + c0] = v;
      }
    }
  }
}

// ---------------------------------------------------------------------------
// row norms: first NN waves -> ||features[j]||, next NN -> ||transformed0[j]||
__global__ __launch_bounds__(256) void k_norms(const float* __restrict__ feat,
                                               const float* __restrict__ A,
                                               float* __restrict__ nf,
                                               float* __restrict__ nt0) {
  int w = blockIdx.x * 4 + (threadIdx.x >> 6);
  int lane = threadIdx.x & 63;
  if (w >= 2 * NN) return;
  const float* p = (w < NN) ? (feat + (long)w * 128) : (A + (long)(NN + (w - NN)) * 128);
  float v0 = p[lane], v1 = p[lane + 64];
  float s = waveReduceSum(v0 * v0 + v1 * v1);
  if (lane == 0) {
    float r = sqrtf(s);
    if (w < NN) nf[w] = r;
    else nt0[w - NN] = r;
  }
}

// cosine-sim replica selection; one wave per edge (degrees come from CSR).
__global__ __launch_bounds__(256) void k_sim(const int* __restrict__ ei,
                                             const float* __restrict__ feat,
                                             const float* __restrict__ A,
                                             const float* __restrict__ nf,
                                             const float* __restrict__ nt0,
                                             int* __restrict__ bn) {
  int e = blockIdx.x * 4 + (threadIdx.x >> 6);
  int lane = threadIdx.x & 63;
  if (e >= NE) return;
  int s = ei[e];
  const float* fp = feat + (long)s * 128;
  float a0 = fp[lane], a1 = fp[lane + 64];
  float na = nf[s];
  float bv = 0.f;
  int bk = 0;
#pragma unroll
  for (int k = 0; k < 3; ++k) {
    int j = 3 * e + k;
    if (j >= NE) j -= NE;
    if (j >= NE) j -= NE;
    int d = ei[NE + j];
    const float* bp = A + (long)(NN + d) * 128;
    float dot = waveReduceSum(a0 * bp[lane] + a1 * bp[lane + 64]);
    float sim = dot / fmaxf(na * nt0[d], 1e-8f);
    if (k == 0 || sim > bv) {
      bv = sim;
      bk = k;
    }
  }
  if (lane == 0) bn[e] = ei[NE + e] + bk * NN;
}

// ---------------------------------------------------------------------------
// CSR build: count -> scan(3 phases) -> fill. Shared by both GCN layers.
__global__ __launch_bounds__(256) void k_zero_count(int* __restrict__ count) {
  int v = blockIdx.x * 256 + threadIdx.x;
  if (v < NTOT) count[v] = 0;
}

__global__ __launch_bounds__(256) void k_count(const int* __restrict__ ei,
                                               const int* __restrict__ bn,
                                               int* __restrict__ count) {
  int e = blockIdx.x * 256 + threadIdx.x;
  if (e < NE) {
    atomicAdd(&count[ei[NE + e]], 1);
    atomicAdd(&count[bn[e]], 1);
  }
}

// dinv[v] = rsqrt(unstructured_count + structured (2 for v<N3, else 1))
__global__ __launch_bounds__(256) void k_dinv(const int* __restrict__ count,
                                              float* __restrict__ dinv) {
  int v = blockIdx.x * 256 + threadIdx.x;
  if (v < NTOT) {
    float deg = (float)count[v] + ((v < N3) ? 2.f : 1.f);
    dinv[v] = 1.f / sqrtf(deg);
  }
}

// scan phase 1: per-1024-block local exclusive scan + block sums
__global__ __launch_bounds__(256) void k_scan1(const int* __restrict__ count,
                                               int* __restrict__ start,
                                               int* __restrict__ bsum) {
  __shared__ int sh[256];
  const int b = blockIdx.x, t = threadIdx.x;
  const int base = b * 1024 + t * 4;
  int c[4];
  int s = 0;
#pragma unroll
  for (int k = 0; k < 4; ++k) {
    int idx = base + k;
    c[k] = (idx < NTOT) ? count[idx] : 0;
    s += c[k];
  }
  sh[t] = s;
  __syncthreads();
  for (int off = 1; off < 256; off <<= 1) {
    int v = (t >= off) ? sh[t - off] : 0;
    __syncthreads();
    sh[t] += v;
    __syncthreads();
  }
  if (t == 255) bsum[b] = sh[255];
  int run = sh[t] - s;  // exclusive prefix of this thread
#pragma unroll
  for (int k = 0; k < 4; ++k) {
    int idx = base + k;
    if (idx < NTOT) start[idx] = run;
    run += c[k];
  }
}

// scan phase 2: exclusive scan of NBLK1 block sums (single block)
__global__ __launch_bounds__(256) void k_scan2(int* __restrict__ bsum) {
  __shared__ int sh[256];
  const int t = threadIdx.x;
  int v = (t < NBLK1) ? bsum[t] : 0;
  sh[t] = v;
  __syncthreads();
  for (int off = 1; off < 256; off <<= 1) {
    int u = (t >= off) ? sh[t - off] : 0;
    __syncthreads();
    sh[t] += u;
    __syncthreads();
  }
  if (t < NBLK1) bsum[t] = sh[t] - v;
}

// scan phase 3: add block offsets; init cursor = start
__global__ __launch_bounds__(256) void k_scan3(int* __restrict__ start,
                                               const int* __restrict__ bsum,
                                               int* __restrict__ cursor) {
  int i = blockIdx.x * 256 + threadIdx.x;
  if (i < NTOT) {
    int v = start[i] + bsum[i >> 10];
    start[i] = v;
    cursor[i] = v;
  }
}

// fill CSR entries: (src, weight) packed in int2
__global__ __launch_bounds__(256) void k_fill(const int* __restrict__ ei,
                                              const int* __restrict__ bn,
                                              const float* __restrict__ dinv,
                                              int* __restrict__ cursor,
                                              int2* __restrict__ ent) {
  int g = blockIdx.x * 256 + threadIdx.x;
  if (g >= 2 * NE) return;
  int e = (g < NE) ? g : g - NE;
  int s = ei[e];
  int d = (g < NE) ? ei[NE + e] : bn[e];
  float w = dinv[s] * dinv[d];
  int pos = atomicAdd(&cursor[d], 1);
  ent[pos] = make_int2(s, __float_as_int(w));
}

// ---------------------------------------------------------------------------
// Fused GCN aggregate: out[v] = bias + selfloop + extra + sum_{CSR} w*xw[src].
// One wave per row, 2 floats/lane, prefetched entry loop, no atomics.
__global__ __launch_bounds__(256) void k_agg(const int2* __restrict__ ent,
                                             const int* __restrict__ start,
                                             const int* __restrict__ end,
                                             const float* __restrict__ xw,
                                             const float* __restrict__ dinv,
                                             const float* __restrict__ bias,
                                             float* __restrict__ out) {
  int v = blockIdx.x * 4 + (threadIdx.x >> 6);
  int lane = threadIdx.x & 63;
  float dv = dinv[v];
  const float* xr = xw + (long)v * 128;
  float b0 = xr[lane], b1 = xr[lane + 64];
  float acc0 = bias[lane] + dv * dv * b0;
  float acc1 = bias[lane + 64] + dv * dv * b1;
  if (v < NN) {
    acc0 += dv * dv * b0;  // extra edge (j, j)
    acc1 += dv * dv * b1;
  } else if (v < N3) {
    int j = (v < 2 * NN) ? v - NN : v - 2 * NN;
    const float* xj = xw + (long)j * 128;
    float w = dinv[j] * dv;
    acc0 = fmaf(w, xj[lane], acc0);  // extra edge (j, i*NN + j)
    acc1 = fmaf(w, xj[lane + 64], acc1);
  }
  const int i1 = end[v];
  int i = start[v];
  if (i < i1) {
    int2 en = ent[i];
    for (; i < i1; ++i) {
      int2 nx = en;
      if (i + 1 < i1) nx = ent[i + 1];
      float w = __int_as_float(en.y);
      const float* xs = xw + (long)en.x * 128;
      acc0 = fmaf(w, xs[lane], acc0);
      acc1 = fmaf(w, xs[lane + 64], acc1);
      en = nx;
    }
  }
  out[(long)v * 128 + lane] = acc0;
  out[(long)v * 128 + lane + 64] = acc1;
}

__global__ __launch_bounds__(256) void k_zero_small(float* __restrict__ hyper,
                                                    int* __restrict__ hist) {
  int i = blockIdx.x * 256 + threadIdx.x;
  if (i < 128 * 128) hyper[i] = 0.f;
  if (i < 640) hist[i] = 0;
}

// vote histogram: hist[c][m] = #nodes whose count for class c is exactly m.
// LDS-accumulated per block (20 blocks x 1000 nodes), one flush per block.
#define HISTBLK 20
__global__ __launch_bounds__(256) void k_hist(const int* __restrict__ cls,
                                              int* __restrict__ hist) {
  __shared__ int sh[640];
  const int t = threadIdx.x;
  for (int i = t; i < 640; i += 256) sh[i] = 0;
  __syncthreads();
  const int per = NN / HISTBLK;  // 1000
  const int j0 = blockIdx.x * per;
  for (int j = j0 + t; j < j0 + per; j += 256) {
    int cc[4] = {cls[j], cls[NN + j], cls[2 * NN + j], cls[3 * NN + j]};
#pragma unroll
    for (int i = 0; i < 4; ++i) {
      bool first = true;
      int m = 0;
#pragma unroll
      for (int k = 0; k < 4; ++k) {
        if (cc[k] == cc[i]) {
          if (k < i) first = false;
          m++;
        }
      }
      if (first) atomicAdd(&sh[cc[i] * 5 + m], 1);
    }
  }
  __syncthreads();
  for (int i = t; i < 640; i += 256) {
    int v = sh[i];
    if (v) atomicAdd(&hist[i], v);
  }
}

// per-class softmax table over count values 0..4
__global__ void k_table(const int* __restrict__ hist, float* __restrict__ table) {
  int c = threadIdx.x;
  if (c >= 128) return;
  int cnt[5];
  int tot = 0;
  for (int v = 1; v <= 4; ++v) {
    cnt[v] = hist[c * 5 + v];
    tot += cnt[v];
  }
  cnt[0] = NN - tot;
  int m = 0;
  for (int v = 0; v <= 4; ++v)
    if (cnt[v] > 0) m = v;
  float ex[5];
  float denom = 0.f;
  for (int v = 0; v <= 4; ++v) {
    ex[v] = expf((float)(v - m));
    denom += (float)cnt[v] * ex[v];
  }
  for (int v = 0; v <= 4; ++v) table[c * 5 + v] = ex[v] / denom;
}

__global__ __launch_bounds__(256) void k_hwrite(const int* __restrict__ cls,
                                                const float* __restrict__ table,
                                                float* __restrict__ H) {
  int j = blockIdx.x * 2 + (threadIdx.x >> 7);
  int c = threadIdx.x & 127;
  if (j >= NN) return;
  int c0 = cls[j], c1 = cls[NN + j], c2 = cls[2 * NN + j], c3 = cls[3 * NN + j];
  int cnt = (c == c0) + (c == c1) + (c == c2) + (c == c3);
  H[(long)j * 128 + c] = table[c * 5 + cnt];
}

// ---------------------------------------------------------------------------
// hyper[c][d] = sum over nodes voting for class c of af2[j][d].
// LDS-accumulated: 250 blocks x 80 nodes.
#define HBLK 250
#define HPER 80
__global__ __launch_bounds__(256) void k_hyper(const int* __restrict__ cls,
                                               const float* __restrict__ af2,
                                               float* __restrict__ hyper) {
  __shared__ float acc[128 * 128];
  const int t = threadIdx.x;
  for (int i = t; i < 128 * 128; i += 256) acc[i] = 0.f;
  __syncthreads();
  const int j0 = blockIdx.x * HPER;
  const int j1 = j0 + HPER;  // NN == HBLK*HPER exactly
  const int d = t & 127;
  const int half = t >> 7;  // 0: slots {0,2}; 1: slots {1,3}
  float v = af2[(long)j0 * 128 + d];
  int c0 = cls[j0], c1 = cls[NN + j0], c2 = cls[2 * NN + j0], c3 = cls[3 * NN + j0];
  for (int j = j0; j < j1; ++j) {
    float vn = 0.f;
    int n0 = 0, n1 = 0, n2 = 0, n3 = 0;
    if (j + 1 < j1) {
      vn = af2[(long)(j + 1) * 128 + d];
      n0 = cls[j + 1];
      n1 = cls[NN + j + 1];
      n2 = cls[2 * NN + j + 1];
      n3 = cls[3 * NN + j + 1];
    }
    if (half == 0) {
      atomicAdd(&acc[c0 * 128 + d], v);  // slot 0 always first occurrence
      if (c2 != c0 && c2 != c1) atomicAdd(&acc[c2 * 128 + d], v);
    } else {
      if (c1 != c0) atomicAdd(&acc[c1 * 128 + d], v);
      if (c3 != c0 && c3 != c1 && c3 != c2) atomicAdd(&acc[c3 * 128 + d], v);
    }
    v = vn;
    c0 = n0;
    c1 = n1;
    c2 = n2;
    c3 = n3;
  }
  __syncthreads();
  for (int i = t; i < 128 * 128; i += 256) {
    float x = acc[i];
    if (x != 0.f) atomAddF(&hyper[i], x);
  }
}

// ---------------------------------------------------------------------------
extern "C" void kernel_launch(void* const* d_in, const int* in_sizes, int n_in,
                              void* d_out, int out_size, void* d_ws, size_t ws_size,
                              hipStream_t stream) {
  (void)in_sizes;
  (void)n_in;
  (void)out_size;
  (void)ws_size;
  const int* ei = (const int*)d_in[0];
  const float* feat = (const float*)d_in[1];
  const float* lin_W = (const float*)d_in[2];
  const float* lin_b = (const float*)d_in[3];
  const float* g1W = (const float*)d_in[4];
  const float* g1b = (const float*)d_in[5];
  const float* g2W = (const float*)d_in[6];
  const float* g2b = (const float*)d_in[7];
  const float* l1W = (const float*)d_in[8];
  const float* l1b = (const float*)d_in[9];

  float* out = (float*)d_out;
  float* H = out;
  float* hyper = out + (size_t)NN * 128;
  float* dots = hyper + 128 * 128;

  float* ws = (float*)d_ws;
  float* A = ws;                          // all_features [(T+1)*NN, 128]
  float* Cb = A + (size_t)NTOT * 128;     // h1 / af2 buffer
  float* Bb = dots;                       // xw buffer aliased onto dots
                                          // (dots written only by final GEMM)
  float* dinv = Cb + (size_t)NTOT * 128;  // [NTOT]
  float* nf = dinv + NTOT;                // feature norms [NN]
  float* nt0 = nf + NN;                   // transformed0 norms [NN]
  int* bn = (int*)(nt0 + NN);             // best_nodes [NE]
  int* cls = bn + NE;                     // classes [NTOT]
  int* hist = cls + NTOT;                 // [640]
  float* table = (float*)(hist + 640);    // [640]
  int* count = (int*)(table + 640);       // [NTOT]
  int* startA = count + NTOT;             // [NTOT]
  int* cursor = startA + NTOT;            // [NTOT]  (== end after fill)
  int* bsum = cursor + NTOT;              // [128]
  int2* ent = (int2*)(bsum + 128);        // [2*NE] CSR entries (src, weight)

  const float kScale = 0.08838834764831843f;  // 128^-0.5

  // 1. all_features rows [0,NN) = features
  k_copy_feat<<<(NN * 128 / 4 + 255) / 256, 256, 0, stream>>>(feat, A, NN * 128 / 4);
  // 2. transformed: per-replica linears -> rows [NN, 4*NN)
  gemm128<0, 0, 0><<<dim3(157, 3), 512, 0, stream>>>(
      feat, lin_W, lin_b, A + (size_t)NN * 128, NN, 1.f, 128 * 128, 128,
      (long)NN * 128, nullptr);
  // 3. row norms
  k_norms<<<10000, 256, 0, stream>>>(feat, A, nf, nt0);
  // 4. cosine-sim replica pick
  k_zero_count<<<(NTOT + 255) / 256, 256, 0, stream>>>(count);
  k_sim<<<NE / 4, 256, 0, stream>>>(ei, feat, A, nf, nt0, bn);
  // 5. CSR build: count, dinv, scan, fill
  k_count<<<(NE + 255) / 256, 256, 0, stream>>>(ei, bn, count);
  k_dinv<<<(NTOT + 255) / 256, 256, 0, stream>>>(count, dinv);
  k_scan1<<<NBLK1, 256, 0, stream>>>(count, startA, bsum);
  k_scan2<<<1, 256, 0, stream>>>(bsum);
  k_scan3<<<(NTOT + 255) / 256, 256, 0, stream>>>(startA, bsum, cursor);
  k_fill<<<(2 * NE + 255) / 256, 256, 0, stream>>>(ei, bn, dinv, cursor, ent);
  // 6. GCN1: xw1 = relu(all_features) @ W1; fused aggregate -> h1 in Cb
  gemm128<1, 0, 0><<<dim3(NTOT / 128, 1), 512, 0, stream>>>(A, g1W, nullptr, Bb, NTOT,
                                                            1.f, 0, 0, 0, nullptr);
  k_agg<<<NTOT / 4, 256, 0, stream>>>(ent, startA, cursor, Bb, dinv, g1b, Cb);
  // 7. GCN2: xw2 = relu(h1) @ W2; fused aggregate -> af2 in Cb
  gemm128<1, 0, 0><<<dim3(NTOT / 128, 1), 512, 0, stream>>>(Cb, g2W, nullptr, Bb, NTOT,
                                                            1.f, 0, 0, 0, nullptr);
  k_agg<<<NTOT / 4, 256, 0, stream>>>(ent, startA, cursor, Bb, dinv, g2b, Cb);
  // 8. logits GEMM with fused per-row argmax -> classes (no logits store)
  gemm128<1, 0, 1><<<dim3(NTOT / 128, 1), 512, 0, stream>>>(Cb, l1W, l1b, nullptr,
                                                            NTOT, 1.f, 0, 0, 0, cls);
  // 9. zero hyper + hist
  k_zero_small<<<64, 256, 0, stream>>>(hyper, hist);
  // 10. vote histogram (LDS) -> per-class softmax table
  k_hist<<<HISTBLK, 256, 0, stream>>>(cls, hist);
  k_table<<<1, 128, 0, stream>>>(hist, table);
  // 11. H output (softmax over nodes, via count table)
  k_hwrite<<<NN / 2, 256, 0, stream>>>(cls, table, H);
  // 12. hyperedge features (LDS-accumulated)
  k_hyper<<<HBLK, 256, 0, stream>>>(cls, Cb, hyper);
  // 13. dots = all_features @ hyper^T * scale
  gemm128<0, 1, 0><<<dim3(NTOT / 128, 1), 512, 0, stream>>>(A, hyper, nullptr, dots,
                                                            NTOT, kScale, 0, 0, 0,
                                                            nullptr);
}

// Round 12
// 470.275 us; speedup vs baseline: 1.3851x; 1.3851x over previous
//
#include <hip/hip_runtime.h>
#include <math.h>

#define NN 20000
#define NE 160000
#define TT 3
#define DD 128
#define NTOT 80000   // (TT+1)*NN
#define N3 60000     // TT*NN
#define NBLK1 79     // ceil(NTOT/1024) for the scan

__device__ __forceinline__ float waveReduceSum(float v) {
#pragma unroll
  for (int off = 32; off >= 1; off >>= 1)
    v += __shfl_xor(v, off, 64);
  return v;
}

__device__ __forceinline__ void atomAddF(float* p, float v) {
  unsafeAtomicAdd(p, v);
}

// ---------------------------------------------------------------------------
// copy features into all_features rows [0, NN)
__global__ __launch_bounds__(256) void k_copy_feat(const float* __restrict__ src,
                                                   float* __restrict__ dst, int n4) {
  int i = blockIdx.x * 256 + threadIdx.x;
  if (i < n4) ((float4*)dst)[i] = ((const float4*)src)[i];
}

// ---------------------------------------------------------------------------
// [M,128] @ [128,128] GEMM — round-9 version (best measured: 63 us/dispatch).
// 128x128 tile per block, 512 threads, 4x8 per thread. W staged in LDS ONCE
// (full K, 67.6 KB, one barrier); X read directly from global (16-lane
// broadcast float4, read exactly once per block). 2 blocks/CU = 4 waves/SIMD.
// DO_ARGMAX: per-row argmax (first-max) via 16-lane shuffles.
template <int RELU_IN, int TRANS_W, int DO_ARGMAX>
__global__ __launch_bounds__(512, 4) void gemm128(const float* __restrict__ X,
                                                  const float* __restrict__ W,
                                                  const float* __restrict__ bias,
                                                  float* __restrict__ out, int M,
                                                  float scale, int wStride, int bStride,
                                                  long oStride, int* __restrict__ cls) {
  __shared__ float Ws[128 * 132];
  const int tid = threadIdx.x;
  const int rbase = blockIdx.x * 128;
  W += (long)blockIdx.y * wStride;
  if (bias) bias += (long)blockIdx.y * bStride;
  out += (long)blockIdx.y * oStride;

  // stage all of W into LDS (row kl, padded stride 132)
#pragma unroll
  for (int it = 0; it < 8; ++it) {
    int idx = (tid + it * 512) * 4;
    int kl = idx >> 7, c = idx & 127;
    float4 w;
    if (!TRANS_W) {
      w = *(const float4*)&W[kl * 128 + c];
    } else {
      w.x = W[(c + 0) * 128 + kl];
      w.y = W[(c + 1) * 128 + kl];
      w.z = W[(c + 2) * 128 + kl];
      w.w = W[(c + 3) * 128 + kl];
    }
    *(float4*)&Ws[kl * 132 + c] = w;
  }

  const int tc = tid & 15, tr = tid >> 4;  // tr in [0,32)
  const int c0 = tc * 8, r0 = tr * 4;

  const float4* xrow[4];
#pragma unroll
  for (int i = 0; i < 4; ++i) {
    int gr = rbase + r0 + i;
    int gc = (gr < M) ? gr : 0;  // clamp tail rows (stores are guarded)
    xrow[i] = (const float4*)(X + (long)gc * 128);
  }

  float acc[4][8];
#pragma unroll
  for (int i = 0; i < 4; ++i)
#pragma unroll
    for (int j = 0; j < 8; ++j) acc[i][j] = 0.f;

  float4 xc[4], xn[4];
#pragma unroll
  for (int i = 0; i < 4; ++i) {
    float4 v = xrow[i][0];
    if (RELU_IN) {
      v.x = fmaxf(v.x, 0.f);
      v.y = fmaxf(v.y, 0.f);
      v.z = fmaxf(v.z, 0.f);
      v.w = fmaxf(v.w, 0.f);
    }
    xc[i] = v;
  }

  __syncthreads();  // W staged

  for (int kq = 0; kq < 32; ++kq) {
    if (kq < 31) {
#pragma unroll
      for (int i = 0; i < 4; ++i) {
        float4 v = xrow[i][kq + 1];
        if (RELU_IN) {
          v.x = fmaxf(v.x, 0.f);
          v.y = fmaxf(v.y, 0.f);
          v.z = fmaxf(v.z, 0.f);
          v.w = fmaxf(v.w, 0.f);
        }
        xn[i] = v;
      }
    }
    const int klb = kq * 4;
#pragma unroll
    for (int k = 0; k < 4; ++k) {
      const int kl = klb + k;
      const float4 wa = *(const float4*)&Ws[kl * 132 + c0];
      const float4 wb = *(const float4*)&Ws[kl * 132 + c0 + 4];
      float av[4];
#pragma unroll
      for (int i = 0; i < 4; ++i)
        av[i] = (k == 0) ? xc[i].x : (k == 1) ? xc[i].y : (k == 2) ? xc[i].z : xc[i].w;
      const float bv[8] = {wa.x, wa.y, wa.z, wa.w, wb.x, wb.y, wb.z, wb.w};
#pragma unroll
      for (int i = 0; i < 4; ++i)
#pragma unroll
        for (int j = 0; j < 8; ++j) acc[i][j] = fmaf(av[i], bv[j], acc[i][j]);
    }
    if (kq < 31) {
#pragma unroll
      for (int i = 0; i < 4; ++i) xc[i] = xn[i];
    }
  }

  float bb[8];
#pragma unroll
  for (int j = 0; j < 8; ++j) bb[j] = 0.f;
  if (bias) {
#pragma unroll
    for (int j = 0; j < 8; ++j) bb[j] = bias[c0 + j];
  }

  if (DO_ARGMAX) {
#pragma unroll
    for (int i = 0; i < 4; ++i) {
      float bv = acc[i][0] * scale + bb[0];
      int bc = c0;
#pragma unroll
      for (int j = 1; j < 8; ++j) {
        float v = acc[i][j] * scale + bb[j];
        if (v > bv) {
          bv = v;
          bc = c0 + j;
        }
      }
#pragma unroll
      for (int off = 1; off <= 8; off <<= 1) {
        float ov = __shfl_xor(bv, off, 64);
        int oc = __shfl_xor(bc, off, 64);
        if (ov > bv || (ov == bv && oc < bc)) {
          bv = ov;
          bc = oc;
        }
      }
      int gr = rbase + r0 + i;
      if (tc == 0 && gr < M) cls[gr] = bc;
    }
  } else {
#pragma unroll
    for (int i = 0; i < 4; ++i) {
      int gr = rbase + r0 + i;
      if (gr < M) {
        float4 v0, v1;
        v0.x = acc[i][0] * scale + bb[0];
        v0.y = acc[i][1] * scale + bb[1];
        v0.z = acc[i][2] * scale + bb[2];
        v0.w = acc[i][3] * scale + bb[3];
        v1.x = acc[i][4] * scale + bb[4];
        v1.y = acc[i][5] * scale + bb[5];
        v1.z = acc[i][6] * scale + bb[6];
        v1.w = acc[i][7] * scale + bb[7];
        *(float4*)&out[(long)gr * 128 + c0] = v0;
        *(float4*)&out[(long)gr * 128 + c0 + 4] = v1;
      }
    }
  }
}

// ---------------------------------------------------------------------------
// row norms (float2 per lane): first NN waves -> ||features[j]||,
// next NN -> ||transformed0[j]||
__global__ __launch_bounds__(256) void k_norms(const float* __restrict__ feat,
                                               const float* __restrict__ A,
                                               float* __restrict__ nf,
                                               float* __restrict__ nt0) {
  int w = blockIdx.x * 4 + (threadIdx.x >> 6);
  int lane = threadIdx.x & 63;
  if (w >= 2 * NN) return;
  const float* p = (w < NN) ? (feat + (long)w * 128) : (A + (long)(NN + (w - NN)) * 128);
  float2 v = *(const float2*)(p + lane * 2);
  float s = waveReduceSum(v.x * v.x + v.y * v.y);
  if (lane == 0) {
    float r = sqrtf(s);
    if (w < NN) nf[w] = r;
    else nt0[w - NN] = r;
  }
}

// cosine-sim replica selection; one wave per edge, float2 per lane, all three
// candidate rows loaded before any reduce (3 independent gathers in flight).
__global__ __launch_bounds__(256) void k_sim(const int* __restrict__ ei,
                                             const float* __restrict__ feat,
                                             const float* __restrict__ A,
                                             const float* __restrict__ nf,
                                             const float* __restrict__ nt0,
                                             int* __restrict__ bn) {
  int e = blockIdx.x * 4 + (threadIdx.x >> 6);
  int lane = threadIdx.x & 63;
  if (e >= NE) return;
  int s = ei[e];
  float2 a = *(const float2*)(feat + (long)s * 128 + lane * 2);
  float na = nf[s];
  int dd[3];
#pragma unroll
  for (int k = 0; k < 3; ++k) {
    int j = 3 * e + k;
    if (j >= NE) j -= NE;
    if (j >= NE) j -= NE;
    dd[k] = ei[NE + j];
  }
  float2 b0 = *(const float2*)(A + (long)(NN + dd[0]) * 128 + lane * 2);
  float2 b1 = *(const float2*)(A + (long)(NN + dd[1]) * 128 + lane * 2);
  float2 b2 = *(const float2*)(A + (long)(NN + dd[2]) * 128 + lane * 2);
  float s0 = waveReduceSum(a.x * b0.x + a.y * b0.y);
  float s1 = waveReduceSum(a.x * b1.x + a.y * b1.y);
  float s2 = waveReduceSum(a.x * b2.x + a.y * b2.y);
  float sim0 = s0 / fmaxf(na * nt0[dd[0]], 1e-8f);
  float sim1 = s1 / fmaxf(na * nt0[dd[1]], 1e-8f);
  float sim2 = s2 / fmaxf(na * nt0[dd[2]], 1e-8f);
  int bk = 0;
  float bv = sim0;
  if (sim1 > bv) {
    bv = sim1;
    bk = 1;
  }
  if (sim2 > bv) {
    bv = sim2;
    bk = 2;
  }
  if (lane == 0) bn[e] = ei[NE + e] + bk * NN;
}

// ---------------------------------------------------------------------------
// CSR build: count -> scan(3 phases) -> fill. Shared by both GCN layers.
__global__ __launch_bounds__(256) void k_zero_count(int* __restrict__ count) {
  int v = blockIdx.x * 256 + threadIdx.x;
  if (v < NTOT) count[v] = 0;
}

__global__ __launch_bounds__(256) void k_count(const int* __restrict__ ei,
                                               const int* __restrict__ bn,
                                               int* __restrict__ count) {
  int e = blockIdx.x * 256 + threadIdx.x;
  if (e < NE) {
    atomicAdd(&count[ei[NE + e]], 1);
    atomicAdd(&count[bn[e]], 1);
  }
}

// dinv[v] = rsqrt(unstructured_count + structured (2 for v<N3, else 1))
__global__ __launch_bounds__(256) void k_dinv(const int* __restrict__ count,
                                              float* __restrict__ dinv) {
  int v = blockIdx.x * 256 + threadIdx.x;
  if (v < NTOT) {
    float deg = (float)count[v] + ((v < N3) ? 2.f : 1.f);
    dinv[v] = 1.f / sqrtf(deg);
  }
}

// scan phase 1: per-1024-block local exclusive scan + block sums
__global__ __launch_bounds__(256) void k_scan1(const int* __restrict__ count,
                                               int* __restrict__ start,
                                               int* __restrict__ bsum) {
  __shared__ int sh[256];
  const int b = blockIdx.x, t = threadIdx.x;
  const int base = b * 1024 + t * 4;
  int c[4];
  int s = 0;
#pragma unroll
  for (int k = 0; k < 4; ++k) {
    int idx = base + k;
    c[k] = (idx < NTOT) ? count[idx] : 0;
    s += c[k];
  }
  sh[t] = s;
  __syncthreads();
  for (int off = 1; off < 256; off <<= 1) {
    int v = (t >= off) ? sh[t - off] : 0;
    __syncthreads();
    sh[t] += v;
    __syncthreads();
  }
  if (t == 255) bsum[b] = sh[255];
  int run = sh[t] - s;  // exclusive prefix of this thread
#pragma unroll
  for (int k = 0; k < 4; ++k) {
    int idx = base + k;
    if (idx < NTOT) start[idx] = run;
    run += c[k];
  }
}

// scan phase 2: exclusive scan of NBLK1 block sums (single block)
__global__ __launch_bounds__(256) void k_scan2(int* __restrict__ bsum) {
  __shared__ int sh[256];
  const int t = threadIdx.x;
  int v = (t < NBLK1) ? bsum[t] : 0;
  sh[t] = v;
  __syncthreads();
  for (int off = 1; off < 256; off <<= 1) {
    int u = (t >= off) ? sh[t - off] : 0;
    __syncthreads();
    sh[t] += u;
    __syncthreads();
  }
  if (t < NBLK1) bsum[t] = sh[t] - v;
}

// scan phase 3: add block offsets; init cursor = start
__global__ __launch_bounds__(256) void k_scan3(int* __restrict__ start,
                                               const int* __restrict__ bsum,
                                               int* __restrict__ cursor) {
  int i = blockIdx.x * 256 + threadIdx.x;
  if (i < NTOT) {
    int v = start[i] + bsum[i >> 10];
    start[i] = v;
    cursor[i] = v;
  }
}

// fill CSR entries: (src, weight) packed in int2
__global__ __launch_bounds__(256) void k_fill(const int* __restrict__ ei,
                                              const int* __restrict__ bn,
                                              const float* __restrict__ dinv,
                                              int* __restrict__ cursor,
                                              int2* __restrict__ ent) {
  int g = blockIdx.x * 256 + threadIdx.x;
  if (g >= 2 * NE) return;
  int e = (g < NE) ? g : g - NE;
  int s = ei[e];
  int d = (g < NE) ? ei[NE + e] : bn[e];
  float w = dinv[s] * dinv[d];
  int pos = atomicAdd(&cursor[d], 1);
  ent[pos] = make_int2(s, __float_as_int(w));
}

// ---------------------------------------------------------------------------
// Fused GCN aggregate: out[v] = bias + selfloop + extra + sum_{CSR} w*xw[src].
// One wave per row, float2 per lane, entry loop unrolled x2 (both gathers
// issued before use -> 2 outstanding row loads), no atomics.
__global__ __launch_bounds__(256) void k_agg(const int2* __restrict__ ent,
                                             const int* __restrict__ start,
                                             const int* __restrict__ end,
                                             const float* __restrict__ xw,
                                             const float* __restrict__ dinv,
                                             const float* __restrict__ bias,
                                             float* __restrict__ out) {
  int v = blockIdx.x * 4 + (threadIdx.x >> 6);
  int lane = threadIdx.x & 63;
  float dv = dinv[v];
  float2 xv = *(const float2*)(xw + (long)v * 128 + lane * 2);
  float2 b2 = *(const float2*)(bias + lane * 2);
  float acc0 = b2.x + dv * dv * xv.x;
  float acc1 = b2.y + dv * dv * xv.y;
  if (v < NN) {
    acc0 += dv * dv * xv.x;  // extra edge (j, j)
    acc1 += dv * dv * xv.y;
  } else if (v < N3) {
    int j = (v < 2 * NN) ? v - NN : v - 2 * NN;
    float2 xj = *(const float2*)(xw + (long)j * 128 + lane * 2);
    float w = dinv[j] * dv;
    acc0 = fmaf(w, xj.x, acc0);  // extra edge (j, i*NN + j)
    acc1 = fmaf(w, xj.y, acc1);
  }
  const int i1 = end[v];
  int i = start[v];
  for (; i + 1 < i1; i += 2) {
    int2 e0 = ent[i], e1 = ent[i + 1];
    float w0 = __int_as_float(e0.y), w1 = __int_as_float(e1.y);
    float2 x0 = *(const float2*)(xw + (long)e0.x * 128 + lane * 2);
    float2 x1 = *(const float2*)(xw + (long)e1.x * 128 + lane * 2);
    acc0 = fmaf(w0, x0.x, acc0);
    acc1 = fmaf(w0, x0.y, acc1);
    acc0 = fmaf(w1, x1.x, acc0);
    acc1 = fmaf(w1, x1.y, acc1);
  }
  if (i < i1) {
    int2 e0 = ent[i];
    float w0 = __int_as_float(e0.y);
    float2 x0 = *(const float2*)(xw + (long)e0.x * 128 + lane * 2);
    acc0 = fmaf(w0, x0.x, acc0);
    acc1 = fmaf(w0, x0.y, acc1);
  }
  *(float2*)(out + (long)v * 128 + lane * 2) = make_float2(acc0, acc1);
}

__global__ __launch_bounds__(256) void k_zero_small(float* __restrict__ hyper,
                                                    int* __restrict__ hist) {
  int i = blockIdx.x * 256 + threadIdx.x;
  if (i < 128 * 128) hyper[i] = 0.f;
  if (i < 640) hist[i] = 0;
}

// vote histogram: hist[c][m] = #nodes whose count for class c is exactly m.
// LDS-accumulated per block (20 blocks x 1000 nodes), one flush per block.
#define HISTBLK 20
__global__ __launch_bounds__(256) void k_hist(const int* __restrict__ cls,
                                              int* __restrict__ hist) {
  __shared__ int sh[640];
  const int t = threadIdx.x;
  for (int i = t; i < 640; i += 256) sh[i] = 0;
  __syncthreads();
  const int per = NN / HISTBLK;  // 1000
  const int j0 = blockIdx.x * per;
  for (int j = j0 + t; j < j0 + per; j += 256) {
    int cc[4] = {cls[j], cls[NN + j], cls[2 * NN + j], cls[3 * NN + j]};
#pragma unroll
    for (int i = 0; i < 4; ++i) {
      bool first = true;
      int m = 0;
#pragma unroll
      for (int k = 0; k < 4; ++k) {
        if (cc[k] == cc[i]) {
          if (k < i) first = false;
          m++;
        }
      }
      if (first) atomicAdd(&sh[cc[i] * 5 + m], 1);
    }
  }
  __syncthreads();
  for (int i = t; i < 640; i += 256) {
    int v = sh[i];
    if (v) atomicAdd(&hist[i], v);
  }
}

// per-class softmax table over count values 0..4
__global__ void k_table(const int* __restrict__ hist, float* __restrict__ table) {
  int c = threadIdx.x;
  if (c >= 128) return;
  int cnt[5];
  int tot = 0;
  for (int v = 1; v <= 4; ++v) {
    cnt[v] = hist[c * 5 + v];
    tot += cnt[v];
  }
  cnt[0] = NN - tot;
  int m = 0;
  for (int v = 0; v <= 4; ++v)
    if (cnt[v] > 0) m = v;
  float ex[5];
  float denom = 0.f;
  for (int v = 0; v <= 4; ++v) {
    ex[v] = expf((float)(v - m));
    denom += (float)cnt[v] * ex[v];
  }
  for (int v = 0; v <= 4; ++v) table[c * 5 + v] = ex[v] / denom;
}

__global__ __launch_bounds__(256) void k_hwrite(const int* __restrict__ cls,
                                                const float* __restrict__ table,
                                                float* __restrict__ H) {
  int j = blockIdx.x * 2 + (threadIdx.x >> 7);
  int c = threadIdx.x & 127;
  if (j >= NN) return;
  int c0 = cls[j], c1 = cls[NN + j], c2 = cls[2 * NN + j], c3 = cls[3 * NN + j];
  int cnt = (c == c0) + (c == c1) + (c == c2) + (c == c3);
  H[(long)j * 128 + c] = table[c * 5 + cnt];
}

// ---------------------------------------------------------------------------
// hyper[c][d] = sum over nodes voting for class c of af2[j][d].
// LDS-accumulated: 250 blocks x 80 nodes.
#define HBLK 250
#define HPER 80
__global__ __launch_bounds__(256) void k_hyper(const int* __restrict__ cls,
                                               const float* __restrict__ af2,
                                               float* __restrict__ hyper) {
  __shared__ float acc[128 * 128];
  const int t = threadIdx.x;
  for (int i = t; i < 128 * 128; i += 256) acc[i] = 0.f;
  __syncthreads();
  const int j0 = blockIdx.x * HPER;
  const int j1 = j0 + HPER;  // NN == HBLK*HPER exactly
  const int d = t & 127;
  const int half = t >> 7;  // 0: slots {0,2}; 1: slots {1,3}
  float v = af2[(long)j0 * 128 + d];
  int c0 = cls[j0], c1 = cls[NN + j0], c2 = cls[2 * NN + j0], c3 = cls[3 * NN + j0];
  for (int j = j0; j < j1; ++j) {
    float vn = 0.f;
    int n0 = 0, n1 = 0, n2 = 0, n3 = 0;
    if (j + 1 < j1) {
      vn = af2[(long)(j + 1) * 128 + d];
      n0 = cls[j + 1];
      n1 = cls[NN + j + 1];
      n2 = cls[2 * NN + j + 1];
      n3 = cls[3 * NN + j + 1];
    }
    if (half == 0) {
      atomicAdd(&acc[c0 * 128 + d], v);  // slot 0 always first occurrence
      if (c2 != c0 && c2 != c1) atomicAdd(&acc[c2 * 128 + d], v);
    } else {
      if (c1 != c0) atomicAdd(&acc[c1 * 128 + d], v);
      if (c3 != c0 && c3 != c1 && c3 != c2) atomicAdd(&acc[c3 * 128 + d], v);
    }
    v = vn;
    c0 = n0;
    c1 = n1;
    c2 = n2;
    c3 = n3;
  }
  __syncthreads();
  for (int i = t; i < 128 * 128; i += 256) {
    float x = acc[i];
    if (x != 0.f) atomAddF(&hyper[i], x);
  }
}

// ---------------------------------------------------------------------------
extern "C" void kernel_launch(void* const* d_in, const int* in_sizes, int n_in,
                              void* d_out, int out_size, void* d_ws, size_t ws_size,
                              hipStream_t stream) {
  (void)in_sizes;
  (void)n_in;
  (void)out_size;
  (void)ws_size;
  const int* ei = (const int*)d_in[0];
  const float* feat = (const float*)d_in[1];
  const float* lin_W = (const float*)d_in[2];
  const float* lin_b = (const float*)d_in[3];
  const float* g1W = (const float*)d_in[4];
  const float* g1b = (const float*)d_in[5];
  const float* g2W = (const float*)d_in[6];
  const float* g2b = (const float*)d_in[7];
  const float* l1W = (const float*)d_in[8];
  const float* l1b = (const float*)d_in[9];

  float* out = (float*)d_out;
  float* H = out;
  float* hyper = out + (size_t)NN * 128;
  float* dots = hyper + 128 * 128;

  float* ws = (float*)d_ws;
  float* A = ws;                          // all_features [(T+1)*NN, 128]
  float* Cb = A + (size_t)NTOT * 128;     // h1 / af2 buffer
  float* Bb = dots;                       // xw buffer aliased onto dots
                                          // (dots written only by final GEMM)
  float* dinv = Cb + (size_t)NTOT * 128;  // [NTOT]
  float* nf = dinv + NTOT;                // feature norms [NN]
  float* nt0 = nf + NN;                   // transformed0 norms [NN]
  int* bn = (int*)(nt0 + NN);             // best_nodes [NE]
  int* cls = bn + NE;                     // classes [NTOT]
  int* hist = cls + NTOT;                 // [640]
  float* table = (float*)(hist + 640);    // [640]
  int* count = (int*)(table + 640);       // [NTOT]
  int* startA = count + NTOT;             // [NTOT]
  int* cursor = startA + NTOT;            // [NTOT]  (== end after fill)
  int* bsum = cursor + NTOT;              // [128]
  int2* ent = (int2*)(bsum + 128);        // [2*NE] CSR entries (src, weight)

  const float kScale = 0.08838834764831843f;  // 128^-0.5

  // 1. all_features rows [0,NN) = features
  k_copy_feat<<<(NN * 128 / 4 + 255) / 256, 256, 0, stream>>>(feat, A, NN * 128 / 4);
  // 2. transformed: per-replica linears -> rows [NN, 4*NN)
  gemm128<0, 0, 0><<<dim3(157, 3), 512, 0, stream>>>(
      feat, lin_W, lin_b, A + (size_t)NN * 128, NN, 1.f, 128 * 128, 128,
      (long)NN * 128, nullptr);
  // 3. row norms
  k_norms<<<10000, 256, 0, stream>>>(feat, A, nf, nt0);
  // 4. cosine-sim replica pick
  k_zero_count<<<(NTOT + 255) / 256, 256, 0, stream>>>(count);
  k_sim<<<NE / 4, 256, 0, stream>>>(ei, feat, A, nf, nt0, bn);
  // 5. CSR build: count, dinv, scan, fill
  k_count<<<(NE + 255) / 256, 256, 0, stream>>>(ei, bn, count);
  k_dinv<<<(NTOT + 255) / 256, 256, 0, stream>>>(count, dinv);
  k_scan1<<<NBLK1, 256, 0, stream>>>(count, startA, bsum);
  k_scan2<<<1, 256, 0, stream>>>(bsum);
  k_scan3<<<(NTOT + 255) / 256, 256, 0, stream>>>(startA, bsum, cursor);
  k_fill<<<(2 * NE + 255) / 256, 256, 0, stream>>>(ei, bn, dinv, cursor, ent);
  // 6. GCN1: xw1 = relu(all_features) @ W1; fused aggregate -> h1 in Cb
  gemm128<1, 0, 0><<<dim3(NTOT / 128, 1), 512, 0, stream>>>(A, g1W, nullptr, Bb, NTOT,
                                                            1.f, 0, 0, 0, nullptr);
  k_agg<<<NTOT / 4, 256, 0, stream>>>(ent, startA, cursor, Bb, dinv, g1b, Cb);
  // 7. GCN2: xw2 = relu(h1) @ W2; fused aggregate -> af2 in Cb
  gemm128<1, 0, 0><<<dim3(NTOT / 128, 1), 512, 0, stream>>>(Cb, g2W, nullptr, Bb, NTOT,
                                                            1.f, 0, 0, 0, nullptr);
  k_agg<<<NTOT / 4, 256, 0, stream>>>(ent, startA, cursor, Bb, dinv, g2b, Cb);
  // 8. logits GEMM with fused per-row argmax -> classes (no logits store)
  gemm128<1, 0, 1><<<dim3(NTOT / 128, 1), 512, 0, stream>>>(Cb, l1W, l1b, nullptr,
                                                            NTOT, 1.f, 0, 0, 0, cls);
  // 9. zero hyper + hist
  k_zero_small<<<64, 256, 0, stream>>>(hyper, hist);
  // 10. vote histogram (LDS) -> per-class softmax table
  k_hist<<<HISTBLK, 256, 0, stream>>>(cls, hist);
  k_table<<<1, 128, 0, stream>>>(hist, table);
  // 11. H output (softmax over nodes, via count table)
  k_hwrite<<<NN / 2, 256, 0, stream>>>(cls, table, H);
  // 12. hyperedge features (LDS-accumulated)
  k_hyper<<<HBLK, 256, 0, stream>>>(cls, Cb, hyper);
  // 13. dots = all_features @ hyper^T * scale
  gemm128<0, 1, 0><<<dim3(NTOT / 128, 1), 512, 0, stream>>>(A, hyper, nullptr, dots,
                                                            NTOT, kScale, 0, 0, 0,
                                                            nullptr);
}

// Round 13
// 467.963 us; speedup vs baseline: 1.3920x; 1.0049x over previous
//
#include <hip/hip_runtime.h>
#include <math.h>

#define NN 20000
#define NE 160000
#define TT 3
#define DD 128
#define NTOT 80000   // (TT+1)*NN
#define N3 60000     // TT*NN
#define NBLK1 79     // ceil(NTOT/1024) for the scan

__device__ __forceinline__ float waveReduceSum(float v) {
#pragma unroll
  for (int off = 32; off >= 1; off >>= 1)
    v += __shfl_xor(v, off, 64);
  return v;
}

__device__ __forceinline__ void atomAddF(float* p, float v) {
  unsafeAtomicAdd(p, v);
}

// ---------------------------------------------------------------------------
// copy features into all_features rows [0, NN)
__global__ __launch_bounds__(256) void k_copy_feat(const float* __restrict__ src,
                                                   float* __restrict__ dst, int n4) {
  int i = blockIdx.x * 256 + threadIdx.x;
  if (i < n4) ((float4*)dst)[i] = ((const float4*)src)[i];
}

// ---------------------------------------------------------------------------
// [M,128] @ [128,128] GEMM. 160x128 tile per block: 80000/160 = 500 blocks
// <= 512 concurrent (2 blocks/CU at 67.6 KB LDS) -> SINGLE residency round,
// no dispatch tail (625-block version wasted a 113/512 straggler round).
// 512 threads, 5 rows x 8 cols per thread. W staged in LDS once (full K, one
// barrier); X read directly from global (16-lane broadcast float4, read
// exactly once per block). DO_ARGMAX: per-row argmax via 16-lane shuffles.
template <int RELU_IN, int TRANS_W, int DO_ARGMAX>
__global__ __launch_bounds__(512, 4) void gemm128(const float* __restrict__ X,
                                                  const float* __restrict__ W,
                                                  const float* __restrict__ bias,
                                                  float* __restrict__ out, int M,
                                                  float scale, int wStride, int bStride,
                                                  long oStride, int* __restrict__ cls) {
  __shared__ float Ws[128 * 132];
  const int tid = threadIdx.x;
  const int rbase = blockIdx.x * 160;
  W += (long)blockIdx.y * wStride;
  if (bias) bias += (long)blockIdx.y * bStride;
  out += (long)blockIdx.y * oStride;

  // stage all of W into LDS (row kl, padded stride 132)
#pragma unroll
  for (int it = 0; it < 8; ++it) {
    int idx = (tid + it * 512) * 4;
    int kl = idx >> 7, c = idx & 127;
    float4 w;
    if (!TRANS_W) {
      w = *(const float4*)&W[kl * 128 + c];
    } else {
      w.x = W[(c + 0) * 128 + kl];
      w.y = W[(c + 1) * 128 + kl];
      w.z = W[(c + 2) * 128 + kl];
      w.w = W[(c + 3) * 128 + kl];
    }
    *(float4*)&Ws[kl * 132 + c] = w;
  }

  const int tc = tid & 15, tr = tid >> 4;  // tr in [0,32)
  const int c0 = tc * 8, r0 = tr * 5;

  const float4* xrow[5];
#pragma unroll
  for (int i = 0; i < 5; ++i) {
    int gr = rbase + r0 + i;
    int gc = (gr < M) ? gr : 0;  // clamp tail rows (stores are guarded)
    xrow[i] = (const float4*)(X + (long)gc * 128);
  }

  float acc[5][8];
#pragma unroll
  for (int i = 0; i < 5; ++i)
#pragma unroll
    for (int j = 0; j < 8; ++j) acc[i][j] = 0.f;

  float4 xc[5], xn[5];
#pragma unroll
  for (int i = 0; i < 5; ++i) {
    float4 v = xrow[i][0];
    if (RELU_IN) {
      v.x = fmaxf(v.x, 0.f);
      v.y = fmaxf(v.y, 0.f);
      v.z = fmaxf(v.z, 0.f);
      v.w = fmaxf(v.w, 0.f);
    }
    xc[i] = v;
  }

  __syncthreads();  // W staged

  for (int kq = 0; kq < 32; ++kq) {
    if (kq < 31) {
#pragma unroll
      for (int i = 0; i < 5; ++i) {
        float4 v = xrow[i][kq + 1];
        if (RELU_IN) {
          v.x = fmaxf(v.x, 0.f);
          v.y = fmaxf(v.y, 0.f);
          v.z = fmaxf(v.z, 0.f);
          v.w = fmaxf(v.w, 0.f);
        }
        xn[i] = v;
      }
    }
    const int klb = kq * 4;
#pragma unroll
    for (int k = 0; k < 4; ++k) {
      const int kl = klb + k;
      const float4 wa = *(const float4*)&Ws[kl * 132 + c0];
      const float4 wb = *(const float4*)&Ws[kl * 132 + c0 + 4];
      float av[5];
#pragma unroll
      for (int i = 0; i < 5; ++i)
        av[i] = (k == 0) ? xc[i].x : (k == 1) ? xc[i].y : (k == 2) ? xc[i].z : xc[i].w;
      const float bv[8] = {wa.x, wa.y, wa.z, wa.w, wb.x, wb.y, wb.z, wb.w};
#pragma unroll
      for (int i = 0; i < 5; ++i)
#pragma unroll
        for (int j = 0; j < 8; ++j) acc[i][j] = fmaf(av[i], bv[j], acc[i][j]);
    }
    if (kq < 31) {
#pragma unroll
      for (int i = 0; i < 5; ++i) xc[i] = xn[i];
    }
  }

  float bb[8];
#pragma unroll
  for (int j = 0; j < 8; ++j) bb[j] = 0.f;
  if (bias) {
#pragma unroll
    for (int j = 0; j < 8; ++j) bb[j] = bias[c0 + j];
  }

  if (DO_ARGMAX) {
#pragma unroll
    for (int i = 0; i < 5; ++i) {
      float bv = acc[i][0] * scale + bb[0];
      int bc = c0;
#pragma unroll
      for (int j = 1; j < 8; ++j) {
        float v = acc[i][j] * scale + bb[j];
        if (v > bv) {
          bv = v;
          bc = c0 + j;
        }
      }
#pragma unroll
      for (int off = 1; off <= 8; off <<= 1) {
        float ov = __shfl_xor(bv, off, 64);
        int oc = __shfl_xor(bc, off, 64);
        if (ov > bv || (ov == bv && oc < bc)) {
          bv = ov;
          bc = oc;
        }
      }
      int gr = rbase + r0 + i;
      if (tc == 0 && gr < M) cls[gr] = bc;
    }
  } else {
#pragma unroll
    for (int i = 0; i < 5; ++i) {
      int gr = rbase + r0 + i;
      if (gr < M) {
        float4 v0, v1;
        v0.x = acc[i][0] * scale + bb[0];
        v0.y = acc[i][1] * scale + bb[1];
        v0.z = acc[i][2] * scale + bb[2];
        v0.w = acc[i][3] * scale + bb[3];
        v1.x = acc[i][4] * scale + bb[4];
        v1.y = acc[i][5] * scale + bb[5];
        v1.z = acc[i][6] * scale + bb[6];
        v1.w = acc[i][7] * scale + bb[7];
        *(float4*)&out[(long)gr * 128 + c0] = v0;
        *(float4*)&out[(long)gr * 128 + c0 + 4] = v1;
      }
    }
  }
}

// ---------------------------------------------------------------------------
// row norms (float2 per lane): first NN waves -> ||features[j]||,
// next NN -> ||transformed0[j]||
__global__ __launch_bounds__(256) void k_norms(const float* __restrict__ feat,
                                               const float* __restrict__ A,
                                               float* __restrict__ nf,
                                               float* __restrict__ nt0) {
  int w = blockIdx.x * 4 + (threadIdx.x >> 6);
  int lane = threadIdx.x & 63;
  if (w >= 2 * NN) return;
  const float* p = (w < NN) ? (feat + (long)w * 128) : (A + (long)(NN + (w - NN)) * 128);
  float2 v = *(const float2*)(p + lane * 2);
  float s = waveReduceSum(v.x * v.x + v.y * v.y);
  if (lane == 0) {
    float r = sqrtf(s);
    if (w < NN) nf[w] = r;
    else nt0[w - NN] = r;
  }
}

// cosine-sim replica selection; one wave per edge, float2 per lane, all three
// candidate rows loaded before any reduce (3 independent gathers in flight).
__global__ __launch_bounds__(256) void k_sim(const int* __restrict__ ei,
                                             const float* __restrict__ feat,
                                             const float* __restrict__ A,
                                             const float* __restrict__ nf,
                                             const float* __restrict__ nt0,
                                             int* __restrict__ bn) {
  int e = blockIdx.x * 4 + (threadIdx.x >> 6);
  int lane = threadIdx.x & 63;
  if (e >= NE) return;
  int s = ei[e];
  float2 a = *(const float2*)(feat + (long)s * 128 + lane * 2);
  float na = nf[s];
  int dd[3];
#pragma unroll
  for (int k = 0; k < 3; ++k) {
    int j = 3 * e + k;
    if (j >= NE) j -= NE;
    if (j >= NE) j -= NE;
    dd[k] = ei[NE + j];
  }
  float2 b0 = *(const float2*)(A + (long)(NN + dd[0]) * 128 + lane * 2);
  float2 b1 = *(const float2*)(A + (long)(NN + dd[1]) * 128 + lane * 2);
  float2 b2 = *(const float2*)(A + (long)(NN + dd[2]) * 128 + lane * 2);
  float s0 = waveReduceSum(a.x * b0.x + a.y * b0.y);
  float s1 = waveReduceSum(a.x * b1.x + a.y * b1.y);
  float s2 = waveReduceSum(a.x * b2.x + a.y * b2.y);
  float sim0 = s0 / fmaxf(na * nt0[dd[0]], 1e-8f);
  float sim1 = s1 / fmaxf(na * nt0[dd[1]], 1e-8f);
  float sim2 = s2 / fmaxf(na * nt0[dd[2]], 1e-8f);
  int bk = 0;
  float bv = sim0;
  if (sim1 > bv) {
    bv = sim1;
    bk = 1;
  }
  if (sim2 > bv) {
    bv = sim2;
    bk = 2;
  }
  if (lane == 0) bn[e] = ei[NE + e] + bk * NN;
}

// ---------------------------------------------------------------------------
// CSR build: count -> scan(3 phases) -> fill. Shared by both GCN layers.
__global__ __launch_bounds__(256) void k_zero_count(int* __restrict__ count) {
  int v = blockIdx.x * 256 + threadIdx.x;
  if (v < NTOT) count[v] = 0;
}

__global__ __launch_bounds__(256) void k_count(const int* __restrict__ ei,
                                               const int* __restrict__ bn,
                                               int* __restrict__ count) {
  int e = blockIdx.x * 256 + threadIdx.x;
  if (e < NE) {
    atomicAdd(&count[ei[NE + e]], 1);
    atomicAdd(&count[bn[e]], 1);
  }
}

// dinv[v] = rsqrt(unstructured_count + structured (2 for v<N3, else 1))
__global__ __launch_bounds__(256) void k_dinv(const int* __restrict__ count,
                                              float* __restrict__ dinv) {
  int v = blockIdx.x * 256 + threadIdx.x;
  if (v < NTOT) {
    float deg = (float)count[v] + ((v < N3) ? 2.f : 1.f);
    dinv[v] = 1.f / sqrtf(deg);
  }
}

// scan phase 1: per-1024-block local exclusive scan + block sums
__global__ __launch_bounds__(256) void k_scan1(const int* __restrict__ count,
                                               int* __restrict__ start,
                                               int* __restrict__ bsum) {
  __shared__ int sh[256];
  const int b = blockIdx.x, t = threadIdx.x;
  const int base = b * 1024 + t * 4;
  int c[4];
  int s = 0;
#pragma unroll
  for (int k = 0; k < 4; ++k) {
    int idx = base + k;
    c[k] = (idx < NTOT) ? count[idx] : 0;
    s += c[k];
  }
  sh[t] = s;
  __syncthreads();
  for (int off = 1; off < 256; off <<= 1) {
    int v = (t >= off) ? sh[t - off] : 0;
    __syncthreads();
    sh[t] += v;
    __syncthreads();
  }
  if (t == 255) bsum[b] = sh[255];
  int run = sh[t] - s;  // exclusive prefix of this thread
#pragma unroll
  for (int k = 0; k < 4; ++k) {
    int idx = base + k;
    if (idx < NTOT) start[idx] = run;
    run += c[k];
  }
}

// scan phase 2: exclusive scan of NBLK1 block sums (single block)
__global__ __launch_bounds__(256) void k_scan2(int* __restrict__ bsum) {
  __shared__ int sh[256];
  const int t = threadIdx.x;
  int v = (t < NBLK1) ? bsum[t] : 0;
  sh[t] = v;
  __syncthreads();
  for (int off = 1; off < 256; off <<= 1) {
    int u = (t >= off) ? sh[t - off] : 0;
    __syncthreads();
    sh[t] += u;
    __syncthreads();
  }
  if (t < NBLK1) bsum[t] = sh[t] - v;
}

// scan phase 3: add block offsets; init cursor = start
__global__ __launch_bounds__(256) void k_scan3(int* __restrict__ start,
                                               const int* __restrict__ bsum,
                                               int* __restrict__ cursor) {
  int i = blockIdx.x * 256 + threadIdx.x;
  if (i < NTOT) {
    int v = start[i] + bsum[i >> 10];
    start[i] = v;
    cursor[i] = v;
  }
}

// fill CSR entries: (src, weight) packed in int2
__global__ __launch_bounds__(256) void k_fill(const int* __restrict__ ei,
                                              const int* __restrict__ bn,
                                              const float* __restrict__ dinv,
                                              int* __restrict__ cursor,
                                              int2* __restrict__ ent) {
  int g = blockIdx.x * 256 + threadIdx.x;
  if (g >= 2 * NE) return;
  int e = (g < NE) ? g : g - NE;
  int s = ei[e];
  int d = (g < NE) ? ei[NE + e] : bn[e];
  float w = dinv[s] * dinv[d];
  int pos = atomicAdd(&cursor[d], 1);
  ent[pos] = make_int2(s, __float_as_int(w));
}

// ---------------------------------------------------------------------------
// Fused GCN aggregate: out[v] = bias + selfloop + extra + sum_{CSR} w*xw[src].
// One wave per row, float2 per lane, entry loop unrolled x2 (both gathers
// issued before use -> 2 outstanding row loads), no atomics.
__global__ __launch_bounds__(256) void k_agg(const int2* __restrict__ ent,
                                             const int* __restrict__ start,
                                             const int* __restrict__ end,
                                             const float* __restrict__ xw,
                                             const float* __restrict__ dinv,
                                             const float* __restrict__ bias,
                                             float* __restrict__ out) {
  int v = blockIdx.x * 4 + (threadIdx.x >> 6);
  int lane = threadIdx.x & 63;
  float dv = dinv[v];
  float2 xv = *(const float2*)(xw + (long)v * 128 + lane * 2);
  float2 b2 = *(const float2*)(bias + lane * 2);
  float acc0 = b2.x + dv * dv * xv.x;
  float acc1 = b2.y + dv * dv * xv.y;
  if (v < NN) {
    acc0 += dv * dv * xv.x;  // extra edge (j, j)
    acc1 += dv * dv * xv.y;
  } else if (v < N3) {
    int j = (v < 2 * NN) ? v - NN : v - 2 * NN;
    float2 xj = *(const float2*)(xw + (long)j * 128 + lane * 2);
    float w = dinv[j] * dv;
    acc0 = fmaf(w, xj.x, acc0);  // extra edge (j, i*NN + j)
    acc1 = fmaf(w, xj.y, acc1);
  }
  const int i1 = end[v];
  int i = start[v];
  for (; i + 1 < i1; i += 2) {
    int2 e0 = ent[i], e1 = ent[i + 1];
    float w0 = __int_as_float(e0.y), w1 = __int_as_float(e1.y);
    float2 x0 = *(const float2*)(xw + (long)e0.x * 128 + lane * 2);
    float2 x1 = *(const float2*)(xw + (long)e1.x * 128 + lane * 2);
    acc0 = fmaf(w0, x0.x, acc0);
    acc1 = fmaf(w0, x0.y, acc1);
    acc0 = fmaf(w1, x1.x, acc0);
    acc1 = fmaf(w1, x1.y, acc1);
  }
  if (i < i1) {
    int2 e0 = ent[i];
    float w0 = __int_as_float(e0.y);
    float2 x0 = *(const float2*)(xw + (long)e0.x * 128 + lane * 2);
    acc0 = fmaf(w0, x0.x, acc0);
    acc1 = fmaf(w0, x0.y, acc1);
  }
  *(float2*)(out + (long)v * 128 + lane * 2) = make_float2(acc0, acc1);
}

__global__ __launch_bounds__(256) void k_zero_small(float* __restrict__ hyper,
                                                    int* __restrict__ hist) {
  int i = blockIdx.x * 256 + threadIdx.x;
  if (i < 128 * 128) hyper[i] = 0.f;
  if (i < 640) hist[i] = 0;
}

// vote histogram: hist[c][m] = #nodes whose count for class c is exactly m.
// LDS-accumulated per block (20 blocks x 1000 nodes), one flush per block.
#define HISTBLK 20
__global__ __launch_bounds__(256) void k_hist(const int* __restrict__ cls,
                                              int* __restrict__ hist) {
  __shared__ int sh[640];
  const int t = threadIdx.x;
  for (int i = t; i < 640; i += 256) sh[i] = 0;
  __syncthreads();
  const int per = NN / HISTBLK;  // 1000
  const int j0 = blockIdx.x * per;
  for (int j = j0 + t; j < j0 + per; j += 256) {
    int cc[4] = {cls[j], cls[NN + j], cls[2 * NN + j], cls[3 * NN + j]};
#pragma unroll
    for (int i = 0; i < 4; ++i) {
      bool first = true;
      int m = 0;
#pragma unroll
      for (int k = 0; k < 4; ++k) {
        if (cc[k] == cc[i]) {
          if (k < i) first = false;
          m++;
        }
      }
      if (first) atomicAdd(&sh[cc[i] * 5 + m], 1);
    }
  }
  __syncthreads();
  for (int i = t; i < 640; i += 256) {
    int v = sh[i];
    if (v) atomicAdd(&hist[i], v);
  }
}

// per-class softmax table over count values 0..4
__global__ void k_table(const int* __restrict__ hist, float* __restrict__ table) {
  int c = threadIdx.x;
  if (c >= 128) return;
  int cnt[5];
  int tot = 0;
  for (int v = 1; v <= 4; ++v) {
    cnt[v] = hist[c * 5 + v];
    tot += cnt[v];
  }
  cnt[0] = NN - tot;
  int m = 0;
  for (int v = 0; v <= 4; ++v)
    if (cnt[v] > 0) m = v;
  float ex[5];
  float denom = 0.f;
  for (int v = 0; v <= 4; ++v) {
    ex[v] = expf((float)(v - m));
    denom += (float)cnt[v] * ex[v];
  }
  for (int v = 0; v <= 4; ++v) table[c * 5 + v] = ex[v] / denom;
}

__global__ __launch_bounds__(256) void k_hwrite(const int* __restrict__ cls,
                                                const float* __restrict__ table,
                                                float* __restrict__ H) {
  int j = blockIdx.x * 2 + (threadIdx.x >> 7);
  int c = threadIdx.x & 127;
  if (j >= NN) return;
  int c0 = cls[j], c1 = cls[NN + j], c2 = cls[2 * NN + j], c3 = cls[3 * NN + j];
  int cnt = (c == c0) + (c == c1) + (c == c2) + (c == c3);
  H[(long)j * 128 + c] = table[c * 5 + cnt];
}

// ---------------------------------------------------------------------------
// hyper[c][d] = sum over nodes voting for class c of af2[j][d].
// LDS-accumulated: 250 blocks x 80 nodes.
#define HBLK 250
#define HPER 80
__global__ __launch_bounds__(256) void k_hyper(const int* __restrict__ cls,
                                               const float* __restrict__ af2,
                                               float* __restrict__ hyper) {
  __shared__ float acc[128 * 128];
  const int t = threadIdx.x;
  for (int i = t; i < 128 * 128; i += 256) acc[i] = 0.f;
  __syncthreads();
  const int j0 = blockIdx.x * HPER;
  const int j1 = j0 + HPER;  // NN == HBLK*HPER exactly
  const int d = t & 127;
  const int half = t >> 7;  // 0: slots {0,2}; 1: slots {1,3}
  float v = af2[(long)j0 * 128 + d];
  int c0 = cls[j0], c1 = cls[NN + j0], c2 = cls[2 * NN + j0], c3 = cls[3 * NN + j0];
  for (int j = j0; j < j1; ++j) {
    float vn = 0.f;
    int n0 = 0, n1 = 0, n2 = 0, n3 = 0;
    if (j + 1 < j1) {
      vn = af2[(long)(j + 1) * 128 + d];
      n0 = cls[j + 1];
      n1 = cls[NN + j + 1];
      n2 = cls[2 * NN + j + 1];
      n3 = cls[3 * NN + j + 1];
    }
    if (half == 0) {
      atomicAdd(&acc[c0 * 128 + d], v);  // slot 0 always first occurrence
      if (c2 != c0 && c2 != c1) atomicAdd(&acc[c2 * 128 + d], v);
    } else {
      if (c1 != c0) atomicAdd(&acc[c1 * 128 + d], v);
      if (c3 != c0 && c3 != c1 && c3 != c2) atomicAdd(&acc[c3 * 128 + d], v);
    }
    v = vn;
    c0 = n0;
    c1 = n1;
    c2 = n2;
    c3 = n3;
  }
  __syncthreads();
  for (int i = t; i < 128 * 128; i += 256) {
    float x = acc[i];
    if (x != 0.f) atomAddF(&hyper[i], x);
  }
}

// ---------------------------------------------------------------------------
extern "C" void kernel_launch(void* const* d_in, const int* in_sizes, int n_in,
                              void* d_out, int out_size, void* d_ws, size_t ws_size,
                              hipStream_t stream) {
  (void)in_sizes;
  (void)n_in;
  (void)out_size;
  (void)ws_size;
  const int* ei = (const int*)d_in[0];
  const float* feat = (const float*)d_in[1];
  const float* lin_W = (const float*)d_in[2];
  const float* lin_b = (const float*)d_in[3];
  const float* g1W = (const float*)d_in[4];
  const float* g1b = (const float*)d_in[5];
  const float* g2W = (const float*)d_in[6];
  const float* g2b = (const float*)d_in[7];
  const float* l1W = (const float*)d_in[8];
  const float* l1b = (const float*)d_in[9];

  float* out = (float*)d_out;
  float* H = out;
  float* hyper = out + (size_t)NN * 128;
  float* dots = hyper + 128 * 128;

  float* ws = (float*)d_ws;
  float* A = ws;                          // all_features [(T+1)*NN, 128]
  float* Cb = A + (size_t)NTOT * 128;     // h1 / af2 buffer
  float* Bb = dots;                       // xw buffer aliased onto dots
                                          // (dots written only by final GEMM)
  float* dinv = Cb + (size_t)NTOT * 128;  // [NTOT]
  float* nf = dinv + NTOT;                // feature norms [NN]
  float* nt0 = nf + NN;                   // transformed0 norms [NN]
  int* bn = (int*)(nt0 + NN);             // best_nodes [NE]
  int* cls = bn + NE;                     // classes [NTOT]
  int* hist = cls + NTOT;                 // [640]
  float* table = (float*)(hist + 640);    // [640]
  int* count = (int*)(table + 640);       // [NTOT]
  int* startA = count + NTOT;             // [NTOT]
  int* cursor = startA + NTOT;            // [NTOT]  (== end after fill)
  int* bsum = cursor + NTOT;              // [128]
  int2* ent = (int2*)(bsum + 128);        // [2*NE] CSR entries (src, weight)

  const float kScale = 0.08838834764831843f;  // 128^-0.5

  // 1. all_features rows [0,NN) = features
  k_copy_feat<<<(NN * 128 / 4 + 255) / 256, 256, 0, stream>>>(feat, A, NN * 128 / 4);
  // 2. transformed: per-replica linears -> rows [NN, 4*NN)  (20000 = 125*160)
  gemm128<0, 0, 0><<<dim3(125, 3), 512, 0, stream>>>(
      feat, lin_W, lin_b, A + (size_t)NN * 128, NN, 1.f, 128 * 128, 128,
      (long)NN * 128, nullptr);
  // 3. row norms
  k_norms<<<10000, 256, 0, stream>>>(feat, A, nf, nt0);
  // 4. cosine-sim replica pick
  k_zero_count<<<(NTOT + 255) / 256, 256, 0, stream>>>(count);
  k_sim<<<NE / 4, 256, 0, stream>>>(ei, feat, A, nf, nt0, bn);
  // 5. CSR build: count, dinv, scan, fill
  k_count<<<(NE + 255) / 256, 256, 0, stream>>>(ei, bn, count);
  k_dinv<<<(NTOT + 255) / 256, 256, 0, stream>>>(count, dinv);
  k_scan1<<<NBLK1, 256, 0, stream>>>(count, startA, bsum);
  k_scan2<<<1, 256, 0, stream>>>(bsum);
  k_scan3<<<(NTOT + 255) / 256, 256, 0, stream>>>(startA, bsum, cursor);
  k_fill<<<(2 * NE + 255) / 256, 256, 0, stream>>>(ei, bn, dinv, cursor, ent);
  // 6. GCN1: xw1 = relu(all_features) @ W1; fused aggregate -> h1 in Cb
  //    (80000 = 500*160 -> single residency round at 2 blocks/CU)
  gemm128<1, 0, 0><<<dim3(NTOT / 160, 1), 512, 0, stream>>>(A, g1W, nullptr, Bb, NTOT,
                                                            1.f, 0, 0, 0, nullptr);
  k_agg<<<NTOT / 4, 256, 0, stream>>>(ent, startA, cursor, Bb, dinv, g1b, Cb);
  // 7. GCN2: xw2 = relu(h1) @ W2; fused aggregate -> af2 in Cb
  gemm128<1, 0, 0><<<dim3(NTOT / 160, 1), 512, 0, stream>>>(Cb, g2W, nullptr, Bb, NTOT,
                                                            1.f, 0, 0, 0, nullptr);
  k_agg<<<NTOT / 4, 256, 0, stream>>>(ent, startA, cursor, Bb, dinv, g2b, Cb);
  // 8. logits GEMM with fused per-row argmax -> classes (no logits store)
  gemm128<1, 0, 1><<<dim3(NTOT / 160, 1), 512, 0, stream>>>(Cb, l1W, l1b, nullptr,
                                                            NTOT, 1.f, 0, 0, 0, cls);
  // 9. zero hyper + hist
  k_zero_small<<<64, 256, 0, stream>>>(hyper, hist);
  // 10. vote histogram (LDS) -> per-class softmax table
  k_hist<<<HISTBLK, 256, 0, stream>>>(cls, hist);
  k_table<<<1, 128, 0, stream>>>(hist, table);
  // 11. H output (softmax over nodes, via count table)
  k_hwrite<<<NN / 2, 256, 0, stream>>>(cls, table, H);
  // 12. hyperedge features (LDS-accumulated)
  k_hyper<<<HBLK, 256, 0, stream>>>(cls, Cb, hyper);
  // 13. dots = all_features @ hyper^T * scale
  gemm128<0, 1, 0><<<dim3(NTOT / 160, 1), 512, 0, stream>>>(A, hyper, nullptr, dots,
                                                            NTOT, kScale, 0, 0, 0,
                                                            nullptr);
}

// Round 15
// 435.704 us; speedup vs baseline: 1.4950x; 1.0740x over previous
//
#include <hip/hip_runtime.h>
#include <math.h>

#define NN 20000
#define NE 160000
#define TT 3
#define DD 128
#define NTOT 80000   // (TT+1)*NN
#define N3 60000     // TT*NN
#define NBLK1 79     // ceil(NTOT/1024) for the scan
#define SIMW 20000   // k_sim waves (grid 5000 x 4 waves)

__device__ __forceinline__ float waveReduceSum(float v) {
#pragma unroll
  for (int off = 32; off >= 1; off >>= 1)
    v += __shfl_xor(v, off, 64);
  return v;
}

__device__ __forceinline__ void atomAddF(float* p, float v) {
  unsafeAtomicAdd(p, v);
}

// ---------------------------------------------------------------------------
// copy features into all_features rows [0, NN)
__global__ __launch_bounds__(256) void k_copy_feat(const float* __restrict__ src,
                                                   float* __restrict__ dst, int n4) {
  int i = blockIdx.x * 256 + threadIdx.x;
  if (i < n4) ((float4*)dst)[i] = ((const float4*)src)[i];
}

// ---------------------------------------------------------------------------
// [M,128] @ [128,128] GEMM. 160x128 tile per block (500 blocks <= 512
// concurrent -> single residency round). 512 threads, 5x8 per thread.
// W staged in LDS once (full K); X broadcast-read from global, once/block.
// __launch_bounds__(512,3): VGPR budget ~170 so the 2-deep X prefetch
// (xc+xn+acc ~ 110 VGPR) stays resident instead of being discarded (r9/r12
// compiled to VGPR=56 -> prefetch dead, VALUBusy 33%).
template <int RELU_IN, int TRANS_W, int DO_ARGMAX>
__global__ __launch_bounds__(512, 3) void gemm128(const float* __restrict__ X,
                                                  const float* __restrict__ W,
                                                  const float* __restrict__ bias,
                                                  float* __restrict__ out, int M,
                                                  float scale, int wStride, int bStride,
                                                  long oStride, int* __restrict__ cls) {
  __shared__ float Ws[128 * 132];
  const int tid = threadIdx.x;
  const int rbase = blockIdx.x * 160;
  W += (long)blockIdx.y * wStride;
  if (bias) bias += (long)blockIdx.y * bStride;
  out += (long)blockIdx.y * oStride;

  // stage all of W into LDS (row kl, padded stride 132)
#pragma unroll
  for (int it = 0; it < 8; ++it) {
    int idx = (tid + it * 512) * 4;
    int kl = idx >> 7, c = idx & 127;
    float4 w;
    if (!TRANS_W) {
      w = *(const float4*)&W[kl * 128 + c];
    } else {
      w.x = W[(c + 0) * 128 + kl];
      w.y = W[(c + 1) * 128 + kl];
      w.z = W[(c + 2) * 128 + kl];
      w.w = W[(c + 3) * 128 + kl];
    }
    *(float4*)&Ws[kl * 132 + c] = w;
  }

  const int tc = tid & 15, tr = tid >> 4;  // tr in [0,32)
  const int c0 = tc * 8, r0 = tr * 5;

  const float4* xrow[5];
#pragma unroll
  for (int i = 0; i < 5; ++i) {
    int gr = rbase + r0 + i;
    int gc = (gr < M) ? gr : 0;  // clamp tail rows (stores are guarded)
    xrow[i] = (const float4*)(X + (long)gc * 128);
  }

  float acc[5][8];
#pragma unroll
  for (int i = 0; i < 5; ++i)
#pragma unroll
    for (int j = 0; j < 8; ++j) acc[i][j] = 0.f;

  float4 xc[5], xn[5];
#pragma unroll
  for (int i = 0; i < 5; ++i) {
    float4 v = xrow[i][0];
    if (RELU_IN) {
      v.x = fmaxf(v.x, 0.f);
      v.y = fmaxf(v.y, 0.f);
      v.z = fmaxf(v.z, 0.f);
      v.w = fmaxf(v.w, 0.f);
    }
    xc[i] = v;
  }

  __syncthreads();  // W staged

  for (int kq = 0; kq < 32; ++kq) {
    if (kq < 31) {
#pragma unroll
      for (int i = 0; i < 5; ++i) {
        float4 v = xrow[i][kq + 1];
        if (RELU_IN) {
          v.x = fmaxf(v.x, 0.f);
          v.y = fmaxf(v.y, 0.f);
          v.z = fmaxf(v.z, 0.f);
          v.w = fmaxf(v.w, 0.f);
        }
        xn[i] = v;
      }
    }
    const int klb = kq * 4;
#pragma unroll
    for (int k = 0; k < 4; ++k) {
      const int kl = klb + k;
      const float4 wa = *(const float4*)&Ws[kl * 132 + c0];
      const float4 wb = *(const float4*)&Ws[kl * 132 + c0 + 4];
      float av[5];
#pragma unroll
      for (int i = 0; i < 5; ++i)
        av[i] = (k == 0) ? xc[i].x : (k == 1) ? xc[i].y : (k == 2) ? xc[i].z : xc[i].w;
      const float bv[8] = {wa.x, wa.y, wa.z, wa.w, wb.x, wb.y, wb.z, wb.w};
#pragma unroll
      for (int i = 0; i < 5; ++i)
#pragma unroll
        for (int j = 0; j < 8; ++j) acc[i][j] = fmaf(av[i], bv[j], acc[i][j]);
    }
    if (kq < 31) {
#pragma unroll
      for (int i = 0; i < 5; ++i) xc[i] = xn[i];
    }
  }

  float bb[8];
#pragma unroll
  for (int j = 0; j < 8; ++j) bb[j] = 0.f;
  if (bias) {
#pragma unroll
    for (int j = 0; j < 8; ++j) bb[j] = bias[c0 + j];
  }

  if (DO_ARGMAX) {
#pragma unroll
    for (int i = 0; i < 5; ++i) {
      float bv = acc[i][0] * scale + bb[0];
      int bc = c0;
#pragma unroll
      for (int j = 1; j < 8; ++j) {
        float v = acc[i][j] * scale + bb[j];
        if (v > bv) {
          bv = v;
          bc = c0 + j;
        }
      }
#pragma unroll
      for (int off = 1; off <= 8; off <<= 1) {
        float ov = __shfl_xor(bv, off, 64);
        int oc = __shfl_xor(bc, off, 64);
        if (ov > bv || (ov == bv && oc < bc)) {
          bv = ov;
          bc = oc;
        }
      }
      int gr = rbase + r0 + i;
      if (tc == 0 && gr < M) cls[gr] = bc;
    }
  } else {
#pragma unroll
    for (int i = 0; i < 5; ++i) {
      int gr = rbase + r0 + i;
      if (gr < M) {
        float4 v0, v1;
        v0.x = acc[i][0] * scale + bb[0];
        v0.y = acc[i][1] * scale + bb[1];
        v0.z = acc[i][2] * scale + bb[2];
        v0.w = acc[i][3] * scale + bb[3];
        v1.x = acc[i][4] * scale + bb[4];
        v1.y = acc[i][5] * scale + bb[5];
        v1.z = acc[i][6] * scale + bb[6];
        v1.w = acc[i][7] * scale + bb[7];
        *(float4*)&out[(long)gr * 128 + c0] = v0;
        *(float4*)&out[(long)gr * 128 + c0 + 4] = v1;
      }
    }
  }
}

// ---------------------------------------------------------------------------
// row norms (float2 per lane): first NN waves -> ||features[j]||,
// next NN -> ||transformed0[j]||
__global__ __launch_bounds__(256) void k_norms(const float* __restrict__ feat,
                                               const float* __restrict__ A,
                                               float* __restrict__ nf,
                                               float* __restrict__ nt0) {
  int w = blockIdx.x * 4 + (threadIdx.x >> 6);
  int lane = threadIdx.x & 63;
  if (w >= 2 * NN) return;
  const float* p = (w < NN) ? (feat + (long)w * 128) : (A + (long)(NN + (w - NN)) * 128);
  float2 v = *(const float2*)(p + lane * 2);
  float s = waveReduceSum(v.x * v.x + v.y * v.y);
  if (lane == 0) {
    float r = sqrtf(s);
    if (w < NN) nf[w] = r;
    else nt0[w - NN] = r;
  }
}

// ---------------------------------------------------------------------------
// cosine-sim replica selection. 32 lanes per edge (float4/lane), 2 edges per
// wave, 4 grid-strided iterations with 1-ahead prefetch -> 16 row-loads in
// flight per wave (vs 4). Reduce: 5-step shfl within each 32-lane half.
__global__ __launch_bounds__(256) void k_sim(const int* __restrict__ ei,
                                             const float* __restrict__ feat,
                                             const float* __restrict__ A,
                                             const float* __restrict__ nf,
                                             const float* __restrict__ nt0,
                                             int* __restrict__ bn) {
  const int t = threadIdx.x;
  const int lane = t & 31;
  const int half = (t >> 5) & 1;
  const int w = blockIdx.x * 4 + (t >> 6);  // wave id in [0, SIMW)

#define SIM_LOAD(I, E, DE, AV, B0, B1, B2, NA, NB0, NB1, NB2)              \
  {                                                                        \
    E = 2 * (w + (I)*SIMW) + half;                                         \
    DE = ei[NE + E];                                                       \
    int s_ = ei[E];                                                        \
    int j0_ = 3 * E;                                                       \
    if (j0_ >= NE) j0_ -= NE;                                              \
    if (j0_ >= NE) j0_ -= NE;                                              \
    int j1_ = j0_ + 1;                                                     \
    if (j1_ >= NE) j1_ -= NE;                                              \
    int j2_ = j0_ + 2;                                                     \
    if (j2_ >= NE) j2_ -= NE;                                              \
    int d0_ = ei[NE + j0_], d1_ = ei[NE + j1_], d2_ = ei[NE + j2_];        \
    AV = ((const float4*)(feat + (long)s_ * 128))[lane];                   \
    B0 = ((const float4*)(A + (long)(NN + d0_) * 128))[lane];              \
    B1 = ((const float4*)(A + (long)(NN + d1_) * 128))[lane];              \
    B2 = ((const float4*)(A + (long)(NN + d2_) * 128))[lane];              \
    NA = nf[s_];                                                           \
    NB0 = nt0[d0_];                                                        \
    NB1 = nt0[d1_];                                                        \
    NB2 = nt0[d2_];                                                        \
  }

  int ec, dec;
  float4 ac, b0c, b1c, b2c;
  float nac, nb0c, nb1c, nb2c;
  SIM_LOAD(0, ec, dec, ac, b0c, b1c, b2c, nac, nb0c, nb1c, nb2c);

#pragma unroll
  for (int i = 0; i < 4; ++i) {
    int en = 0, den = 0;
    float4 an, b0n, b1n, b2n;
    float nan2 = 0.f, nb0n = 0.f, nb1n = 0.f, nb2n = 0.f;
    if (i < 3) {
      SIM_LOAD(i + 1, en, den, an, b0n, b1n, b2n, nan2, nb0n, nb1n, nb2n);
    }
    float p0 = ac.x * b0c.x + ac.y * b0c.y + ac.z * b0c.z + ac.w * b0c.w;
    float p1 = ac.x * b1c.x + ac.y * b1c.y + ac.z * b1c.z + ac.w * b1c.w;
    float p2 = ac.x * b2c.x + ac.y * b2c.y + ac.z * b2c.z + ac.w * b2c.w;
#pragma unroll
    for (int off = 1; off <= 16; off <<= 1) {
      p0 += __shfl_xor(p0, off, 64);
      p1 += __shfl_xor(p1, off, 64);
      p2 += __shfl_xor(p2, off, 64);
    }
    float s0 = p0 / fmaxf(nac * nb0c, 1e-8f);
    float s1 = p1 / fmaxf(nac * nb1c, 1e-8f);
    float s2 = p2 / fmaxf(nac * nb2c, 1e-8f);
    int bk = 0;
    float bv = s0;
    if (s1 > bv) {
      bv = s1;
      bk = 1;
    }
    if (s2 > bv) {
      bv = s2;
      bk = 2;
    }
    if (lane == 0) bn[ec] = dec + bk * NN;
    if (i < 3) {
      ec = en;
      dec = den;
      ac = an;
      b0c = b0n;
      b1c = b1n;
      b2c = b2n;
      nac = nan2;
      nb0c = nb0n;
      nb1c = nb1n;
      nb2c = nb2n;
    }
  }
#undef SIM_LOAD
}

// ---------------------------------------------------------------------------
// CSR build: count -> scan(3 phases) -> fill. Shared by both GCN layers.
__global__ __launch_bounds__(256) void k_zero_count(int* __restrict__ count) {
  int v = blockIdx.x * 256 + threadIdx.x;
  if (v < NTOT) count[v] = 0;
}

__global__ __launch_bounds__(256) void k_count(const int* __restrict__ ei,
                                               const int* __restrict__ bn,
                                               int* __restrict__ count) {
  int e = blockIdx.x * 256 + threadIdx.x;
  if (e < NE) {
    atomicAdd(&count[ei[NE + e]], 1);
    atomicAdd(&count[bn[e]], 1);
  }
}

// dinv[v] = rsqrt(unstructured_count + structured (2 for v<N3, else 1))
__global__ __launch_bounds__(256) void k_dinv(const int* __restrict__ count,
                                              float* __restrict__ dinv) {
  int v = blockIdx.x * 256 + threadIdx.x;
  if (v < NTOT) {
    float deg = (float)count[v] + ((v < N3) ? 2.f : 1.f);
    dinv[v] = 1.f / sqrtf(deg);
  }
}

// scan phase 1: per-1024-block local exclusive scan + block sums
__global__ __launch_bounds__(256) void k_scan1(const int* __restrict__ count,
                                               int* __restrict__ start,
                                               int* __restrict__ bsum) {
  __shared__ int sh[256];
  const int b = blockIdx.x, t = threadIdx.x;
  const int base = b * 1024 + t * 4;
  int c[4];
  int s = 0;
#pragma unroll
  for (int k = 0; k < 4; ++k) {
    int idx = base + k;
    c[k] = (idx < NTOT) ? count[idx] : 0;
    s += c[k];
  }
  sh[t] = s;
  __syncthreads();
  for (int off = 1; off < 256; off <<= 1) {
    int v = (t >= off) ? sh[t - off] : 0;
    __syncthreads();
    sh[t] += v;
    __syncthreads();
  }
  if (t == 255) bsum[b] = sh[255];
  int run = sh[t] - s;  // exclusive prefix of this thread
#pragma unroll
  for (int k = 0; k < 4; ++k) {
    int idx = base + k;
    if (idx < NTOT) start[idx] = run;
    run += c[k];
  }
}

// scan phase 2: exclusive scan of NBLK1 block sums (single block)
__global__ __launch_bounds__(256) void k_scan2(int* __restrict__ bsum) {
  __shared__ int sh[256];
  const int t = threadIdx.x;
  int v = (t < NBLK1) ? bsum[t] : 0;
  sh[t] = v;
  __syncthreads();
  for (int off = 1; off < 256; off <<= 1) {
    int u = (t >= off) ? sh[t - off] : 0;
    __syncthreads();
    sh[t] += u;
    __syncthreads();
  }
  if (t < NBLK1) bsum[t] = sh[t] - v;
}

// scan phase 3: add block offsets; init cursor = start
__global__ __launch_bounds__(256) void k_scan3(int* __restrict__ start,
                                               const int* __restrict__ bsum,
                                               int* __restrict__ cursor) {
  int i = blockIdx.x * 256 + threadIdx.x;
  if (i < NTOT) {
    int v = start[i] + bsum[i >> 10];
    start[i] = v;
    cursor[i] = v;
  }
}

// fill CSR entries: (src, weight) packed in int2
__global__ __launch_bounds__(256) void k_fill(const int* __restrict__ ei,
                                              const int* __restrict__ bn,
                                              const float* __restrict__ dinv,
                                              int* __restrict__ cursor,
                                              int2* __restrict__ ent) {
  int g = blockIdx.x * 256 + threadIdx.x;
  if (g >= 2 * NE) return;
  int e = (g < NE) ? g : g - NE;
  int s = ei[e];
  int d = (g < NE) ? ei[NE + e] : bn[e];
  float w = dinv[s] * dinv[d];
  int pos = atomicAdd(&cursor[d], 1);
  ent[pos] = make_int2(s, __float_as_int(w));
}

// ---------------------------------------------------------------------------
// Fused GCN aggregate: out[v] = bias + selfloop + extra + sum_{CSR} w*xw[src].
// One wave per row, float2 per lane, entry loop unrolled x2 (both gathers
// issued before use -> 2 outstanding row loads), no atomics.
__global__ __launch_bounds__(256) void k_agg(const int2* __restrict__ ent,
                                             const int* __restrict__ start,
                                             const int* __restrict__ end,
                                             const float* __restrict__ xw,
                                             const float* __restrict__ dinv,
                                             const float* __restrict__ bias,
                                             float* __restrict__ out) {
  int v = blockIdx.x * 4 + (threadIdx.x >> 6);
  int lane = threadIdx.x & 63;
  float dv = dinv[v];
  float2 xv = *(const float2*)(xw + (long)v * 128 + lane * 2);
  float2 b2 = *(const float2*)(bias + lane * 2);
  float acc0 = b2.x + dv * dv * xv.x;
  float acc1 = b2.y + dv * dv * xv.y;
  if (v < NN) {
    acc0 += dv * dv * xv.x;  // extra edge (j, j)
    acc1 += dv * dv * xv.y;
  } else if (v < N3) {
    int j = (v < 2 * NN) ? v - NN : v - 2 * NN;
    float2 xj = *(const float2*)(xw + (long)j * 128 + lane * 2);
    float w = dinv[j] * dv;
    acc0 = fmaf(w, xj.x, acc0);  // extra edge (j, i*NN + j)
    acc1 = fmaf(w, xj.y, acc1);
  }
  const int i1 = end[v];
  int i = start[v];
  for (; i + 1 < i1; i += 2) {
    int2 e0 = ent[i], e1 = ent[i + 1];
    float w0 = __int_as_float(e0.y), w1 = __int_as_float(e1.y);
    float2 x0 = *(const float2*)(xw + (long)e0.x * 128 + lane * 2);
    float2 x1 = *(const float2*)(xw + (long)e1.x * 128 + lane * 2);
    acc0 = fmaf(w0, x0.x, acc0);
    acc1 = fmaf(w0, x0.y, acc1);
    acc0 = fmaf(w1, x1.x, acc0);
    acc1 = fmaf(w1, x1.y, acc1);
  }
  if (i < i1) {
    int2 e0 = ent[i];
    float w0 = __int_as_float(e0.y);
    float2 x0 = *(const float2*)(xw + (long)e0.x * 128 + lane * 2);
    acc0 = fmaf(w0, x0.x, acc0);
    acc1 = fmaf(w0, x0.y, acc1);
  }
  *(float2*)(out + (long)v * 128 + lane * 2) = make_float2(acc0, acc1);
}

__global__ __launch_bounds__(256) void k_zero_small(float* __restrict__ hyper,
                                                    int* __restrict__ hist) {
  int i = blockIdx.x * 256 + threadIdx.x;
  if (i < 128 * 128) hyper[i] = 0.f;
  if (i < 640) hist[i] = 0;
}

// vote histogram: hist[c][m] = #nodes whose count for class c is exactly m.
// LDS-accumulated per block (20 blocks x 1000 nodes), one flush per block.
#define HISTBLK 20
__global__ __launch_bounds__(256) void k_hist(const int* __restrict__ cls,
                                              int* __restrict__ hist) {
  __shared__ int sh[640];
  const int t = threadIdx.x;
  for (int i = t; i < 640; i += 256) sh[i] = 0;
  __syncthreads();
  const int per = NN / HISTBLK;  // 1000
  const int j0 = blockIdx.x * per;
  for (int j = j0 + t; j < j0 + per; j += 256) {
    int cc[4] = {cls[j], cls[NN + j], cls[2 * NN + j], cls[3 * NN + j]};
#pragma unroll
    for (int i = 0; i < 4; ++i) {
      bool first = true;
      int m = 0;
#pragma unroll
      for (int k = 0; k < 4; ++k) {
        if (cc[k] == cc[i]) {
          if (k < i) first = false;
          m++;
        }
      }
      if (first) atomicAdd(&sh[cc[i] * 5 + m], 1);
    }
  }
  __syncthreads();
  for (int i = t; i < 640; i += 256) {
    int v = sh[i];
    if (v) atomicAdd(&hist[i], v);
  }
}

// per-class softmax table over count values 0..4
__global__ void k_table(const int* __restrict__ hist, float* __restrict__ table) {
  int c = threadIdx.x;
  if (c >= 128) return;
  int cnt[5];
  int tot = 0;
  for (int v = 1; v <= 4; ++v) {
    cnt[v] = hist[c * 5 + v];
    tot += cnt[v];
  }
  cnt[0] = NN - tot;
  int m = 0;
  for (int v = 0; v <= 4; ++v)
    if (cnt[v] > 0) m = v;
  float ex[5];
  float denom = 0.f;
  for (int v = 0; v <= 4; ++v) {
    ex[v] = expf((float)(v - m));
    denom += (float)cnt[v] * ex[v];
  }
  for (int v = 0; v <= 4; ++v) table[c * 5 + v] = ex[v] / denom;
}

__global__ __launch_bounds__(256) void k_hwrite(const int* __restrict__ cls,
                                                const float* __restrict__ table,
                                                float* __restrict__ H) {
  int j = blockIdx.x * 2 + (threadIdx.x >> 7);
  int c = threadIdx.x & 127;
  if (j >= NN) return;
  int c0 = cls[j], c1 = cls[NN + j], c2 = cls[2 * NN + j], c3 = cls[3 * NN + j];
  int cnt = (c == c0) + (c == c1) + (c == c2) + (c == c3);
  H[(long)j * 128 + c] = table[c * 5 + cnt];
}

// ---------------------------------------------------------------------------
// hyper[c][d] = sum over nodes voting for class c of af2[j][d].
// LDS-accumulated: 250 blocks x 80 nodes.
#define HBLK 250
#define HPER 80
__global__ __launch_bounds__(256) void k_hyper(const int* __restrict__ cls,
                                               const float* __restrict__ af2,
                                               float* __restrict__ hyper) {
  __shared__ float acc[128 * 128];
  const int t = threadIdx.x;
  for (int i = t; i < 128 * 128; i += 256) acc[i] = 0.f;
  __syncthreads();
  const int j0 = blockIdx.x * HPER;
  const int j1 = j0 + HPER;  // NN == HBLK*HPER exactly
  const int d = t & 127;
  const int half = t >> 7;  // 0: slots {0,2}; 1: slots {1,3}
  float v = af2[(long)j0 * 128 + d];
  int c0 = cls[j0], c1 = cls[NN + j0], c2 = cls[2 * NN + j0], c3 = cls[3 * NN + j0];
  for (int j = j0; j < j1; ++j) {
    float vn = 0.f;
    int n0 = 0, n1 = 0, n2 = 0, n3 = 0;
    if (j + 1 < j1) {
      vn = af2[(long)(j + 1) * 128 + d];
      n0 = cls[j + 1];
      n1 = cls[NN + j + 1];
      n2 = cls[2 * NN + j + 1];
      n3 = cls[3 * NN + j + 1];
    }
    if (half == 0) {
      atomicAdd(&acc[c0 * 128 + d], v);  // slot 0 always first occurrence
      if (c2 != c0 && c2 != c1) atomicAdd(&acc[c2 * 128 + d], v);
    } else {
      if (c1 != c0) atomicAdd(&acc[c1 * 128 + d], v);
      if (c3 != c0 && c3 != c1 && c3 != c2) atomicAdd(&acc[c3 * 128 + d], v);
    }
    v = vn;
    c0 = n0;
    c1 = n1;
    c2 = n2;
    c3 = n3;
  }
  __syncthreads();
  for (int i = t; i < 128 * 128; i += 256) {
    float x = acc[i];
    if (x != 0.f) atomAddF(&hyper[i], x);
  }
}

// ---------------------------------------------------------------------------
extern "C" void kernel_launch(void* const* d_in, const int* in_sizes, int n_in,
                              void* d_out, int out_size, void* d_ws, size_t ws_size,
                              hipStream_t stream) {
  (void)in_sizes;
  (void)n_in;
  (void)out_size;
  (void)ws_size;
  const int* ei = (const int*)d_in[0];
  const float* feat = (const float*)d_in[1];
  const float* lin_W = (const float*)d_in[2];
  const float* lin_b = (const float*)d_in[3];
  const float* g1W = (const float*)d_in[4];
  const float* g1b = (const float*)d_in[5];
  const float* g2W = (const float*)d_in[6];
  const float* g2b = (const float*)d_in[7];
  const float* l1W = (const float*)d_in[8];
  const float* l1b = (const float*)d_in[9];

  float* out = (float*)d_out;
  float* H = out;
  float* hyper = out + (size_t)NN * 128;
  float* dots = hyper + 128 * 128;

  float* ws = (float*)d_ws;
  float* A = ws;                          // all_features [(T+1)*NN, 128]
  float* Cb = A + (size_t)NTOT * 128;     // h1 / af2 buffer
  float* Bb = dots;                       // xw buffer aliased onto dots
                                          // (dots written only by final GEMM)
  float* dinv = Cb + (size_t)NTOT * 128;  // [NTOT]
  float* nf = dinv + NTOT;                // feature norms [NN]
  float* nt0 = nf + NN;                   // transformed0 norms [NN]
  int* bn = (int*)(nt0 + NN);             // best_nodes [NE]
  int* cls = bn + NE;                     // classes [NTOT]
  int* hist = cls + NTOT;                 // [640]
  float* table = (float*)(hist + 640);    // [640]
  int* count = (int*)(table + 640);       // [NTOT]
  int* startA = count + NTOT;             // [NTOT]
  int* cursor = startA + NTOT;            // [NTOT]  (== end after fill)
  int* bsum = cursor + NTOT;              // [128]
  int2* ent = (int2*)(bsum + 128);        // [2*NE] CSR entries (src, weight)

  const float kScale = 0.08838834764831843f;  // 128^-0.5

  // 1. all_features rows [0,NN) = features
  k_copy_feat<<<(NN * 128 / 4 + 255) / 256, 256, 0, stream>>>(feat, A, NN * 128 / 4);
  // 2. transformed: per-replica linears -> rows [NN, 4*NN)  (20000 = 125*160)
  gemm128<0, 0, 0><<<dim3(125, 3), 512, 0, stream>>>(
      feat, lin_W, lin_b, A + (size_t)NN * 128, NN, 1.f, 128 * 128, 128,
      (long)NN * 128, nullptr);
  // 3. row norms
  k_norms<<<10000, 256, 0, stream>>>(feat, A, nf, nt0);
  // 4. cosine-sim replica pick (pipelined, 2 edges/wave, 4 iters/wave)
  k_zero_count<<<(NTOT + 255) / 256, 256, 0, stream>>>(count);
  k_sim<<<SIMW / 4, 256, 0, stream>>>(ei, feat, A, nf, nt0, bn);
  // 5. CSR build: count, dinv, scan, fill
  k_count<<<(NE + 255) / 256, 256, 0, stream>>>(ei, bn, count);
  k_dinv<<<(NTOT + 255) / 256, 256, 0, stream>>>(count, dinv);
  k_scan1<<<NBLK1, 256, 0, stream>>>(count, startA, bsum);
  k_scan2<<<1, 256, 0, stream>>>(bsum);
  k_scan3<<<(NTOT + 255) / 256, 256, 0, stream>>>(startA, bsum, cursor);
  k_fill<<<(2 * NE + 255) / 256, 256, 0, stream>>>(ei, bn, dinv, cursor, ent);
  // 6. GCN1: xw1 = relu(all_features) @ W1; fused aggregate -> h1 in Cb
  gemm128<1, 0, 0><<<dim3(NTOT / 160, 1), 512, 0, stream>>>(A, g1W, nullptr, Bb, NTOT,
                                                            1.f, 0, 0, 0, nullptr);
  k_agg<<<NTOT / 4, 256, 0, stream>>>(ent, startA, cursor, Bb, dinv, g1b, Cb);
  // 7. GCN2: xw2 = relu(h1) @ W2; fused aggregate -> af2 in Cb
  gemm128<1, 0, 0><<<dim3(NTOT / 160, 1), 512, 0, stream>>>(Cb, g2W, nullptr, Bb, NTOT,
                                                            1.f, 0, 0, 0, nullptr);
  k_agg<<<NTOT / 4, 256, 0, stream>>>(ent, startA, cursor, Bb, dinv, g2b, Cb);
  // 8. logits GEMM with fused per-row argmax -> classes (no logits store)
  gemm128<1, 0, 1><<<dim3(NTOT / 160, 1), 512, 0, stream>>>(Cb, l1W, l1b, nullptr,
                                                            NTOT, 1.f, 0, 0, 0, cls);
  // 9. zero hyper + hist
  k_zero_small<<<64, 256, 0, stream>>>(hyper, hist);
  // 10. vote histogram (LDS) -> per-class softmax table
  k_hist<<<HISTBLK, 256, 0, stream>>>(cls, hist);
  k_table<<<1, 128, 0, stream>>>(hist, table);
  // 11. H output (softmax over nodes, via count table)
  k_hwrite<<<NN / 2, 256, 0, stream>>>(cls, table, H);
  // 12. hyperedge features (LDS-accumulated)
  k_hyper<<<HBLK, 256, 0, stream>>>(cls, Cb, hyper);
  // 13. dots = all_features @ hyper^T * scale
  gemm128<0, 1, 0><<<dim3(NTOT / 160, 1), 512, 0, stream>>>(A, hyper, nullptr, dots,
                                                            NTOT, kScale, 0, 0, 0,
                                                            nullptr);
}

// Round 16
// 432.724 us; speedup vs baseline: 1.5053x; 1.0069x over previous
//
#include <hip/hip_runtime.h>
#include <math.h>

#define NN 20000
#define NE 160000
#define TT 3
#define DD 128
#define NTOT 80000   // (TT+1)*NN
#define N3 60000     // TT*NN
#define NBLK1 79     // ceil(NTOT/1024) for the scan
#define SIMW 20000   // k_sim waves (grid 5000 x 4 waves)

__device__ __forceinline__ float waveReduceSum(float v) {
#pragma unroll
  for (int off = 32; off >= 1; off >>= 1)
    v += __shfl_xor(v, off, 64);
  return v;
}

__device__ __forceinline__ void atomAddF(float* p, float v) {
  unsafeAtomicAdd(p, v);
}

// ---------------------------------------------------------------------------
// copy features into all_features rows [0, NN)
__global__ __launch_bounds__(256) void k_copy_feat(const float* __restrict__ src,
                                                   float* __restrict__ dst, int n4) {
  int i = blockIdx.x * 256 + threadIdx.x;
  if (i < n4) ((float4*)dst)[i] = ((const float4*)src)[i];
}

// ---------------------------------------------------------------------------
// [M,128] @ [128,128] GEMM. 160x128 tile per block (500 blocks <= 512
// concurrent -> single residency round). 512 threads, 5x8 per thread.
// W staged in LDS once (full K); X broadcast-read from global, once/block.
// K-loop is an explicit branch-free double buffer (xa/xb, kq step 2): loads
// precede the 160-FMA block in straight-line code so they stay in flight
// (r15's conditional prefetch compiled to VGPR=64 = prefetch discarded).
template <int RELU_IN, int TRANS_W, int DO_ARGMAX>
__global__ __launch_bounds__(512, 3) void gemm128(const float* __restrict__ X,
                                                  const float* __restrict__ W,
                                                  const float* __restrict__ bias,
                                                  float* __restrict__ out, int M,
                                                  float scale, int wStride, int bStride,
                                                  long oStride, int* __restrict__ cls) {
  __shared__ float Ws[128 * 132];
  const int tid = threadIdx.x;
  const int rbase = blockIdx.x * 160;
  W += (long)blockIdx.y * wStride;
  if (bias) bias += (long)blockIdx.y * bStride;
  out += (long)blockIdx.y * oStride;

  // stage all of W into LDS (row kl, padded stride 132)
#pragma unroll
  for (int it = 0; it < 8; ++it) {
    int idx = (tid + it * 512) * 4;
    int kl = idx >> 7, c = idx & 127;
    float4 w;
    if (!TRANS_W) {
      w = *(const float4*)&W[kl * 128 + c];
    } else {
      w.x = W[(c + 0) * 128 + kl];
      w.y = W[(c + 1) * 128 + kl];
      w.z = W[(c + 2) * 128 + kl];
      w.w = W[(c + 3) * 128 + kl];
    }
    *(float4*)&Ws[kl * 132 + c] = w;
  }

  const int tc = tid & 15, tr = tid >> 4;  // tr in [0,32)
  const int c0 = tc * 8, r0 = tr * 5;

  const float4* xrow[5];
#pragma unroll
  for (int i = 0; i < 5; ++i) {
    int gr = rbase + r0 + i;
    int gc = (gr < M) ? gr : 0;  // clamp tail rows (stores are guarded)
    xrow[i] = (const float4*)(X + (long)gc * 128);
  }

  float acc[5][8];
#pragma unroll
  for (int i = 0; i < 5; ++i)
#pragma unroll
    for (int j = 0; j < 8; ++j) acc[i][j] = 0.f;

  auto loadCol = [&](float4* dst, int col) {
#pragma unroll
    for (int i = 0; i < 5; ++i) {
      float4 v = xrow[i][col];
      if (RELU_IN) {
        v.x = fmaxf(v.x, 0.f);
        v.y = fmaxf(v.y, 0.f);
        v.z = fmaxf(v.z, 0.f);
        v.w = fmaxf(v.w, 0.f);
      }
      dst[i] = v;
    }
  };
  auto fmaStep = [&](const float4* xv, int kq) {
#pragma unroll
    for (int k = 0; k < 4; ++k) {
      const int kl = kq * 4 + k;
      const float4 wa = *(const float4*)&Ws[kl * 132 + c0];
      const float4 wb = *(const float4*)&Ws[kl * 132 + c0 + 4];
      float av[5];
#pragma unroll
      for (int i = 0; i < 5; ++i)
        av[i] = (k == 0) ? xv[i].x : (k == 1) ? xv[i].y : (k == 2) ? xv[i].z
                                                                   : xv[i].w;
      const float bv[8] = {wa.x, wa.y, wa.z, wa.w, wb.x, wb.y, wb.z, wb.w};
#pragma unroll
      for (int i = 0; i < 5; ++i)
#pragma unroll
        for (int j = 0; j < 8; ++j) acc[i][j] = fmaf(av[i], bv[j], acc[i][j]);
    }
  };

  float4 xa[5], xb[5];
  loadCol(xa, 0);

  __syncthreads();  // W staged

  for (int kq = 0; kq < 32; kq += 2) {
    loadCol(xb, kq + 1);  // kq+1 <= 31 always
    fmaStep(xa, kq);
    loadCol(xa, (kq + 2 < 32) ? kq + 2 : 31);  // last iter: redundant, unused
    fmaStep(xb, kq + 1);
  }

  float bb[8];
#pragma unroll
  for (int j = 0; j < 8; ++j) bb[j] = 0.f;
  if (bias) {
#pragma unroll
    for (int j = 0; j < 8; ++j) bb[j] = bias[c0 + j];
  }

  if (DO_ARGMAX) {
#pragma unroll
    for (int i = 0; i < 5; ++i) {
      float bv = acc[i][0] * scale + bb[0];
      int bc = c0;
#pragma unroll
      for (int j = 1; j < 8; ++j) {
        float v = acc[i][j] * scale + bb[j];
        if (v > bv) {
          bv = v;
          bc = c0 + j;
        }
      }
#pragma unroll
      for (int off = 1; off <= 8; off <<= 1) {
        float ov = __shfl_xor(bv, off, 64);
        int oc = __shfl_xor(bc, off, 64);
        if (ov > bv || (ov == bv && oc < bc)) {
          bv = ov;
          bc = oc;
        }
      }
      int gr = rbase + r0 + i;
      if (tc == 0 && gr < M) cls[gr] = bc;
    }
  } else {
#pragma unroll
    for (int i = 0; i < 5; ++i) {
      int gr = rbase + r0 + i;
      if (gr < M) {
        float4 v0, v1;
        v0.x = acc[i][0] * scale + bb[0];
        v0.y = acc[i][1] * scale + bb[1];
        v0.z = acc[i][2] * scale + bb[2];
        v0.w = acc[i][3] * scale + bb[3];
        v1.x = acc[i][4] * scale + bb[4];
        v1.y = acc[i][5] * scale + bb[5];
        v1.z = acc[i][6] * scale + bb[6];
        v1.w = acc[i][7] * scale + bb[7];
        *(float4*)&out[(long)gr * 128 + c0] = v0;
        *(float4*)&out[(long)gr * 128 + c0 + 4] = v1;
      }
    }
  }
}

// ---------------------------------------------------------------------------
// row norms (float2 per lane): first NN waves -> ||features[j]||,
// next NN -> ||transformed0[j]||
__global__ __launch_bounds__(256) void k_norms(const float* __restrict__ feat,
                                               const float* __restrict__ A,
                                               float* __restrict__ nf,
                                               float* __restrict__ nt0) {
  int w = blockIdx.x * 4 + (threadIdx.x >> 6);
  int lane = threadIdx.x & 63;
  if (w >= 2 * NN) return;
  const float* p = (w < NN) ? (feat + (long)w * 128) : (A + (long)(NN + (w - NN)) * 128);
  float2 v = *(const float2*)(p + lane * 2);
  float s = waveReduceSum(v.x * v.x + v.y * v.y);
  if (lane == 0) {
    float r = sqrtf(s);
    if (w < NN) nf[w] = r;
    else nt0[w - NN] = r;
  }
}

// ---------------------------------------------------------------------------
// cosine-sim replica selection. 32 lanes per edge (float4/lane), 2 edges per
// wave, 4 grid-strided iterations with 1-ahead prefetch -> 16 row-loads in
// flight per wave (vs 4). Reduce: 5-step shfl within each 32-lane half.
__global__ __launch_bounds__(256) void k_sim(const int* __restrict__ ei,
                                             const float* __restrict__ feat,
                                             const float* __restrict__ A,
                                             const float* __restrict__ nf,
                                             const float* __restrict__ nt0,
                                             int* __restrict__ bn) {
  const int t = threadIdx.x;
  const int lane = t & 31;
  const int half = (t >> 5) & 1;
  const int w = blockIdx.x * 4 + (t >> 6);  // wave id in [0, SIMW)

#define SIM_LOAD(I, E, DE, AV, B0, B1, B2, NA, NB0, NB1, NB2)              \
  {                                                                        \
    E = 2 * (w + (I)*SIMW) + half;                                         \
    DE = ei[NE + E];                                                       \
    int s_ = ei[E];                                                        \
    int j0_ = 3 * E;                                                       \
    if (j0_ >= NE) j0_ -= NE;                                              \
    if (j0_ >= NE) j0_ -= NE;                                              \
    int j1_ = j0_ + 1;                                                     \
    if (j1_ >= NE) j1_ -= NE;                                              \
    int j2_ = j0_ + 2;                                                     \
    if (j2_ >= NE) j2_ -= NE;                                              \
    int d0_ = ei[NE + j0_], d1_ = ei[NE + j1_], d2_ = ei[NE + j2_];        \
    AV = ((const float4*)(feat + (long)s_ * 128))[lane];                   \
    B0 = ((const float4*)(A + (long)(NN + d0_) * 128))[lane];              \
    B1 = ((const float4*)(A + (long)(NN + d1_) * 128))[lane];              \
    B2 = ((const float4*)(A + (long)(NN + d2_) * 128))[lane];              \
    NA = nf[s_];                                                           \
    NB0 = nt0[d0_];                                                        \
    NB1 = nt0[d1_];                                                        \
    NB2 = nt0[d2_];                                                        \
  }

  int ec, dec;
  float4 ac, b0c, b1c, b2c;
  float nac, nb0c, nb1c, nb2c;
  SIM_LOAD(0, ec, dec, ac, b0c, b1c, b2c, nac, nb0c, nb1c, nb2c);

#pragma unroll
  for (int i = 0; i < 4; ++i) {
    int en = 0, den = 0;
    float4 an, b0n, b1n, b2n;
    float nan2 = 0.f, nb0n = 0.f, nb1n = 0.f, nb2n = 0.f;
    if (i < 3) {
      SIM_LOAD(i + 1, en, den, an, b0n, b1n, b2n, nan2, nb0n, nb1n, nb2n);
    }
    float p0 = ac.x * b0c.x + ac.y * b0c.y + ac.z * b0c.z + ac.w * b0c.w;
    float p1 = ac.x * b1c.x + ac.y * b1c.y + ac.z * b1c.z + ac.w * b1c.w;
    float p2 = ac.x * b2c.x + ac.y * b2c.y + ac.z * b2c.z + ac.w * b2c.w;
#pragma unroll
    for (int off = 1; off <= 16; off <<= 1) {
      p0 += __shfl_xor(p0, off, 64);
      p1 += __shfl_xor(p1, off, 64);
      p2 += __shfl_xor(p2, off, 64);
    }
    float s0 = p0 / fmaxf(nac * nb0c, 1e-8f);
    float s1 = p1 / fmaxf(nac * nb1c, 1e-8f);
    float s2 = p2 / fmaxf(nac * nb2c, 1e-8f);
    int bk = 0;
    float bv = s0;
    if (s1 > bv) {
      bv = s1;
      bk = 1;
    }
    if (s2 > bv) {
      bv = s2;
      bk = 2;
    }
    if (lane == 0) bn[ec] = dec + bk * NN;
    if (i < 3) {
      ec = en;
      dec = den;
      ac = an;
      b0c = b0n;
      b1c = b1n;
      b2c = b2n;
      nac = nan2;
      nb0c = nb0n;
      nb1c = nb1n;
      nb2c = nb2n;
    }
  }
#undef SIM_LOAD
}

// ---------------------------------------------------------------------------
// CSR build: count -> scan(3 phases) -> fill. Shared by both GCN layers.
__global__ __launch_bounds__(256) void k_zero_count(int* __restrict__ count) {
  int v = blockIdx.x * 256 + threadIdx.x;
  if (v < NTOT) count[v] = 0;
}

__global__ __launch_bounds__(256) void k_count(const int* __restrict__ ei,
                                               const int* __restrict__ bn,
                                               int* __restrict__ count) {
  int e = blockIdx.x * 256 + threadIdx.x;
  if (e < NE) {
    atomicAdd(&count[ei[NE + e]], 1);
    atomicAdd(&count[bn[e]], 1);
  }
}

// dinv[v] = rsqrt(unstructured_count + structured (2 for v<N3, else 1))
__global__ __launch_bounds__(256) void k_dinv(const int* __restrict__ count,
                                              float* __restrict__ dinv) {
  int v = blockIdx.x * 256 + threadIdx.x;
  if (v < NTOT) {
    float deg = (float)count[v] + ((v < N3) ? 2.f : 1.f);
    dinv[v] = 1.f / sqrtf(deg);
  }
}

// scan phase 1: per-1024-block local exclusive scan + block sums
__global__ __launch_bounds__(256) void k_scan1(const int* __restrict__ count,
                                               int* __restrict__ start,
                                               int* __restrict__ bsum) {
  __shared__ int sh[256];
  const int b = blockIdx.x, t = threadIdx.x;
  const int base = b * 1024 + t * 4;
  int c[4];
  int s = 0;
#pragma unroll
  for (int k = 0; k < 4; ++k) {
    int idx = base + k;
    c[k] = (idx < NTOT) ? count[idx] : 0;
    s += c[k];
  }
  sh[t] = s;
  __syncthreads();
  for (int off = 1; off < 256; off <<= 1) {
    int v = (t >= off) ? sh[t - off] : 0;
    __syncthreads();
    sh[t] += v;
    __syncthreads();
  }
  if (t == 255) bsum[b] = sh[255];
  int run = sh[t] - s;  // exclusive prefix of this thread
#pragma unroll
  for (int k = 0; k < 4; ++k) {
    int idx = base + k;
    if (idx < NTOT) start[idx] = run;
    run += c[k];
  }
}

// scan phase 2: exclusive scan of NBLK1 block sums (single block)
__global__ __launch_bounds__(256) void k_scan2(int* __restrict__ bsum) {
  __shared__ int sh[256];
  const int t = threadIdx.x;
  int v = (t < NBLK1) ? bsum[t] : 0;
  sh[t] = v;
  __syncthreads();
  for (int off = 1; off < 256; off <<= 1) {
    int u = (t >= off) ? sh[t - off] : 0;
    __syncthreads();
    sh[t] += u;
    __syncthreads();
  }
  if (t < NBLK1) bsum[t] = sh[t] - v;
}

// scan phase 3: add block offsets; init cursor = start
__global__ __launch_bounds__(256) void k_scan3(int* __restrict__ start,
                                               const int* __restrict__ bsum,
                                               int* __restrict__ cursor) {
  int i = blockIdx.x * 256 + threadIdx.x;
  if (i < NTOT) {
    int v = start[i] + bsum[i >> 10];
    start[i] = v;
    cursor[i] = v;
  }
}

// fill CSR entries: (src, weight) packed in int2
__global__ __launch_bounds__(256) void k_fill(const int* __restrict__ ei,
                                              const int* __restrict__ bn,
                                              const float* __restrict__ dinv,
                                              int* __restrict__ cursor,
                                              int2* __restrict__ ent) {
  int g = blockIdx.x * 256 + threadIdx.x;
  if (g >= 2 * NE) return;
  int e = (g < NE) ? g : g - NE;
  int s = ei[e];
  int d = (g < NE) ? ei[NE + e] : bn[e];
  float w = dinv[s] * dinv[d];
  int pos = atomicAdd(&cursor[d], 1);
  ent[pos] = make_int2(s, __float_as_int(w));
}

// ---------------------------------------------------------------------------
// Fused GCN aggregate: out[v] = bias + selfloop + extra + sum_{CSR} w*xw[src].
// 32 lanes per row (float4/lane), 2 rows per wave, CSR loop with 1-ahead
// prefetch of entry + gathered row. No atomics; coalesced 512B writes.
__global__ __launch_bounds__(256) void k_agg(const int2* __restrict__ ent,
                                             const int* __restrict__ start,
                                             const int* __restrict__ end,
                                             const float* __restrict__ xw,
                                             const float* __restrict__ dinv,
                                             const float* __restrict__ bias,
                                             float* __restrict__ out) {
  const int t = threadIdx.x;
  const int lane = t & 31;
  const int v = blockIdx.x * 8 + (t >> 5);  // 8 rows per block, 2 per wave
  float dv = dinv[v];
  float4 xv = ((const float4*)(xw + (long)v * 128))[lane];
  float4 bb = ((const float4*)bias)[lane];
  float a0 = bb.x + dv * dv * xv.x;
  float a1 = bb.y + dv * dv * xv.y;
  float a2 = bb.z + dv * dv * xv.z;
  float a3 = bb.w + dv * dv * xv.w;
  if (v < NN) {
    a0 += dv * dv * xv.x;  // extra edge (j, j)
    a1 += dv * dv * xv.y;
    a2 += dv * dv * xv.z;
    a3 += dv * dv * xv.w;
  } else if (v < N3) {
    int j = (v < 2 * NN) ? v - NN : v - 2 * NN;
    float4 xj = ((const float4*)(xw + (long)j * 128))[lane];
    float w = dinv[j] * dv;
    a0 = fmaf(w, xj.x, a0);  // extra edge (j, i*NN + j)
    a1 = fmaf(w, xj.y, a1);
    a2 = fmaf(w, xj.z, a2);
    a3 = fmaf(w, xj.w, a3);
  }
  int i = start[v];
  const int i1 = end[v];
  if (i < i1) {
    int2 e0 = ent[i];
    float4 x0 = ((const float4*)(xw + (long)e0.x * 128))[lane];
    for (; i + 1 < i1; ++i) {
      int2 e1 = ent[i + 1];
      float4 x1 = ((const float4*)(xw + (long)e1.x * 128))[lane];
      float w0 = __int_as_float(e0.y);
      a0 = fmaf(w0, x0.x, a0);
      a1 = fmaf(w0, x0.y, a1);
      a2 = fmaf(w0, x0.z, a2);
      a3 = fmaf(w0, x0.w, a3);
      e0 = e1;
      x0 = x1;
    }
    float w0 = __int_as_float(e0.y);
    a0 = fmaf(w0, x0.x, a0);
    a1 = fmaf(w0, x0.y, a1);
    a2 = fmaf(w0, x0.z, a2);
    a3 = fmaf(w0, x0.w, a3);
  }
  ((float4*)(out + (long)v * 128))[lane] = make_float4(a0, a1, a2, a3);
}

__global__ __launch_bounds__(256) void k_zero_small(float* __restrict__ hyper,
                                                    int* __restrict__ hist) {
  int i = blockIdx.x * 256 + threadIdx.x;
  if (i < 128 * 128) hyper[i] = 0.f;
  if (i < 640) hist[i] = 0;
}

// vote histogram: hist[c][m] = #nodes whose count for class c is exactly m.
// LDS-accumulated per block (20 blocks x 1000 nodes), one flush per block.
#define HISTBLK 20
__global__ __launch_bounds__(256) void k_hist(const int* __restrict__ cls,
                                              int* __restrict__ hist) {
  __shared__ int sh[640];
  const int t = threadIdx.x;
  for (int i = t; i < 640; i += 256) sh[i] = 0;
  __syncthreads();
  const int per = NN / HISTBLK;  // 1000
  const int j0 = blockIdx.x * per;
  for (int j = j0 + t; j < j0 + per; j += 256) {
    int cc[4] = {cls[j], cls[NN + j], cls[2 * NN + j], cls[3 * NN + j]};
#pragma unroll
    for (int i = 0; i < 4; ++i) {
      bool first = true;
      int m = 0;
#pragma unroll
      for (int k = 0; k < 4; ++k) {
        if (cc[k] == cc[i]) {
          if (k < i) first = false;
          m++;
        }
      }
      if (first) atomicAdd(&sh[cc[i] * 5 + m], 1);
    }
  }
  __syncthreads();
  for (int i = t; i < 640; i += 256) {
    int v = sh[i];
    if (v) atomicAdd(&hist[i], v);
  }
}

// per-class softmax table over count values 0..4
__global__ void k_table(const int* __restrict__ hist, float* __restrict__ table) {
  int c = threadIdx.x;
  if (c >= 128) return;
  int cnt[5];
  int tot = 0;
  for (int v = 1; v <= 4; ++v) {
    cnt[v] = hist[c * 5 + v];
    tot += cnt[v];
  }
  cnt[0] = NN - tot;
  int m = 0;
  for (int v = 0; v <= 4; ++v)
    if (cnt[v] > 0) m = v;
  float ex[5];
  float denom = 0.f;
  for (int v = 0; v <= 4; ++v) {
    ex[v] = expf((float)(v - m));
    denom += (float)cnt[v] * ex[v];
  }
  for (int v = 0; v <= 4; ++v) table[c * 5 + v] = ex[v] / denom;
}

__global__ __launch_bounds__(256) void k_hwrite(const int* __restrict__ cls,
                                                const float* __restrict__ table,
                                                float* __restrict__ H) {
  int j = blockIdx.x * 2 + (threadIdx.x >> 7);
  int c = threadIdx.x & 127;
  if (j >= NN) return;
  int c0 = cls[j], c1 = cls[NN + j], c2 = cls[2 * NN + j], c3 = cls[3 * NN + j];
  int cnt = (c == c0) + (c == c1) + (c == c2) + (c == c3);
  H[(long)j * 128 + c] = table[c * 5 + cnt];
}

// ---------------------------------------------------------------------------
// hyper[c][d] = sum over nodes voting for class c of af2[j][d].
// LDS-accumulated: 250 blocks x 80 nodes.
#define HBLK 250
#define HPER 80
__global__ __launch_bounds__(256) void k_hyper(const int* __restrict__ cls,
                                               const float* __restrict__ af2,
                                               float* __restrict__ hyper) {
  __shared__ float acc[128 * 128];
  const int t = threadIdx.x;
  for (int i = t; i < 128 * 128; i += 256) acc[i] = 0.f;
  __syncthreads();
  const int j0 = blockIdx.x * HPER;
  const int j1 = j0 + HPER;  // NN == HBLK*HPER exactly
  const int d = t & 127;
  const int half = t >> 7;  // 0: slots {0,2}; 1: slots {1,3}
  float v = af2[(long)j0 * 128 + d];
  int c0 = cls[j0], c1 = cls[NN + j0], c2 = cls[2 * NN + j0], c3 = cls[3 * NN + j0];
  for (int j = j0; j < j1; ++j) {
    float vn = 0.f;
    int n0 = 0, n1 = 0, n2 = 0, n3 = 0;
    if (j + 1 < j1) {
      vn = af2[(long)(j + 1) * 128 + d];
      n0 = cls[j + 1];
      n1 = cls[NN + j + 1];
      n2 = cls[2 * NN + j + 1];
      n3 = cls[3 * NN + j + 1];
    }
    if (half == 0) {
      atomicAdd(&acc[c0 * 128 + d], v);  // slot 0 always first occurrence
      if (c2 != c0 && c2 != c1) atomicAdd(&acc[c2 * 128 + d], v);
    } else {
      if (c1 != c0) atomicAdd(&acc[c1 * 128 + d], v);
      if (c3 != c0 && c3 != c1 && c3 != c2) atomicAdd(&acc[c3 * 128 + d], v);
    }
    v = vn;
    c0 = n0;
    c1 = n1;
    c2 = n2;
    c3 = n3;
  }
  __syncthreads();
  for (int i = t; i < 128 * 128; i += 256) {
    float x = acc[i];
    if (x != 0.f) atomAddF(&hyper[i], x);
  }
}

// ---------------------------------------------------------------------------
extern "C" void kernel_launch(void* const* d_in, const int* in_sizes, int n_in,
                              void* d_out, int out_size, void* d_ws, size_t ws_size,
                              hipStream_t stream) {
  (void)in_sizes;
  (void)n_in;
  (void)out_size;
  (void)ws_size;
  const int* ei = (const int*)d_in[0];
  const float* feat = (const float*)d_in[1];
  const float* lin_W = (const float*)d_in[2];
  const float* lin_b = (const float*)d_in[3];
  const float* g1W = (const float*)d_in[4];
  const float* g1b = (const float*)d_in[5];
  const float* g2W = (const float*)d_in[6];
  const float* g2b = (const float*)d_in[7];
  const float* l1W = (const float*)d_in[8];
  const float* l1b = (const float*)d_in[9];

  float* out = (float*)d_out;
  float* H = out;
  float* hyper = out + (size_t)NN * 128;
  float* dots = hyper + 128 * 128;

  float* ws = (float*)d_ws;
  float* A = ws;                          // all_features [(T+1)*NN, 128]
  float* Cb = A + (size_t)NTOT * 128;     // h1 / af2 buffer
  float* Bb = dots;                       // xw buffer aliased onto dots
                                          // (dots written only by final GEMM)
  float* dinv = Cb + (size_t)NTOT * 128;  // [NTOT]
  float* nf = dinv + NTOT;                // feature norms [NN]
  float* nt0 = nf + NN;                   // transformed0 norms [NN]
  int* bn = (int*)(nt0 + NN);             // best_nodes [NE]
  int* cls = bn + NE;                     // classes [NTOT]
  int* hist = cls + NTOT;                 // [640]
  float* table = (float*)(hist + 640);    // [640]
  int* count = (int*)(table + 640);       // [NTOT]
  int* startA = count + NTOT;             // [NTOT]
  int* cursor = startA + NTOT;            // [NTOT]  (== end after fill)
  int* bsum = cursor + NTOT;              // [128]
  int2* ent = (int2*)(bsum + 128);        // [2*NE] CSR entries (src, weight)

  const float kScale = 0.08838834764831843f;  // 128^-0.5

  // 1. all_features rows [0,NN) = features
  k_copy_feat<<<(NN * 128 / 4 + 255) / 256, 256, 0, stream>>>(feat, A, NN * 128 / 4);
  // 2. transformed: per-replica linears -> rows [NN, 4*NN)  (20000 = 125*160)
  gemm128<0, 0, 0><<<dim3(125, 3), 512, 0, stream>>>(
      feat, lin_W, lin_b, A + (size_t)NN * 128, NN, 1.f, 128 * 128, 128,
      (long)NN * 128, nullptr);
  // 3. row norms
  k_norms<<<10000, 256, 0, stream>>>(feat, A, nf, nt0);
  // 4. cosine-sim replica pick (pipelined, 2 edges/wave, 4 iters/wave)
  k_zero_count<<<(NTOT + 255) / 256, 256, 0, stream>>>(count);
  k_sim<<<SIMW / 4, 256, 0, stream>>>(ei, feat, A, nf, nt0, bn);
  // 5. CSR build: count, dinv, scan, fill
  k_count<<<(NE + 255) / 256, 256, 0, stream>>>(ei, bn, count);
  k_dinv<<<(NTOT + 255) / 256, 256, 0, stream>>>(count, dinv);
  k_scan1<<<NBLK1, 256, 0, stream>>>(count, startA, bsum);
  k_scan2<<<1, 256, 0, stream>>>(bsum);
  k_scan3<<<(NTOT + 255) / 256, 256, 0, stream>>>(startA, bsum, cursor);
  k_fill<<<(2 * NE + 255) / 256, 256, 0, stream>>>(ei, bn, dinv, cursor, ent);
  // 6. GCN1: xw1 = relu(all_features) @ W1; fused aggregate -> h1 in Cb
  gemm128<1, 0, 0><<<dim3(NTOT / 160, 1), 512, 0, stream>>>(A, g1W, nullptr, Bb, NTOT,
                                                            1.f, 0, 0, 0, nullptr);
  k_agg<<<NTOT / 8, 256, 0, stream>>>(ent, startA, cursor, Bb, dinv, g1b, Cb);
  // 7. GCN2: xw2 = relu(h1) @ W2; fused aggregate -> af2 in Cb
  gemm128<1, 0, 0><<<dim3(NTOT / 160, 1), 512, 0, stream>>>(Cb, g2W, nullptr, Bb, NTOT,
                                                            1.f, 0, 0, 0, nullptr);
  k_agg<<<NTOT / 8, 256, 0, stream>>>(ent, startA, cursor, Bb, dinv, g2b, Cb);
  // 8. logits GEMM with fused per-row argmax -> classes (no logits store)
  gemm128<1, 0, 1><<<dim3(NTOT / 160, 1), 512, 0, stream>>>(Cb, l1W, l1b, nullptr,
                                                            NTOT, 1.f, 0, 0, 0, cls);
  // 9. zero hyper + hist
  k_zero_small<<<64, 256, 0, stream>>>(hyper, hist);
  // 10. vote histogram (LDS) -> per-class softmax table
  k_hist<<<HISTBLK, 256, 0, stream>>>(cls, hist);
  k_table<<<1, 128, 0, stream>>>(hist, table);
  // 11. H output (softmax over nodes, via count table)
  k_hwrite<<<NN / 2, 256, 0, stream>>>(cls, table, H);
  // 12. hyperedge features (LDS-accumulated)
  k_hyper<<<HBLK, 256, 0, stream>>>(cls, Cb, hyper);
  // 13. dots = all_features @ hyper^T * scale
  gemm128<0, 1, 0><<<dim3(NTOT / 160, 1), 512, 0, stream>>>(A, hyper, nullptr, dots,
                                                            NTOT, kScale, 0, 0, 0,
                                                            nullptr);
}

// Round 17
// 421.392 us; speedup vs baseline: 1.5458x; 1.0269x over previous
//
#include <hip/hip_runtime.h>
#include <math.h>

#define NN 20000
#define NE 160000
#define TT 3
#define DD 128
#define NTOT 80000   // (TT+1)*NN
#define N3 60000     // TT*NN
#define NBLK1 79     // ceil(NTOT/1024) for the scan
#define SIMW 20000   // k_sim waves (grid 5000 x 4 waves)

__device__ __forceinline__ float waveReduceSum(float v) {
#pragma unroll
  for (int off = 32; off >= 1; off >>= 1)
    v += __shfl_xor(v, off, 64);
  return v;
}

__device__ __forceinline__ void atomAddF(float* p, float v) {
  unsafeAtomicAdd(p, v);
}

// ---------------------------------------------------------------------------
// copy features into all_features rows [0, NN)
__global__ __launch_bounds__(256) void k_copy_feat(const float* __restrict__ src,
                                                   float* __restrict__ dst, int n4) {
  int i = blockIdx.x * 256 + threadIdx.x;
  if (i < n4) ((float4*)dst)[i] = ((const float4*)src)[i];
}

// ---------------------------------------------------------------------------
// [M,128] @ [128,128] GEMM — round-15 version (best measured: 52.4 us).
// 160x128 tile per block (500 blocks <= 512 concurrent -> single residency
// round). 512 threads, 5x8 per thread. W staged in LDS once (full K); X
// broadcast-read from global, once per block. Do NOT restructure the K-loop:
// r8/r9/r11/r16 all tried deeper source-level prefetch shapes and the
// allocator defeated every one (JIT loads, VGPR 56-72); this shape measured
// fastest.
template <int RELU_IN, int TRANS_W, int DO_ARGMAX>
__global__ __launch_bounds__(512, 3) void gemm128(const float* __restrict__ X,
                                                  const float* __restrict__ W,
                                                  const float* __restrict__ bias,
                                                  float* __restrict__ out, int M,
                                                  float scale, int wStride, int bStride,
                                                  long oStride, int* __restrict__ cls) {
  __shared__ float Ws[128 * 132];
  const int tid = threadIdx.x;
  const int rbase = blockIdx.x * 160;
  W += (long)blockIdx.y * wStride;
  if (bias) bias += (long)blockIdx.y * bStride;
  out += (long)blockIdx.y * oStride;

  // stage all of W into LDS (row kl, padded stride 132)
#pragma unroll
  for (int it = 0; it < 8; ++it) {
    int idx = (tid + it * 512) * 4;
    int kl = idx >> 7, c = idx & 127;
    float4 w;
    if (!TRANS_W) {
      w = *(const float4*)&W[kl * 128 + c];
    } else {
      w.x = W[(c + 0) * 128 + kl];
      w.y = W[(c + 1) * 128 + kl];
      w.z = W[(c + 2) * 128 + kl];
      w.w = W[(c + 3) * 128 + kl];
    }
    *(float4*)&Ws[kl * 132 + c] = w;
  }

  const int tc = tid & 15, tr = tid >> 4;  // tr in [0,32)
  const int c0 = tc * 8, r0 = tr * 5;

  const float4* xrow[5];
#pragma unroll
  for (int i = 0; i < 5; ++i) {
    int gr = rbase + r0 + i;
    int gc = (gr < M) ? gr : 0;  // clamp tail rows (stores are guarded)
    xrow[i] = (const float4*)(X + (long)gc * 128);
  }

  float acc[5][8];
#pragma unroll
  for (int i = 0; i < 5; ++i)
#pragma unroll
    for (int j = 0; j < 8; ++j) acc[i][j] = 0.f;

  float4 xc[5], xn[5];
#pragma unroll
  for (int i = 0; i < 5; ++i) {
    float4 v = xrow[i][0];
    if (RELU_IN) {
      v.x = fmaxf(v.x, 0.f);
      v.y = fmaxf(v.y, 0.f);
      v.z = fmaxf(v.z, 0.f);
      v.w = fmaxf(v.w, 0.f);
    }
    xc[i] = v;
  }

  __syncthreads();  // W staged

  for (int kq = 0; kq < 32; ++kq) {
    if (kq < 31) {
#pragma unroll
      for (int i = 0; i < 5; ++i) {
        float4 v = xrow[i][kq + 1];
        if (RELU_IN) {
          v.x = fmaxf(v.x, 0.f);
          v.y = fmaxf(v.y, 0.f);
          v.z = fmaxf(v.z, 0.f);
          v.w = fmaxf(v.w, 0.f);
        }
        xn[i] = v;
      }
    }
    const int klb = kq * 4;
#pragma unroll
    for (int k = 0; k < 4; ++k) {
      const int kl = klb + k;
      const float4 wa = *(const float4*)&Ws[kl * 132 + c0];
      const float4 wb = *(const float4*)&Ws[kl * 132 + c0 + 4];
      float av[5];
#pragma unroll
      for (int i = 0; i < 5; ++i)
        av[i] = (k == 0) ? xc[i].x : (k == 1) ? xc[i].y : (k == 2) ? xc[i].z : xc[i].w;
      const float bv[8] = {wa.x, wa.y, wa.z, wa.w, wb.x, wb.y, wb.z, wb.w};
#pragma unroll
      for (int i = 0; i < 5; ++i)
#pragma unroll
        for (int j = 0; j < 8; ++j) acc[i][j] = fmaf(av[i], bv[j], acc[i][j]);
    }
    if (kq < 31) {
#pragma unroll
      for (int i = 0; i < 5; ++i) xc[i] = xn[i];
    }
  }

  float bb[8];
#pragma unroll
  for (int j = 0; j < 8; ++j) bb[j] = 0.f;
  if (bias) {
#pragma unroll
    for (int j = 0; j < 8; ++j) bb[j] = bias[c0 + j];
  }

  if (DO_ARGMAX) {
#pragma unroll
    for (int i = 0; i < 5; ++i) {
      float bv = acc[i][0] * scale + bb[0];
      int bc = c0;
#pragma unroll
      for (int j = 1; j < 8; ++j) {
        float v = acc[i][j] * scale + bb[j];
        if (v > bv) {
          bv = v;
          bc = c0 + j;
        }
      }
#pragma unroll
      for (int off = 1; off <= 8; off <<= 1) {
        float ov = __shfl_xor(bv, off, 64);
        int oc = __shfl_xor(bc, off, 64);
        if (ov > bv || (ov == bv && oc < bc)) {
          bv = ov;
          bc = oc;
        }
      }
      int gr = rbase + r0 + i;
      if (tc == 0 && gr < M) cls[gr] = bc;
    }
  } else {
#pragma unroll
    for (int i = 0; i < 5; ++i) {
      int gr = rbase + r0 + i;
      if (gr < M) {
        float4 v0, v1;
        v0.x = acc[i][0] * scale + bb[0];
        v0.y = acc[i][1] * scale + bb[1];
        v0.z = acc[i][2] * scale + bb[2];
        v0.w = acc[i][3] * scale + bb[3];
        v1.x = acc[i][4] * scale + bb[4];
        v1.y = acc[i][5] * scale + bb[5];
        v1.z = acc[i][6] * scale + bb[6];
        v1.w = acc[i][7] * scale + bb[7];
        *(float4*)&out[(long)gr * 128 + c0] = v0;
        *(float4*)&out[(long)gr * 128 + c0 + 4] = v1;
      }
    }
  }
}

// ---------------------------------------------------------------------------
// row norms (float2 per lane): first NN waves -> ||features[j]||,
// next NN -> ||transformed0[j]||
__global__ __launch_bounds__(256) void k_norms(const float* __restrict__ feat,
                                               const float* __restrict__ A,
                                               float* __restrict__ nf,
                                               float* __restrict__ nt0) {
  int w = blockIdx.x * 4 + (threadIdx.x >> 6);
  int lane = threadIdx.x & 63;
  if (w >= 2 * NN) return;
  const float* p = (w < NN) ? (feat + (long)w * 128) : (A + (long)(NN + (w - NN)) * 128);
  float2 v = *(const float2*)(p + lane * 2);
  float s = waveReduceSum(v.x * v.x + v.y * v.y);
  if (lane == 0) {
    float r = sqrtf(s);
    if (w < NN) nf[w] = r;
    else nt0[w - NN] = r;
  }
}

// ---------------------------------------------------------------------------
// cosine-sim replica selection. 32 lanes per edge (float4/lane), 2 edges per
// wave, 4 grid-strided iterations with 1-ahead prefetch -> 16 row-loads in
// flight per wave (vs 4). Reduce: 5-step shfl within each 32-lane half.
__global__ __launch_bounds__(256) void k_sim(const int* __restrict__ ei,
                                             const float* __restrict__ feat,
                                             const float* __restrict__ A,
                                             const float* __restrict__ nf,
                                             const float* __restrict__ nt0,
                                             int* __restrict__ bn) {
  const int t = threadIdx.x;
  const int lane = t & 31;
  const int half = (t >> 5) & 1;
  const int w = blockIdx.x * 4 + (t >> 6);  // wave id in [0, SIMW)

#define SIM_LOAD(I, E, DE, AV, B0, B1, B2, NA, NB0, NB1, NB2)              \
  {                                                                        \
    E = 2 * (w + (I)*SIMW) + half;                                         \
    DE = ei[NE + E];                                                       \
    int s_ = ei[E];                                                        \
    int j0_ = 3 * E;                                                       \
    if (j0_ >= NE) j0_ -= NE;                                              \
    if (j0_ >= NE) j0_ -= NE;                                              \
    int j1_ = j0_ + 1;                                                     \
    if (j1_ >= NE) j1_ -= NE;                                              \
    int j2_ = j0_ + 2;                                                     \
    if (j2_ >= NE) j2_ -= NE;                                              \
    int d0_ = ei[NE + j0_], d1_ = ei[NE + j1_], d2_ = ei[NE + j2_];        \
    AV = ((const float4*)(feat + (long)s_ * 128))[lane];                   \
    B0 = ((const float4*)(A + (long)(NN + d0_) * 128))[lane];              \
    B1 = ((const float4*)(A + (long)(NN + d1_) * 128))[lane];              \
    B2 = ((const float4*)(A + (long)(NN + d2_) * 128))[lane];              \
    NA = nf[s_];                                                           \
    NB0 = nt0[d0_];                                                        \
    NB1 = nt0[d1_];                                                        \
    NB2 = nt0[d2_];                                                        \
  }

  int ec, dec;
  float4 ac, b0c, b1c, b2c;
  float nac, nb0c, nb1c, nb2c;
  SIM_LOAD(0, ec, dec, ac, b0c, b1c, b2c, nac, nb0c, nb1c, nb2c);

#pragma unroll
  for (int i = 0; i < 4; ++i) {
    int en = 0, den = 0;
    float4 an, b0n, b1n, b2n;
    float nan2 = 0.f, nb0n = 0.f, nb1n = 0.f, nb2n = 0.f;
    if (i < 3) {
      SIM_LOAD(i + 1, en, den, an, b0n, b1n, b2n, nan2, nb0n, nb1n, nb2n);
    }
    float p0 = ac.x * b0c.x + ac.y * b0c.y + ac.z * b0c.z + ac.w * b0c.w;
    float p1 = ac.x * b1c.x + ac.y * b1c.y + ac.z * b1c.z + ac.w * b1c.w;
    float p2 = ac.x * b2c.x + ac.y * b2c.y + ac.z * b2c.z + ac.w * b2c.w;
#pragma unroll
    for (int off = 1; off <= 16; off <<= 1) {
      p0 += __shfl_xor(p0, off, 64);
      p1 += __shfl_xor(p1, off, 64);
      p2 += __shfl_xor(p2, off, 64);
    }
    float s0 = p0 / fmaxf(nac * nb0c, 1e-8f);
    float s1 = p1 / fmaxf(nac * nb1c, 1e-8f);
    float s2 = p2 / fmaxf(nac * nb2c, 1e-8f);
    int bk = 0;
    float bv = s0;
    if (s1 > bv) {
      bv = s1;
      bk = 1;
    }
    if (s2 > bv) {
      bv = s2;
      bk = 2;
    }
    if (lane == 0) bn[ec] = dec + bk * NN;
    if (i < 3) {
      ec = en;
      dec = den;
      ac = an;
      b0c = b0n;
      b1c = b1n;
      b2c = b2n;
      nac = nan2;
      nb0c = nb0n;
      nb1c = nb1n;
      nb2c = nb2n;
    }
  }
#undef SIM_LOAD
}

// ---------------------------------------------------------------------------
// CSR build: count -> scan(3 phases) -> fill. Shared by both GCN layers.
__global__ __launch_bounds__(256) void k_zero_count(int* __restrict__ count) {
  int v = blockIdx.x * 256 + threadIdx.x;
  if (v < NTOT) count[v] = 0;
}

__global__ __launch_bounds__(256) void k_count(const int* __restrict__ ei,
                                               const int* __restrict__ bn,
                                               int* __restrict__ count) {
  int e = blockIdx.x * 256 + threadIdx.x;
  if (e < NE) {
    atomicAdd(&count[ei[NE + e]], 1);
    atomicAdd(&count[bn[e]], 1);
  }
}

// dinv[v] = rsqrt(unstructured_count + structured (2 for v<N3, else 1))
__global__ __launch_bounds__(256) void k_dinv(const int* __restrict__ count,
                                              float* __restrict__ dinv) {
  int v = blockIdx.x * 256 + threadIdx.x;
  if (v < NTOT) {
    float deg = (float)count[v] + ((v < N3) ? 2.f : 1.f);
    dinv[v] = 1.f / sqrtf(deg);
  }
}

// scan phase 1: per-1024-block local exclusive scan + block sums
__global__ __launch_bounds__(256) void k_scan1(const int* __restrict__ count,
                                               int* __restrict__ start,
                                               int* __restrict__ bsum) {
  __shared__ int sh[256];
  const int b = blockIdx.x, t = threadIdx.x;
  const int base = b * 1024 + t * 4;
  int c[4];
  int s = 0;
#pragma unroll
  for (int k = 0; k < 4; ++k) {
    int idx = base + k;
    c[k] = (idx < NTOT) ? count[idx] : 0;
    s += c[k];
  }
  sh[t] = s;
  __syncthreads();
  for (int off = 1; off < 256; off <<= 1) {
    int v = (t >= off) ? sh[t - off] : 0;
    __syncthreads();
    sh[t] += v;
    __syncthreads();
  }
  if (t == 255) bsum[b] = sh[255];
  int run = sh[t] - s;  // exclusive prefix of this thread
#pragma unroll
  for (int k = 0; k < 4; ++k) {
    int idx = base + k;
    if (idx < NTOT) start[idx] = run;
    run += c[k];
  }
}

// scan phase 2: exclusive scan of NBLK1 block sums (single block)
__global__ __launch_bounds__(256) void k_scan2(int* __restrict__ bsum) {
  __shared__ int sh[256];
  const int t = threadIdx.x;
  int v = (t < NBLK1) ? bsum[t] : 0;
  sh[t] = v;
  __syncthreads();
  for (int off = 1; off < 256; off <<= 1) {
    int u = (t >= off) ? sh[t - off] : 0;
    __syncthreads();
    sh[t] += u;
    __syncthreads();
  }
  if (t < NBLK1) bsum[t] = sh[t] - v;
}

// scan phase 3: add block offsets; init cursor = start
__global__ __launch_bounds__(256) void k_scan3(int* __restrict__ start,
                                               const int* __restrict__ bsum,
                                               int* __restrict__ cursor) {
  int i = blockIdx.x * 256 + threadIdx.x;
  if (i < NTOT) {
    int v = start[i] + bsum[i >> 10];
    start[i] = v;
    cursor[i] = v;
  }
}

// fill CSR entries: (src, weight) packed in int2
__global__ __launch_bounds__(256) void k_fill(const int* __restrict__ ei,
                                              const int* __restrict__ bn,
                                              const float* __restrict__ dinv,
                                              int* __restrict__ cursor,
                                              int2* __restrict__ ent) {
  int g = blockIdx.x * 256 + threadIdx.x;
  if (g >= 2 * NE) return;
  int e = (g < NE) ? g : g - NE;
  int s = ei[e];
  int d = (g < NE) ? ei[NE + e] : bn[e];
  float w = dinv[s] * dinv[d];
  int pos = atomicAdd(&cursor[d], 1);
  ent[pos] = make_int2(s, __float_as_int(w));
}

// ---------------------------------------------------------------------------
// Fused GCN aggregate: out[v] = bias + selfloop + extra + sum_{CSR} w*xw[src].
// 32 lanes per row (float4/lane), 2 rows per wave, CSR loop with 1-ahead
// prefetch of entry + gathered row. No atomics; coalesced 512B writes.
__global__ __launch_bounds__(256) void k_agg(const int2* __restrict__ ent,
                                             const int* __restrict__ start,
                                             const int* __restrict__ end,
                                             const float* __restrict__ xw,
                                             const float* __restrict__ dinv,
                                             const float* __restrict__ bias,
                                             float* __restrict__ out) {
  const int t = threadIdx.x;
  const int lane = t & 31;
  const int v = blockIdx.x * 8 + (t >> 5);  // 8 rows per block, 2 per wave
  float dv = dinv[v];
  float4 xv = ((const float4*)(xw + (long)v * 128))[lane];
  float4 bb = ((const float4*)bias)[lane];
  float a0 = bb.x + dv * dv * xv.x;
  float a1 = bb.y + dv * dv * xv.y;
  float a2 = bb.z + dv * dv * xv.z;
  float a3 = bb.w + dv * dv * xv.w;
  if (v < NN) {
    a0 += dv * dv * xv.x;  // extra edge (j, j)
    a1 += dv * dv * xv.y;
    a2 += dv * dv * xv.z;
    a3 += dv * dv * xv.w;
  } else if (v < N3) {
    int j = (v < 2 * NN) ? v - NN : v - 2 * NN;
    float4 xj = ((const float4*)(xw + (long)j * 128))[lane];
    float w = dinv[j] * dv;
    a0 = fmaf(w, xj.x, a0);  // extra edge (j, i*NN + j)
    a1 = fmaf(w, xj.y, a1);
    a2 = fmaf(w, xj.z, a2);
    a3 = fmaf(w, xj.w, a3);
  }
  int i = start[v];
  const int i1 = end[v];
  if (i < i1) {
    int2 e0 = ent[i];
    float4 x0 = ((const float4*)(xw + (long)e0.x * 128))[lane];
    for (; i + 1 < i1; ++i) {
      int2 e1 = ent[i + 1];
      float4 x1 = ((const float4*)(xw + (long)e1.x * 128))[lane];
      float w0 = __int_as_float(e0.y);
      a0 = fmaf(w0, x0.x, a0);
      a1 = fmaf(w0, x0.y, a1);
      a2 = fmaf(w0, x0.z, a2);
      a3 = fmaf(w0, x0.w, a3);
      e0 = e1;
      x0 = x1;
    }
    float w0 = __int_as_float(e0.y);
    a0 = fmaf(w0, x0.x, a0);
    a1 = fmaf(w0, x0.y, a1);
    a2 = fmaf(w0, x0.z, a2);
    a3 = fmaf(w0, x0.w, a3);
  }
  ((float4*)(out + (long)v * 128))[lane] = make_float4(a0, a1, a2, a3);
}

__global__ __launch_bounds__(256) void k_zero_small(float* __restrict__ hyper,
                                                    int* __restrict__ hist) {
  int i = blockIdx.x * 256 + threadIdx.x;
  if (i < 128 * 128) hyper[i] = 0.f;
  if (i < 640) hist[i] = 0;
}

// vote histogram: hist[c][m] = #nodes whose count for class c is exactly m.
// LDS-accumulated per block (20 blocks x 1000 nodes), one flush per block.
#define HISTBLK 20
__global__ __launch_bounds__(256) void k_hist(const int* __restrict__ cls,
                                              int* __restrict__ hist) {
  __shared__ int sh[640];
  const int t = threadIdx.x;
  for (int i = t; i < 640; i += 256) sh[i] = 0;
  __syncthreads();
  const int per = NN / HISTBLK;  // 1000
  const int j0 = blockIdx.x * per;
  for (int j = j0 + t; j < j0 + per; j += 256) {
    int cc[4] = {cls[j], cls[NN + j], cls[2 * NN + j], cls[3 * NN + j]};
#pragma unroll
    for (int i = 0; i < 4; ++i) {
      bool first = true;
      int m = 0;
#pragma unroll
      for (int k = 0; k < 4; ++k) {
        if (cc[k] == cc[i]) {
          if (k < i) first = false;
          m++;
        }
      }
      if (first) atomicAdd(&sh[cc[i] * 5 + m], 1);
    }
  }
  __syncthreads();
  for (int i = t; i < 640; i += 256) {
    int v = sh[i];
    if (v) atomicAdd(&hist[i], v);
  }
}

// per-class softmax table over count values 0..4
__global__ void k_table(const int* __restrict__ hist, float* __restrict__ table) {
  int c = threadIdx.x;
  if (c >= 128) return;
  int cnt[5];
  int tot = 0;
  for (int v = 1; v <= 4; ++v) {
    cnt[v] = hist[c * 5 + v];
    tot += cnt[v];
  }
  cnt[0] = NN - tot;
  int m = 0;
  for (int v = 0; v <= 4; ++v)
    if (cnt[v] > 0) m = v;
  float ex[5];
  float denom = 0.f;
  for (int v = 0; v <= 4; ++v) {
    ex[v] = expf((float)(v - m));
    denom += (float)cnt[v] * ex[v];
  }
  for (int v = 0; v <= 4; ++v) table[c * 5 + v] = ex[v] / denom;
}

__global__ __launch_bounds__(256) void k_hwrite(const int* __restrict__ cls,
                                                const float* __restrict__ table,
                                                float* __restrict__ H) {
  int j = blockIdx.x * 2 + (threadIdx.x >> 7);
  int c = threadIdx.x & 127;
  if (j >= NN) return;
  int c0 = cls[j], c1 = cls[NN + j], c2 = cls[2 * NN + j], c3 = cls[3 * NN + j];
  int cnt = (c == c0) + (c == c1) + (c == c2) + (c == c3);
  H[(long)j * 128 + c] = table[c * 5 + cnt];
}

// ---------------------------------------------------------------------------
// hyper[c][d] = sum over nodes voting for class c of af2[j][d].
// LDS-accumulated: 250 blocks x 80 nodes.
#define HBLK 250
#define HPER 80
__global__ __launch_bounds__(256) void k_hyper(const int* __restrict__ cls,
                                               const float* __restrict__ af2,
                                               float* __restrict__ hyper) {
  __shared__ float acc[128 * 128];
  const int t = threadIdx.x;
  for (int i = t; i < 128 * 128; i += 256) acc[i] = 0.f;
  __syncthreads();
  const int j0 = blockIdx.x * HPER;
  const int j1 = j0 + HPER;  // NN == HBLK*HPER exactly
  const int d = t & 127;
  const int half = t >> 7;  // 0: slots {0,2}; 1: slots {1,3}
  float v = af2[(long)j0 * 128 + d];
  int c0 = cls[j0], c1 = cls[NN + j0], c2 = cls[2 * NN + j0], c3 = cls[3 * NN + j0];
  for (int j = j0; j < j1; ++j) {
    float vn = 0.f;
    int n0 = 0, n1 = 0, n2 = 0, n3 = 0;
    if (j + 1 < j1) {
      vn = af2[(long)(j + 1) * 128 + d];
      n0 = cls[j + 1];
      n1 = cls[NN + j + 1];
      n2 = cls[2 * NN + j + 1];
      n3 = cls[3 * NN + j + 1];
    }
    if (half == 0) {
      atomicAdd(&acc[c0 * 128 + d], v);  // slot 0 always first occurrence
      if (c2 != c0 && c2 != c1) atomicAdd(&acc[c2 * 128 + d], v);
    } else {
      if (c1 != c0) atomicAdd(&acc[c1 * 128 + d], v);
      if (c3 != c0 && c3 != c1 && c3 != c2) atomicAdd(&acc[c3 * 128 + d], v);
    }
    v = vn;
    c0 = n0;
    c1 = n1;
    c2 = n2;
    c3 = n3;
  }
  __syncthreads();
  for (int i = t; i < 128 * 128; i += 256) {
    float x = acc[i];
    if (x != 0.f) atomAddF(&hyper[i], x);
  }
}

// ---------------------------------------------------------------------------
extern "C" void kernel_launch(void* const* d_in, const int* in_sizes, int n_in,
                              void* d_out, int out_size, void* d_ws, size_t ws_size,
                              hipStream_t stream) {
  (void)in_sizes;
  (void)n_in;
  (void)out_size;
  (void)ws_size;
  const int* ei = (const int*)d_in[0];
  const float* feat = (const float*)d_in[1];
  const float* lin_W = (const float*)d_in[2];
  const float* lin_b = (const float*)d_in[3];
  const float* g1W = (const float*)d_in[4];
  const float* g1b = (const float*)d_in[5];
  const float* g2W = (const float*)d_in[6];
  const float* g2b = (const float*)d_in[7];
  const float* l1W = (const float*)d_in[8];
  const float* l1b = (const float*)d_in[9];

  float* out = (float*)d_out;
  float* H = out;
  float* hyper = out + (size_t)NN * 128;
  float* dots = hyper + 128 * 128;

  float* ws = (float*)d_ws;
  float* A = ws;                          // all_features [(T+1)*NN, 128]
  float* Cb = A + (size_t)NTOT * 128;     // h1 / af2 buffer
  float* Bb = dots;                       // xw buffer aliased onto dots
                                          // (dots written only by final GEMM)
  float* dinv = Cb + (size_t)NTOT * 128;  // [NTOT]
  float* nf = dinv + NTOT;                // feature norms [NN]
  float* nt0 = nf + NN;                   // transformed0 norms [NN]
  int* bn = (int*)(nt0 + NN);             // best_nodes [NE]
  int* cls = bn + NE;                     // classes [NTOT]
  int* hist = cls + NTOT;                 // [640]
  float* table = (float*)(hist + 640);    // [640]
  int* count = (int*)(table + 640);       // [NTOT]
  int* startA = count + NTOT;             // [NTOT]
  int* cursor = startA + NTOT;            // [NTOT]  (== end after fill)
  int* bsum = cursor + NTOT;              // [128]
  int2* ent = (int2*)(bsum + 128);        // [2*NE] CSR entries (src, weight)

  const float kScale = 0.08838834764831843f;  // 128^-0.5

  // 1. all_features rows [0,NN) = features
  k_copy_feat<<<(NN * 128 / 4 + 255) / 256, 256, 0, stream>>>(feat, A, NN * 128 / 4);
  // 2. transformed: per-replica linears -> rows [NN, 4*NN)  (20000 = 125*160)
  gemm128<0, 0, 0><<<dim3(125, 3), 512, 0, stream>>>(
      feat, lin_W, lin_b, A + (size_t)NN * 128, NN, 1.f, 128 * 128, 128,
      (long)NN * 128, nullptr);
  // 3. row norms
  k_norms<<<10000, 256, 0, stream>>>(feat, A, nf, nt0);
  // 4. cosine-sim replica pick (pipelined, 2 edges/wave, 4 iters/wave)
  k_zero_count<<<(NTOT + 255) / 256, 256, 0, stream>>>(count);
  k_sim<<<SIMW / 4, 256, 0, stream>>>(ei, feat, A, nf, nt0, bn);
  // 5. CSR build: count, dinv, scan, fill
  k_count<<<(NE + 255) / 256, 256, 0, stream>>>(ei, bn, count);
  k_dinv<<<(NTOT + 255) / 256, 256, 0, stream>>>(count, dinv);
  k_scan1<<<NBLK1, 256, 0, stream>>>(count, startA, bsum);
  k_scan2<<<1, 256, 0, stream>>>(bsum);
  k_scan3<<<(NTOT + 255) / 256, 256, 0, stream>>>(startA, bsum, cursor);
  k_fill<<<(2 * NE + 255) / 256, 256, 0, stream>>>(ei, bn, dinv, cursor, ent);
  // 6. GCN1: xw1 = relu(all_features) @ W1; fused aggregate -> h1 in Cb
  gemm128<1, 0, 0><<<dim3(NTOT / 160, 1), 512, 0, stream>>>(A, g1W, nullptr, Bb, NTOT,
                                                            1.f, 0, 0, 0, nullptr);
  k_agg<<<NTOT / 8, 256, 0, stream>>>(ent, startA, cursor, Bb, dinv, g1b, Cb);
  // 7. GCN2: xw2 = relu(h1) @ W2; fused aggregate -> af2 in Cb
  gemm128<1, 0, 0><<<dim3(NTOT / 160, 1), 512, 0, stream>>>(Cb, g2W, nullptr, Bb, NTOT,
                                                            1.f, 0, 0, 0, nullptr);
  k_agg<<<NTOT / 8, 256, 0, stream>>>(ent, startA, cursor, Bb, dinv, g2b, Cb);
  // 8. logits GEMM with fused per-row argmax -> classes (no logits store)
  gemm128<1, 0, 1><<<dim3(NTOT / 160, 1), 512, 0, stream>>>(Cb, l1W, l1b, nullptr,
                                                            NTOT, 1.f, 0, 0, 0, cls);
  // 9. zero hyper + hist
  k_zero_small<<<64, 256, 0, stream>>>(hyper, hist);
  // 10. vote histogram (LDS) -> per-class softmax table
  k_hist<<<HISTBLK, 256, 0, stream>>>(cls, hist);
  k_table<<<1, 128, 0, stream>>>(hist, table);
  // 11. H output (softmax over nodes, via count table)
  k_hwrite<<<NN / 2, 256, 0, stream>>>(cls, table, H);
  // 12. hyperedge features (LDS-accumulated)
  k_hyper<<<HBLK, 256, 0, stream>>>(cls, Cb, hyper);
  // 13. dots = all_features @ hyper^T * scale
  gemm128<0, 1, 0><<<dim3(NTOT / 160, 1), 512, 0, stream>>>(A, hyper, nullptr, dots,
                                                            NTOT, kScale, 0, 0, 0,
                                                            nullptr);
}

// Round 20
// 417.611 us; speedup vs baseline: 1.5598x; 1.0091x over previous
//
#include <hip/hip_runtime.h>
#include <math.h>

#define NN 20000
#define NE 160000
#define TT 3
#define DD 128
#define NTOT 80000   // (TT+1)*NN
#define N3 60000     // TT*NN
#define NBLK1 79     // ceil(NTOT/1024) for the scan
#define SIMW 20000   // k_sim waves (grid 5000 x 4 waves)

__device__ __forceinline__ float waveReduceSum(float v) {
#pragma unroll
  for (int off = 32; off >= 1; off >>= 1)
    v += __shfl_xor(v, off, 64);
  return v;
}

__device__ __forceinline__ void atomAddF(float* p, float v) {
  unsafeAtomicAdd(p, v);
}

// ---------------------------------------------------------------------------
// copy features into all_features rows [0, NN)
__global__ __launch_bounds__(256) void k_copy_feat(const float* __restrict__ src,
                                                   float* __restrict__ dst, int n4) {
  int i = blockIdx.x * 256 + threadIdx.x;
  if (i < n4) ((float4*)dst)[i] = ((const float4*)src)[i];
}

// ---------------------------------------------------------------------------
// [M,128] @ [128,128] GEMM — r15 structure, split-column mapping.
// 160x128 tile per block, 512 threads, 5 rows x 8 cols per thread. W staged
// in LDS once (full K); X broadcast-read from global, once per block.
// Column mapping: thread owns cols {tc*4..+3} and {64+tc*4..+3} (NOT
// contiguous tc*8): W-LDS reads across 16 tc lanes are then 16B apart ->
// 2-way bank aliasing (free) instead of 32B apart -> 4-way conflict
// (r17 counter: 4.1M conflict cycles/dispatch).
template <int RELU_IN, int TRANS_W, int DO_ARGMAX>
__global__ __launch_bounds__(512, 3) void gemm128(const float* __restrict__ X,
                                                  const float* __restrict__ W,
                                                  const float* __restrict__ bias,
                                                  float* __restrict__ out, int M,
                                                  float scale, int wStride, int bStride,
                                                  long oStride, int* __restrict__ cls) {
  __shared__ float Ws[128 * 132];
  const int tid = threadIdx.x;
  const int rbase = blockIdx.x * 160;
  W += (long)blockIdx.y * wStride;
  if (bias) bias += (long)blockIdx.y * bStride;
  out += (long)blockIdx.y * oStride;

  // stage all of W into LDS (row kl, padded stride 132)
#pragma unroll
  for (int it = 0; it < 8; ++it) {
    int idx = (tid + it * 512) * 4;
    int kl = idx >> 7, c = idx & 127;
    float4 w;
    if (!TRANS_W) {
      w = *(const float4*)&W[kl * 128 + c];
    } else {
      w.x = W[(c + 0) * 128 + kl];
      w.y = W[(c + 1) * 128 + kl];
      w.z = W[(c + 2) * 128 + kl];
      w.w = W[(c + 3) * 128 + kl];
    }
    *(float4*)&Ws[kl * 132 + c] = w;
  }

  const int tc = tid & 15, tr = tid >> 4;  // tr in [0,32)
  const int c0a = tc * 4, c0b = 64 + tc * 4;  // two 4-col groups per thread
  const int r0 = tr * 5;

  const float4* xrow[5];
#pragma unroll
  for (int i = 0; i < 5; ++i) {
    int gr = rbase + r0 + i;
    int gc = (gr < M) ? gr : 0;  // clamp tail rows (stores are guarded)
    xrow[i] = (const float4*)(X + (long)gc * 128);
  }

  float acc[5][8];
#pragma unroll
  for (int i = 0; i < 5; ++i)
#pragma unroll
    for (int j = 0; j < 8; ++j) acc[i][j] = 0.f;

  float4 xc[5], xn[5];
#pragma unroll
  for (int i = 0; i < 5; ++i) {
    float4 v = xrow[i][0];
    if (RELU_IN) {
      v.x = fmaxf(v.x, 0.f);
      v.y = fmaxf(v.y, 0.f);
      v.z = fmaxf(v.z, 0.f);
      v.w = fmaxf(v.w, 0.f);
    }
    xc[i] = v;
  }

  __syncthreads();  // W staged

  for (int kq = 0; kq < 32; ++kq) {
    if (kq < 31) {
#pragma unroll
      for (int i = 0; i < 5; ++i) {
        float4 v = xrow[i][kq + 1];
        if (RELU_IN) {
          v.x = fmaxf(v.x, 0.f);
          v.y = fmaxf(v.y, 0.f);
          v.z = fmaxf(v.z, 0.f);
          v.w = fmaxf(v.w, 0.f);
        }
        xn[i] = v;
      }
    }
    const int klb = kq * 4;
#pragma unroll
    for (int k = 0; k < 4; ++k) {
      const int kl = klb + k;
      const float4 wa = *(const float4*)&Ws[kl * 132 + c0a];
      const float4 wb = *(const float4*)&Ws[kl * 132 + c0b];
      float av[5];
#pragma unroll
      for (int i = 0; i < 5; ++i)
        av[i] = (k == 0) ? xc[i].x : (k == 1) ? xc[i].y : (k == 2) ? xc[i].z : xc[i].w;
      const float bv[8] = {wa.x, wa.y, wa.z, wa.w, wb.x, wb.y, wb.z, wb.w};
#pragma unroll
      for (int i = 0; i < 5; ++i)
#pragma unroll
        for (int j = 0; j < 8; ++j) acc[i][j] = fmaf(av[i], bv[j], acc[i][j]);
    }
    if (kq < 31) {
#pragma unroll
      for (int i = 0; i < 5; ++i) xc[i] = xn[i];
    }
  }

  float bb[8];
#pragma unroll
  for (int j = 0; j < 8; ++j) bb[j] = 0.f;
  if (bias) {
#pragma unroll
    for (int j = 0; j < 4; ++j) bb[j] = bias[c0a + j];
#pragma unroll
    for (int j = 0; j < 4; ++j) bb[4 + j] = bias[c0b + j];
  }

  if (DO_ARGMAX) {
#pragma unroll
    for (int i = 0; i < 5; ++i) {
      // local scan in ascending column order: c0a..c0a+3 then c0b..c0b+3
      float bv = acc[i][0] * scale + bb[0];
      int bc = c0a;
#pragma unroll
      for (int j = 1; j < 8; ++j) {
        float v = acc[i][j] * scale + bb[j];
        int col = (j < 4) ? (c0a + j) : (c0b + j - 4);
        if (v > bv) {
          bv = v;
          bc = col;
        }
      }
#pragma unroll
      for (int off = 1; off <= 8; off <<= 1) {
        float ov = __shfl_xor(bv, off, 64);
        int oc = __shfl_xor(bc, off, 64);
        if (ov > bv || (ov == bv && oc < bc)) {
          bv = ov;
          bc = oc;
        }
      }
      int gr = rbase + r0 + i;
      if (tc == 0 && gr < M) cls[gr] = bc;
    }
  } else {
#pragma unroll
    for (int i = 0; i < 5; ++i) {
      int gr = rbase + r0 + i;
      if (gr < M) {
        float4 v0, v1;
        v0.x = acc[i][0] * scale + bb[0];
        v0.y = acc[i][1] * scale + bb[1];
        v0.z = acc[i][2] * scale + bb[2];
        v0.w = acc[i][3] * scale + bb[3];
        v1.x = acc[i][4] * scale + bb[4];
        v1.y = acc[i][5] * scale + bb[5];
        v1.z = acc[i][6] * scale + bb[6];
        v1.w = acc[i][7] * scale + bb[7];
        *(float4*)&out[(long)gr * 128 + c0a] = v0;
        *(float4*)&out[(long)gr * 128 + c0b] = v1;
      }
    }
  }
}

// ---------------------------------------------------------------------------
// row norms (float2 per lane): first NN waves -> ||features[j]||,
// next NN -> ||transformed0[j]||
__global__ __launch_bounds__(256) void k_norms(const float* __restrict__ feat,
                                               const float* __restrict__ A,
                                               float* __restrict__ nf,
                                               float* __restrict__ nt0) {
  int w = blockIdx.x * 4 + (threadIdx.x >> 6);
  int lane = threadIdx.x & 63;
  if (w >= 2 * NN) return;
  const float* p = (w < NN) ? (feat + (long)w * 128) : (A + (long)(NN + (w - NN)) * 128);
  float2 v = *(const float2*)(p + lane * 2);
  float s = waveReduceSum(v.x * v.x + v.y * v.y);
  if (lane == 0) {
    float r = sqrtf(s);
    if (w < NN) nf[w] = r;
    else nt0[w - NN] = r;
  }
}

// ---------------------------------------------------------------------------
// cosine-sim replica selection. 32 lanes per edge (float4/lane), 2 edges per
// wave, 4 grid-strided iterations with 1-ahead prefetch -> 16 row-loads in
// flight per wave (vs 4). Reduce: 5-step shfl within each 32-lane half.
__global__ __launch_bounds__(256) void k_sim(const int* __restrict__ ei,
                                             const float* __restrict__ feat,
                                             const float* __restrict__ A,
                                             const float* __restrict__ nf,
                                             const float* __restrict__ nt0,
                                             int* __restrict__ bn) {
  const int t = threadIdx.x;
  const int lane = t & 31;
  const int half = (t >> 5) & 1;
  const int w = blockIdx.x * 4 + (t >> 6);  // wave id in [0, SIMW)

#define SIM_LOAD(I, E, DE, AV, B0, B1, B2, NA, NB0, NB1, NB2)              \
  {                                                                        \
    E = 2 * (w + (I)*SIMW) + half;                                         \
    DE = ei[NE + E];                                                       \
    int s_ = ei[E];                                                        \
    int j0_ = 3 * E;                                                       \
    if (j0_ >= NE) j0_ -= NE;                                              \
    if (j0_ >= NE) j0_ -= NE;                                              \
    int j1_ = j0_ + 1;                                                     \
    if (j1_ >= NE) j1_ -= NE;                                              \
    int j2_ = j0_ + 2;                                                     \
    if (j2_ >= NE) j2_ -= NE;                                              \
    int d0_ = ei[NE + j0_], d1_ = ei[NE + j1_], d2_ = ei[NE + j2_];        \
    AV = ((const float4*)(feat + (long)s_ * 128))[lane];                   \
    B0 = ((const float4*)(A + (long)(NN + d0_) * 128))[lane];              \
    B1 = ((const float4*)(A + (long)(NN + d1_) * 128))[lane];              \
    B2 = ((const float4*)(A + (long)(NN + d2_) * 128))[lane];              \
    NA = nf[s_];                                                           \
    NB0 = nt0[d0_];                                                        \
    NB1 = nt0[d1_];                                                        \
    NB2 = nt0[d2_];                                                        \
  }

  int ec, dec;
  float4 ac, b0c, b1c, b2c;
  float nac, nb0c, nb1c, nb2c;
  SIM_LOAD(0, ec, dec, ac, b0c, b1c, b2c, nac, nb0c, nb1c, nb2c);

#pragma unroll
  for (int i = 0; i < 4; ++i) {
    int en = 0, den = 0;
    float4 an, b0n, b1n, b2n;
    float nan2 = 0.f, nb0n = 0.f, nb1n = 0.f, nb2n = 0.f;
    if (i < 3) {
      SIM_LOAD(i + 1, en, den, an, b0n, b1n, b2n, nan2, nb0n, nb1n, nb2n);
    }
    float p0 = ac.x * b0c.x + ac.y * b0c.y + ac.z * b0c.z + ac.w * b0c.w;
    float p1 = ac.x * b1c.x + ac.y * b1c.y + ac.z * b1c.z + ac.w * b1c.w;
    float p2 = ac.x * b2c.x + ac.y * b2c.y + ac.z * b2c.z + ac.w * b2c.w;
#pragma unroll
    for (int off = 1; off <= 16; off <<= 1) {
      p0 += __shfl_xor(p0, off, 64);
      p1 += __shfl_xor(p1, off, 64);
      p2 += __shfl_xor(p2, off, 64);
    }
    float s0 = p0 / fmaxf(nac * nb0c, 1e-8f);
    float s1 = p1 / fmaxf(nac * nb1c, 1e-8f);
    float s2 = p2 / fmaxf(nac * nb2c, 1e-8f);
    int bk = 0;
    float bv = s0;
    if (s1 > bv) {
      bv = s1;
      bk = 1;
    }
    if (s2 > bv) {
      bv = s2;
      bk = 2;
    }
    if (lane == 0) bn[ec] = dec + bk * NN;
    if (i < 3) {
      ec = en;
      dec = den;
      ac = an;
      b0c = b0n;
      b1c = b1n;
      b2c = b2n;
      nac = nan2;
      nb0c = nb0n;
      nb1c = nb1n;
      nb2c = nb2n;
    }
  }
#undef SIM_LOAD
}

// ---------------------------------------------------------------------------
// CSR build: count -> scan(3 phases) -> fill. Shared by both GCN layers.
__global__ __launch_bounds__(256) void k_zero_count(int* __restrict__ count) {
  int v = blockIdx.x * 256 + threadIdx.x;
  if (v < NTOT) count[v] = 0;
}

__global__ __launch_bounds__(256) void k_count(const int* __restrict__ ei,
                                               const int* __restrict__ bn,
                                               int* __restrict__ count) {
  int e = blockIdx.x * 256 + threadIdx.x;
  if (e < NE) {
    atomicAdd(&count[ei[NE + e]], 1);
    atomicAdd(&count[bn[e]], 1);
  }
}

// dinv[v] = rsqrt(unstructured_count + structured (2 for v<N3, else 1))
__global__ __launch_bounds__(256) void k_dinv(const int* __restrict__ count,
                                              float* __restrict__ dinv) {
  int v = blockIdx.x * 256 + threadIdx.x;
  if (v < NTOT) {
    float deg = (float)count[v] + ((v < N3) ? 2.f : 1.f);
    dinv[v] = 1.f / sqrtf(deg);
  }
}

// scan phase 1: per-1024-block local exclusive scan + block sums
__global__ __launch_bounds__(256) void k_scan1(const int* __restrict__ count,
                                               int* __restrict__ start,
                                               int* __restrict__ bsum) {
  __shared__ int sh[256];
  const int b = blockIdx.x, t = threadIdx.x;
  const int base = b * 1024 + t * 4;
  int c[4];
  int s = 0;
#pragma unroll
  for (int k = 0; k < 4; ++k) {
    int idx = base + k;
    c[k] = (idx < NTOT) ? count[idx] : 0;
    s += c[k];
  }
  sh[t] = s;
  __syncthreads();
  for (int off = 1; off < 256; off <<= 1) {
    int v = (t >= off) ? sh[t - off] : 0;
    __syncthreads();
    sh[t] += v;
    __syncthreads();
  }
  if (t == 255) bsum[b] = sh[255];
  int run = sh[t] - s;  // exclusive prefix of this thread
#pragma unroll
  for (int k = 0; k < 4; ++k) {
    int idx = base + k;
    if (idx < NTOT) start[idx] = run;
    run += c[k];
  }
}

// scan phase 2: exclusive scan of NBLK1 block sums (single block)
__global__ __launch_bounds__(256) void k_scan2(int* __restrict__ bsum) {
  __shared__ int sh[256];
  const int t = threadIdx.x;
  int v = (t < NBLK1) ? bsum[t] : 0;
  sh[t] = v;
  __syncthreads();
  for (int off = 1; off < 256; off <<= 1) {
    int u = (t >= off) ? sh[t - off] : 0;
    __syncthreads();
    sh[t] += u;
    __syncthreads();
  }
  if (t < NBLK1) bsum[t] = sh[t] - v;
}

// scan phase 3: add block offsets; init cursor = start
__global__ __launch_bounds__(256) void k_scan3(int* __restrict__ start,
                                               const int* __restrict__ bsum,
                                               int* __restrict__ cursor) {
  int i = blockIdx.x * 256 + threadIdx.x;
  if (i < NTOT) {
    int v = start[i] + bsum[i >> 10];
    start[i] = v;
    cursor[i] = v;
  }
}

// fill CSR entries: (src, weight) packed in int2
__global__ __launch_bounds__(256) void k_fill(const int* __restrict__ ei,
                                              const int* __restrict__ bn,
                                              const float* __restrict__ dinv,
                                              int* __restrict__ cursor,
                                              int2* __restrict__ ent) {
  int g = blockIdx.x * 256 + threadIdx.x;
  if (g >= 2 * NE) return;
  int e = (g < NE) ? g : g - NE;
  int s = ei[e];
  int d = (g < NE) ? ei[NE + e] : bn[e];
  float w = dinv[s] * dinv[d];
  int pos = atomicAdd(&cursor[d], 1);
  ent[pos] = make_int2(s, __float_as_int(w));
}

// ---------------------------------------------------------------------------
// Fused GCN aggregate: out[v] = bias + selfloop + extra + sum_{CSR} w*xw[src].
// 32 lanes per row (float4/lane), 2 rows per wave, CSR loop with 1-ahead
// prefetch of entry + gathered row. No atomics; coalesced 512B writes.
__global__ __launch_bounds__(256) void k_agg(const int2* __restrict__ ent,
                                             const int* __restrict__ start,
                                             const int* __restrict__ end,
                                             const float* __restrict__ xw,
                                             const float* __restrict__ dinv,
                                             const float* __restrict__ bias,
                                             float* __restrict__ out) {
  const int t = threadIdx.x;
  const int lane = t & 31;
  const int v = blockIdx.x * 8 + (t >> 5);  // 8 rows per block, 2 per wave
  float dv = dinv[v];
  float4 xv = ((const float4*)(xw + (long)v * 128))[lane];
  float4 bb = ((const float4*)bias)[lane];
  float a0 = bb.x + dv * dv * xv.x;
  float a1 = bb.y + dv * dv * xv.y;
  float a2 = bb.z + dv * dv * xv.z;
  float a3 = bb.w + dv * dv * xv.w;
  if (v < NN) {
    a0 += dv * dv * xv.x;  // extra edge (j, j)
    a1 += dv * dv * xv.y;
    a2 += dv * dv * xv.z;
    a3 += dv * dv * xv.w;
  } else if (v < N3) {
    int j = (v < 2 * NN) ? v - NN : v - 2 * NN;
    float4 xj = ((const float4*)(xw + (long)j * 128))[lane];
    float w = dinv[j] * dv;
    a0 = fmaf(w, xj.x, a0);  // extra edge (j, i*NN + j)
    a1 = fmaf(w, xj.y, a1);
    a2 = fmaf(w, xj.z, a2);
    a3 = fmaf(w, xj.w, a3);
  }
  int i = start[v];
  const int i1 = end[v];
  if (i < i1) {
    int2 e0 = ent[i];
    float4 x0 = ((const float4*)(xw + (long)e0.x * 128))[lane];
    for (; i + 1 < i1; ++i) {
      int2 e1 = ent[i + 1];
      float4 x1 = ((const float4*)(xw + (long)e1.x * 128))[lane];
      float w0 = __int_as_float(e0.y);
      a0 = fmaf(w0, x0.x, a0);
      a1 = fmaf(w0, x0.y, a1);
      a2 = fmaf(w0, x0.z, a2);
      a3 = fmaf(w0, x0.w, a3);
      e0 = e1;
      x0 = x1;
    }
    float w0 = __int_as_float(e0.y);
    a0 = fmaf(w0, x0.x, a0);
    a1 = fmaf(w0, x0.y, a1);
    a2 = fmaf(w0, x0.z, a2);
    a3 = fmaf(w0, x0.w, a3);
  }
  ((float4*)(out + (long)v * 128))[lane] = make_float4(a0, a1, a2, a3);
}

__global__ __launch_bounds__(256) void k_zero_small(float* __restrict__ hyper,
                                                    int* __restrict__ hist) {
  int i = blockIdx.x * 256 + threadIdx.x;
  if (i < 128 * 128) hyper[i] = 0.f;
  if (i < 640) hist[i] = 0;
}

// vote histogram: hist[c][m] = #nodes whose count for class c is exactly m.
// LDS-accumulated per block (20 blocks x 1000 nodes), one flush per block.
#define HISTBLK 20
__global__ __launch_bounds__(256) void k_hist(const int* __restrict__ cls,
                                              int* __restrict__ hist) {
  __shared__ int sh[640];
  const int t = threadIdx.x;
  for (int i = t; i < 640; i += 256) sh[i] = 0;
  __syncthreads();
  const int per = NN / HISTBLK;  // 1000
  const int j0 = blockIdx.x * per;
  for (int j = j0 + t; j < j0 + per; j += 256) {
    int cc[4] = {cls[j], cls[NN + j], cls[2 * NN + j], cls[3 * NN + j]};
#pragma unroll
    for (int i = 0; i < 4; ++i) {
      bool first = true;
      int m = 0;
#pragma unroll
      for (int k = 0; k < 4; ++k) {
        if (cc[k] == cc[i]) {
          if (k < i) first = false;
          m++;
        }
      }
      if (first) atomicAdd(&sh[cc[i] * 5 + m], 1);
    }
  }
  __syncthreads();
  for (int i = t; i < 640; i += 256) {
    int v = sh[i];
    if (v) atomicAdd(&hist[i], v);
  }
}

// per-class softmax table over count values 0..4
__global__ void k_table(const int* __restrict__ hist, float* __restrict__ table) {
  int c = threadIdx.x;
  if (c >= 128) return;
  int cnt[5];
  int tot = 0;
  for (int v = 1; v <= 4; ++v) {
    cnt[v] = hist[c * 5 + v];
    tot += cnt[v];
  }
  cnt[0] = NN - tot;
  int m = 0;
  for (int v = 0; v <= 4; ++v)
    if (cnt[v] > 0) m = v;
  float ex[5];
  float denom = 0.f;
  for (int v = 0; v <= 4; ++v) {
    ex[v] = expf((float)(v - m));
    denom += (float)cnt[v] * ex[v];
  }
  for (int v = 0; v <= 4; ++v) table[c * 5 + v] = ex[v] / denom;
}

__global__ __launch_bounds__(256) void k_hwrite(const int* __restrict__ cls,
                                                const float* __restrict__ table,
                                                float* __restrict__ H) {
  int j = blockIdx.x * 2 + (threadIdx.x >> 7);
  int c = threadIdx.x & 127;
  if (j >= NN) return;
  int c0 = cls[j], c1 = cls[NN + j], c2 = cls[2 * NN + j], c3 = cls[3 * NN + j];
  int cnt = (c == c0) + (c == c1) + (c == c2) + (c == c3);
  H[(long)j * 128 + c] = table[c * 5 + cnt];
}

// ---------------------------------------------------------------------------
// hyper[c][d] = sum over nodes voting for class c of af2[j][d].
// LDS-accumulated: 250 blocks x 80 nodes.
#define HBLK 250
#define HPER 80
__global__ __launch_bounds__(256) void k_hyper(const int* __restrict__ cls,
                                               const float* __restrict__ af2,
                                               float* __restrict__ hyper) {
  __shared__ float acc[128 * 128];
  const int t = threadIdx.x;
  for (int i = t; i < 128 * 128; i += 256) acc[i] = 0.f;
  __syncthreads();
  const int j0 = blockIdx.x * HPER;
  const int j1 = j0 + HPER;  // NN == HBLK*HPER exactly
  const int d = t & 127;
  const int half = t >> 7;  // 0: slots {0,2}; 1: slots {1,3}
  float v = af2[(long)j0 * 128 + d];
  int c0 = cls[j0], c1 = cls[NN + j0], c2 = cls[2 * NN + j0], c3 = cls[3 * NN + j0];
  for (int j = j0; j < j1; ++j) {
    float vn = 0.f;
    int n0 = 0, n1 = 0, n2 = 0, n3 = 0;
    if (j + 1 < j1) {
      vn = af2[(long)(j + 1) * 128 + d];
      n0 = cls[j + 1];
      n1 = cls[NN + j + 1];
      n2 = cls[2 * NN + j + 1];
      n3 = cls[3 * NN + j + 1];
    }
    if (half == 0) {
      atomicAdd(&acc[c0 * 128 + d], v);  // slot 0 always first occurrence
      if (c2 != c0 && c2 != c1) atomicAdd(&acc[c2 * 128 + d], v);
    } else {
      if (c1 != c0) atomicAdd(&acc[c1 * 128 + d], v);
      if (c3 != c0 && c3 != c1 && c3 != c2) atomicAdd(&acc[c3 * 128 + d], v);
    }
    v = vn;
    c0 = n0;
    c1 = n1;
    c2 = n2;
    c3 = n3;
  }
  __syncthreads();
  for (int i = t; i < 128 * 128; i += 256) {
    float x = acc[i];
    if (x != 0.f) atomAddF(&hyper[i], x);
  }
}

// ---------------------------------------------------------------------------
extern "C" void kernel_launch(void* const* d_in, const int* in_sizes, int n_in,
                              void* d_out, int out_size, void* d_ws, size_t ws_size,
                              hipStream_t stream) {
  (void)in_sizes;
  (void)n_in;
  (void)out_size;
  (void)ws_size;
  const int* ei = (const int*)d_in[0];
  const float* feat = (const float*)d_in[1];
  const float* lin_W = (const float*)d_in[2];
  const float* lin_b = (const float*)d_in[3];
  const float* g1W = (const float*)d_in[4];
  const float* g1b = (const float*)d_in[5];
  const float* g2W = (const float*)d_in[6];
  const float* g2b = (const float*)d_in[7];
  const float* l1W = (const float*)d_in[8];
  const float* l1b = (const float*)d_in[9];

  float* out = (float*)d_out;
  float* H = out;
  float* hyper = out + (size_t)NN * 128;
  float* dots = hyper + 128 * 128;

  float* ws = (float*)d_ws;
  float* A = ws;                          // all_features [(T+1)*NN, 128]
  float* Cb = A + (size_t)NTOT * 128;     // h1 / af2 buffer
  float* Bb = dots;                       // xw buffer aliased onto dots
                                          // (dots written only by final GEMM)
  float* dinv = Cb + (size_t)NTOT * 128;  // [NTOT]
  float* nf = dinv + NTOT;                // feature norms [NN]
  float* nt0 = nf + NN;                   // transformed0 norms [NN]
  int* bn = (int*)(nt0 + NN);             // best_nodes [NE]
  int* cls = bn + NE;                     // classes [NTOT]
  int* hist = cls + NTOT;                 // [640]
  float* table = (float*)(hist + 640);    // [640]
  int* count = (int*)(table + 640);       // [NTOT]
  int* startA = count + NTOT;             // [NTOT]
  int* cursor = startA + NTOT;            // [NTOT]  (== end after fill)
  int* bsum = cursor + NTOT;              // [128]
  int2* ent = (int2*)(bsum + 128);        // [2*NE] CSR entries (src, weight)

  const float kScale = 0.08838834764831843f;  // 128^-0.5

  // 1. all_features rows [0,NN) = features
  k_copy_feat<<<(NN * 128 / 4 + 255) / 256, 256, 0, stream>>>(feat, A, NN * 128 / 4);
  // 2. transformed: per-replica linears -> rows [NN, 4*NN)  (20000 = 125*160)
  gemm128<0, 0, 0><<<dim3(125, 3), 512, 0, stream>>>(
      feat, lin_W, lin_b, A + (size_t)NN * 128, NN, 1.f, 128 * 128, 128,
      (long)NN * 128, nullptr);
  // 3. row norms
  k_norms<<<10000, 256, 0, stream>>>(feat, A, nf, nt0);
  // 4. cosine-sim replica pick (pipelined, 2 edges/wave, 4 iters/wave)
  k_zero_count<<<(NTOT + 255) / 256, 256, 0, stream>>>(count);
  k_sim<<<SIMW / 4, 256, 0, stream>>>(ei, feat, A, nf, nt0, bn);
  // 5. CSR build: count, dinv, scan, fill
  k_count<<<(NE + 255) / 256, 256, 0, stream>>>(ei, bn, count);
  k_dinv<<<(NTOT + 255) / 256, 256, 0, stream>>>(count, dinv);
  k_scan1<<<NBLK1, 256, 0, stream>>>(count, startA, bsum);
  k_scan2<<<1, 256, 0, stream>>>(bsum);
  k_scan3<<<(NTOT + 255) / 256, 256, 0, stream>>>(startA, bsum, cursor);
  k_fill<<<(2 * NE + 255) / 256, 256, 0, stream>>>(ei, bn, dinv, cursor, ent);
  // 6. GCN1: xw1 = relu(all_features) @ W1; fused aggregate -> h1 in Cb
  gemm128<1, 0, 0><<<dim3(NTOT / 160, 1), 512, 0, stream>>>(A, g1W, nullptr, Bb, NTOT,
                                                            1.f, 0, 0, 0, nullptr);
  k_agg<<<NTOT / 8, 256, 0, stream>>>(ent, startA, cursor, Bb, dinv, g1b, Cb);
  // 7. GCN2: xw2 = relu(h1) @ W2; fused aggregate -> af2 in Cb
  gemm128<1, 0, 0><<<dim3(NTOT / 160, 1), 512, 0, stream>>>(Cb, g2W, nullptr, Bb, NTOT,
                                                            1.f, 0, 0, 0, nullptr);
  k_agg<<<NTOT / 8, 256, 0, stream>>>(ent, startA, cursor, Bb, dinv, g2b, Cb);
  // 8. logits GEMM with fused per-row argmax -> classes (no logits store)
  gemm128<1, 0, 1><<<dim3(NTOT / 160, 1), 512, 0, stream>>>(Cb, l1W, l1b, nullptr,
                                                            NTOT, 1.f, 0, 0, 0, cls);
  // 9. zero hyper + hist
  k_zero_small<<<64, 256, 0, stream>>>(hyper, hist);
  // 10. vote histogram (LDS) -> per-class softmax table
  k_hist<<<HISTBLK, 256, 0, stream>>>(cls, hist);
  k_table<<<1, 128, 0, stream>>>(hist, table);
  // 11. H output (softmax over nodes, via count table)
  k_hwrite<<<NN / 2, 256, 0, stream>>>(cls, table, H);
  // 12. hyperedge features (LDS-accumulated)
  k_hyper<<<HBLK, 256, 0, stream>>>(cls, Cb, hyper);
  // 13. dots = all_features @ hyper^T * scale
  gemm128<0, 1, 0><<<dim3(NTOT / 160, 1), 512, 0, stream>>>(A, hyper, nullptr, dots,
                                                            NTOT, kScale, 0, 0, 0,
                                                            nullptr);
}

// Round 21
// 414.430 us; speedup vs baseline: 1.5718x; 1.0077x over previous
//
#include <hip/hip_runtime.h>
#include <math.h>

#define NN 20000
#define NE 160000
#define TT 3
#define DD 128
#define NTOT 80000   // (TT+1)*NN
#define N3 60000     // TT*NN
#define NBLK1 79     // ceil(NTOT/1024) for the scan
#define SIMW 20000   // k_sim waves (grid 5000 x 4 waves)

__device__ __forceinline__ float waveReduceSum(float v) {
#pragma unroll
  for (int off = 32; off >= 1; off >>= 1)
    v += __shfl_xor(v, off, 64);
  return v;
}

__device__ __forceinline__ void atomAddF(float* p, float v) {
  unsafeAtomicAdd(p, v);
}

// deg^-1/2 from unstructured count + structured part (self-loop + extra edge)
__device__ __forceinline__ float dinvOf(const int* __restrict__ count, int v) {
  float deg = (float)count[v] + ((v < N3) ? 2.f : 1.f);
  return 1.f / sqrtf(deg);
}

// ---------------------------------------------------------------------------
// [M,128] @ [128,128] GEMM — r15 structure + split-column mapping (r20:
// bank conflicts 4.1M -> 0 verified). 160x128 tile per block, 512 threads,
// 5 rows x 8 cols per thread; cols {tc*4..+3} and {64+tc*4..+3}. W staged in
// LDS once (full K); X broadcast-read from global once per block. Do NOT
// restructure the K-loop (r8/r9/r11/r16: allocator defeats deeper prefetch).
template <int RELU_IN, int TRANS_W, int DO_ARGMAX>
__global__ __launch_bounds__(512, 3) void gemm128(const float* __restrict__ X,
                                                  const float* __restrict__ W,
                                                  const float* __restrict__ bias,
                                                  float* __restrict__ out, int M,
                                                  float scale, int wStride, int bStride,
                                                  long oStride, int* __restrict__ cls) {
  __shared__ float Ws[128 * 132];
  const int tid = threadIdx.x;
  const int rbase = blockIdx.x * 160;
  W += (long)blockIdx.y * wStride;
  if (bias) bias += (long)blockIdx.y * bStride;
  out += (long)blockIdx.y * oStride;

  // stage all of W into LDS (row kl, padded stride 132)
#pragma unroll
  for (int it = 0; it < 8; ++it) {
    int idx = (tid + it * 512) * 4;
    int kl = idx >> 7, c = idx & 127;
    float4 w;
    if (!TRANS_W) {
      w = *(const float4*)&W[kl * 128 + c];
    } else {
      w.x = W[(c + 0) * 128 + kl];
      w.y = W[(c + 1) * 128 + kl];
      w.z = W[(c + 2) * 128 + kl];
      w.w = W[(c + 3) * 128 + kl];
    }
    *(float4*)&Ws[kl * 132 + c] = w;
  }

  const int tc = tid & 15, tr = tid >> 4;  // tr in [0,32)
  const int c0a = tc * 4, c0b = 64 + tc * 4;  // two 4-col groups per thread
  const int r0 = tr * 5;

  const float4* xrow[5];
#pragma unroll
  for (int i = 0; i < 5; ++i) {
    int gr = rbase + r0 + i;
    int gc = (gr < M) ? gr : 0;  // clamp tail rows (stores are guarded)
    xrow[i] = (const float4*)(X + (long)gc * 128);
  }

  float acc[5][8];
#pragma unroll
  for (int i = 0; i < 5; ++i)
#pragma unroll
    for (int j = 0; j < 8; ++j) acc[i][j] = 0.f;

  float4 xc[5], xn[5];
#pragma unroll
  for (int i = 0; i < 5; ++i) {
    float4 v = xrow[i][0];
    if (RELU_IN) {
      v.x = fmaxf(v.x, 0.f);
      v.y = fmaxf(v.y, 0.f);
      v.z = fmaxf(v.z, 0.f);
      v.w = fmaxf(v.w, 0.f);
    }
    xc[i] = v;
  }

  __syncthreads();  // W staged

  for (int kq = 0; kq < 32; ++kq) {
    if (kq < 31) {
#pragma unroll
      for (int i = 0; i < 5; ++i) {
        float4 v = xrow[i][kq + 1];
        if (RELU_IN) {
          v.x = fmaxf(v.x, 0.f);
          v.y = fmaxf(v.y, 0.f);
          v.z = fmaxf(v.z, 0.f);
          v.w = fmaxf(v.w, 0.f);
        }
        xn[i] = v;
      }
    }
    const int klb = kq * 4;
#pragma unroll
    for (int k = 0; k < 4; ++k) {
      const int kl = klb + k;
      const float4 wa = *(const float4*)&Ws[kl * 132 + c0a];
      const float4 wb = *(const float4*)&Ws[kl * 132 + c0b];
      float av[5];
#pragma unroll
      for (int i = 0; i < 5; ++i)
        av[i] = (k == 0) ? xc[i].x : (k == 1) ? xc[i].y : (k == 2) ? xc[i].z : xc[i].w;
      const float bv[8] = {wa.x, wa.y, wa.z, wa.w, wb.x, wb.y, wb.z, wb.w};
#pragma unroll
      for (int i = 0; i < 5; ++i)
#pragma unroll
        for (int j = 0; j < 8; ++j) acc[i][j] = fmaf(av[i], bv[j], acc[i][j]);
    }
    if (kq < 31) {
#pragma unroll
      for (int i = 0; i < 5; ++i) xc[i] = xn[i];
    }
  }

  float bb[8];
#pragma unroll
  for (int j = 0; j < 8; ++j) bb[j] = 0.f;
  if (bias) {
#pragma unroll
    for (int j = 0; j < 4; ++j) bb[j] = bias[c0a + j];
#pragma unroll
    for (int j = 0; j < 4; ++j) bb[4 + j] = bias[c0b + j];
  }

  if (DO_ARGMAX) {
#pragma unroll
    for (int i = 0; i < 5; ++i) {
      // local scan in ascending column order: c0a..c0a+3 then c0b..c0b+3
      float bv = acc[i][0] * scale + bb[0];
      int bc = c0a;
#pragma unroll
      for (int j = 1; j < 8; ++j) {
        float v = acc[i][j] * scale + bb[j];
        int col = (j < 4) ? (c0a + j) : (c0b + j - 4);
        if (v > bv) {
          bv = v;
          bc = col;
        }
      }
#pragma unroll
      for (int off = 1; off <= 8; off <<= 1) {
        float ov = __shfl_xor(bv, off, 64);
        int oc = __shfl_xor(bc, off, 64);
        if (ov > bv || (ov == bv && oc < bc)) {
          bv = ov;
          bc = oc;
        }
      }
      int gr = rbase + r0 + i;
      if (tc == 0 && gr < M) cls[gr] = bc;
    }
  } else {
#pragma unroll
    for (int i = 0; i < 5; ++i) {
      int gr = rbase + r0 + i;
      if (gr < M) {
        float4 v0, v1;
        v0.x = acc[i][0] * scale + bb[0];
        v0.y = acc[i][1] * scale + bb[1];
        v0.z = acc[i][2] * scale + bb[2];
        v0.w = acc[i][3] * scale + bb[3];
        v1.x = acc[i][4] * scale + bb[4];
        v1.y = acc[i][5] * scale + bb[5];
        v1.z = acc[i][6] * scale + bb[6];
        v1.w = acc[i][7] * scale + bb[7];
        *(float4*)&out[(long)gr * 128 + c0a] = v0;
        *(float4*)&out[(long)gr * 128 + c0b] = v1;
      }
    }
  }
}

// ---------------------------------------------------------------------------
// fused copy + row norms (float2 per lane): first NN waves copy features into
// A[0..NN) AND compute ||features[j]||; next NN waves -> ||transformed0[j]||.
__global__ __launch_bounds__(256) void k_norms(const float* __restrict__ feat,
                                               float* __restrict__ A,
                                               float* __restrict__ nf,
                                               float* __restrict__ nt0) {
  int w = blockIdx.x * 4 + (threadIdx.x >> 6);
  int lane = threadIdx.x & 63;
  if (w >= 2 * NN) return;
  float2 v;
  if (w < NN) {
    v = *(const float2*)(feat + (long)w * 128 + lane * 2);
    *(float2*)(A + (long)w * 128 + lane * 2) = v;  // all_features row copy
  } else {
    v = *(const float2*)(A + (long)(NN + (w - NN)) * 128 + lane * 2);
  }
  float s = waveReduceSum(v.x * v.x + v.y * v.y);
  if (lane == 0) {
    float r = sqrtf(s);
    if (w < NN) nf[w] = r;
    else nt0[w - NN] = r;
  }
}

// ---------------------------------------------------------------------------
// cosine-sim replica selection. 32 lanes per edge (float4/lane), 2 edges per
// wave, 4 grid-strided iterations with 1-ahead prefetch -> 16 row-loads in
// flight per wave. Reduce: 5-step shfl within each 32-lane half.
__global__ __launch_bounds__(256) void k_sim(const int* __restrict__ ei,
                                             const float* __restrict__ feat,
                                             const float* __restrict__ A,
                                             const float* __restrict__ nf,
                                             const float* __restrict__ nt0,
                                             int* __restrict__ bn) {
  const int t = threadIdx.x;
  const int lane = t & 31;
  const int half = (t >> 5) & 1;
  const int w = blockIdx.x * 4 + (t >> 6);  // wave id in [0, SIMW)

#define SIM_LOAD(I, E, DE, AV, B0, B1, B2, NA, NB0, NB1, NB2)              \
  {                                                                        \
    E = 2 * (w + (I)*SIMW) + half;                                         \
    DE = ei[NE + E];                                                       \
    int s_ = ei[E];                                                        \
    int j0_ = 3 * E;                                                       \
    if (j0_ >= NE) j0_ -= NE;                                              \
    if (j0_ >= NE) j0_ -= NE;                                              \
    int j1_ = j0_ + 1;                                                     \
    if (j1_ >= NE) j1_ -= NE;                                              \
    int j2_ = j0_ + 2;                                                     \
    if (j2_ >= NE) j2_ -= NE;                                              \
    int d0_ = ei[NE + j0_], d1_ = ei[NE + j1_], d2_ = ei[NE + j2_];        \
    AV = ((const float4*)(feat + (long)s_ * 128))[lane];                   \
    B0 = ((const float4*)(A + (long)(NN + d0_) * 128))[lane];              \
    B1 = ((const float4*)(A + (long)(NN + d1_) * 128))[lane];              \
    B2 = ((const float4*)(A + (long)(NN + d2_) * 128))[lane];              \
    NA = nf[s_];                                                           \
    NB0 = nt0[d0_];                                                        \
    NB1 = nt0[d1_];                                                        \
    NB2 = nt0[d2_];                                                        \
  }

  int ec, dec;
  float4 ac, b0c, b1c, b2c;
  float nac, nb0c, nb1c, nb2c;
  SIM_LOAD(0, ec, dec, ac, b0c, b1c, b2c, nac, nb0c, nb1c, nb2c);

#pragma unroll
  for (int i = 0; i < 4; ++i) {
    int en = 0, den = 0;
    float4 an, b0n, b1n, b2n;
    float nan2 = 0.f, nb0n = 0.f, nb1n = 0.f, nb2n = 0.f;
    if (i < 3) {
      SIM_LOAD(i + 1, en, den, an, b0n, b1n, b2n, nan2, nb0n, nb1n, nb2n);
    }
    float p0 = ac.x * b0c.x + ac.y * b0c.y + ac.z * b0c.z + ac.w * b0c.w;
    float p1 = ac.x * b1c.x + ac.y * b1c.y + ac.z * b1c.z + ac.w * b1c.w;
    float p2 = ac.x * b2c.x + ac.y * b2c.y + ac.z * b2c.z + ac.w * b2c.w;
#pragma unroll
    for (int off = 1; off <= 16; off <<= 1) {
      p0 += __shfl_xor(p0, off, 64);
      p1 += __shfl_xor(p1, off, 64);
      p2 += __shfl_xor(p2, off, 64);
    }
    float s0 = p0 / fmaxf(nac * nb0c, 1e-8f);
    float s1 = p1 / fmaxf(nac * nb1c, 1e-8f);
    float s2 = p2 / fmaxf(nac * nb2c, 1e-8f);
    int bk = 0;
    float bv = s0;
    if (s1 > bv) {
      bv = s1;
      bk = 1;
    }
    if (s2 > bv) {
      bv = s2;
      bk = 2;
    }
    if (lane == 0) bn[ec] = dec + bk * NN;
    if (i < 3) {
      ec = en;
      dec = den;
      ac = an;
      b0c = b0n;
      b1c = b1n;
      b2c = b2n;
      nac = nan2;
      nb0c = nb0n;
      nb1c = nb1n;
      nb2c = nb2n;
    }
  }
#undef SIM_LOAD
}

// ---------------------------------------------------------------------------
// CSR build: count -> scan(2 dispatches) -> fill. Shared by both GCN layers.
__global__ __launch_bounds__(256) void k_zero_count(int* __restrict__ count) {
  int v = blockIdx.x * 256 + threadIdx.x;
  if (v < NTOT) count[v] = 0;
}

__global__ __launch_bounds__(256) void k_count(const int* __restrict__ ei,
                                               const int* __restrict__ bn,
                                               int* __restrict__ count) {
  int e = blockIdx.x * 256 + threadIdx.x;
  if (e < NE) {
    atomicAdd(&count[ei[NE + e]], 1);
    atomicAdd(&count[bn[e]], 1);
  }
}

// scan phase 1: per-1024-block local exclusive scan + block sums
__global__ __launch_bounds__(256) void k_scan1(const int* __restrict__ count,
                                               int* __restrict__ start,
                                               int* __restrict__ bsum) {
  __shared__ int sh[256];
  const int b = blockIdx.x, t = threadIdx.x;
  const int base = b * 1024 + t * 4;
  int c[4];
  int s = 0;
#pragma unroll
  for (int k = 0; k < 4; ++k) {
    int idx = base + k;
    c[k] = (idx < NTOT) ? count[idx] : 0;
    s += c[k];
  }
  sh[t] = s;
  __syncthreads();
  for (int off = 1; off < 256; off <<= 1) {
    int v = (t >= off) ? sh[t - off] : 0;
    __syncthreads();
    sh[t] += v;
    __syncthreads();
  }
  if (t == 255) bsum[b] = sh[255];
  int run = sh[t] - s;  // exclusive prefix of this thread
#pragma unroll
  for (int k = 0; k < 4; ++k) {
    int idx = base + k;
    if (idx < NTOT) start[idx] = run;
    run += c[k];
  }
}

// scan phase 2+3 fused: each block scans the NBLK1 block sums in LDS (cheap,
// redundant per block) and adds its group's exclusive offset; init cursor.
__global__ __launch_bounds__(256) void k_scan3(int* __restrict__ start,
                                               const int* __restrict__ bsum,
                                               int* __restrict__ cursor) {
  __shared__ int sh[128];
  const int t = threadIdx.x;
  int mine = 0;
  if (t < 128) {
    mine = (t < NBLK1) ? bsum[t] : 0;
    sh[t] = mine;
  }
  __syncthreads();
  for (int off = 1; off < 128; off <<= 1) {
    int u = (t < 128 && t >= off) ? sh[t - off] : 0;
    __syncthreads();
    if (t < 128) sh[t] += u;
    __syncthreads();
  }
  int i = blockIdx.x * 256 + t;
  if (i < NTOT) {
    int g = i >> 10;  // each 256-index block lies within one 1024-group
    int excl = sh[g] - bsum[g];
    int v = start[i] + excl;
    start[i] = v;
    cursor[i] = v;
  }
}

// fill CSR entries: (src, weight) packed in int2; dinv computed inline
__global__ __launch_bounds__(256) void k_fill(const int* __restrict__ ei,
                                              const int* __restrict__ bn,
                                              const int* __restrict__ count,
                                              int* __restrict__ cursor,
                                              int2* __restrict__ ent) {
  int g = blockIdx.x * 256 + threadIdx.x;
  if (g >= 2 * NE) return;
  int e = (g < NE) ? g : g - NE;
  int s = ei[e];
  int d = (g < NE) ? ei[NE + e] : bn[e];
  float w = dinvOf(count, s) * dinvOf(count, d);
  int pos = atomicAdd(&cursor[d], 1);
  ent[pos] = make_int2(s, __float_as_int(w));
}

// ---------------------------------------------------------------------------
// Fused GCN aggregate: out[v] = bias + selfloop + extra + sum_{CSR} w*xw[src].
// 32 lanes per row (float4/lane), 2 rows per wave, CSR loop with 1-ahead
// prefetch of entry + gathered row. dinv computed inline from count.
__global__ __launch_bounds__(256) void k_agg(const int2* __restrict__ ent,
                                             const int* __restrict__ start,
                                             const int* __restrict__ end,
                                             const float* __restrict__ xw,
                                             const int* __restrict__ count,
                                             const float* __restrict__ bias,
                                             float* __restrict__ out) {
  const int t = threadIdx.x;
  const int lane = t & 31;
  const int v = blockIdx.x * 8 + (t >> 5);  // 8 rows per block, 2 per wave
  float dv = dinvOf(count, v);
  float4 xv = ((const float4*)(xw + (long)v * 128))[lane];
  float4 bb = ((const float4*)bias)[lane];
  float a0 = bb.x + dv * dv * xv.x;
  float a1 = bb.y + dv * dv * xv.y;
  float a2 = bb.z + dv * dv * xv.z;
  float a3 = bb.w + dv * dv * xv.w;
  if (v < NN) {
    a0 += dv * dv * xv.x;  // extra edge (j, j)
    a1 += dv * dv * xv.y;
    a2 += dv * dv * xv.z;
    a3 += dv * dv * xv.w;
  } else if (v < N3) {
    int j = (v < 2 * NN) ? v - NN : v - 2 * NN;
    float4 xj = ((const float4*)(xw + (long)j * 128))[lane];
    float w = dinvOf(count, j) * dv;
    a0 = fmaf(w, xj.x, a0);  // extra edge (j, i*NN + j)
    a1 = fmaf(w, xj.y, a1);
    a2 = fmaf(w, xj.z, a2);
    a3 = fmaf(w, xj.w, a3);
  }
  int i = start[v];
  const int i1 = end[v];
  if (i < i1) {
    int2 e0 = ent[i];
    float4 x0 = ((const float4*)(xw + (long)e0.x * 128))[lane];
    for (; i + 1 < i1; ++i) {
      int2 e1 = ent[i + 1];
      float4 x1 = ((const float4*)(xw + (long)e1.x * 128))[lane];
      float w0 = __int_as_float(e0.y);
      a0 = fmaf(w0, x0.x, a0);
      a1 = fmaf(w0, x0.y, a1);
      a2 = fmaf(w0, x0.z, a2);
      a3 = fmaf(w0, x0.w, a3);
      e0 = e1;
      x0 = x1;
    }
    float w0 = __int_as_float(e0.y);
    a0 = fmaf(w0, x0.x, a0);
    a1 = fmaf(w0, x0.y, a1);
    a2 = fmaf(w0, x0.z, a2);
    a3 = fmaf(w0, x0.w, a3);
  }
  ((float4*)(out + (long)v * 128))[lane] = make_float4(a0, a1, a2, a3);
}

__global__ __launch_bounds__(256) void k_zero_small(float* __restrict__ hyper,
                                                    int* __restrict__ hist) {
  int i = blockIdx.x * 256 + threadIdx.x;
  if (i < 128 * 128) hyper[i] = 0.f;
  if (i < 640) hist[i] = 0;
}

// vote histogram: hist[c][m] = #nodes whose count for class c is exactly m.
// LDS-accumulated per block (20 blocks x 1000 nodes), one flush per block.
#define HISTBLK 20
__global__ __launch_bounds__(256) void k_hist(const int* __restrict__ cls,
                                              int* __restrict__ hist) {
  __shared__ int sh[640];
  const int t = threadIdx.x;
  for (int i = t; i < 640; i += 256) sh[i] = 0;
  __syncthreads();
  const int per = NN / HISTBLK;  // 1000
  const int j0 = blockIdx.x * per;
  for (int j = j0 + t; j < j0 + per; j += 256) {
    int cc[4] = {cls[j], cls[NN + j], cls[2 * NN + j], cls[3 * NN + j]};
#pragma unroll
    for (int i = 0; i < 4; ++i) {
      bool first = true;
      int m = 0;
#pragma unroll
      for (int k = 0; k < 4; ++k) {
        if (cc[k] == cc[i]) {
          if (k < i) first = false;
          m++;
        }
      }
      if (first) atomicAdd(&sh[cc[i] * 5 + m], 1);
    }
  }
  __syncthreads();
  for (int i = t; i < 640; i += 256) {
    int v = sh[i];
    if (v) atomicAdd(&hist[i], v);
  }
}

// per-class softmax table over count values 0..4
__global__ void k_table(const int* __restrict__ hist, float* __restrict__ table) {
  int c = threadIdx.x;
  if (c >= 128) return;
  int cnt[5];
  int tot = 0;
  for (int v = 1; v <= 4; ++v) {
    cnt[v] = hist[c * 5 + v];
    tot += cnt[v];
  }
  cnt[0] = NN - tot;
  int m = 0;
  for (int v = 0; v <= 4; ++v)
    if (cnt[v] > 0) m = v;
  float ex[5];
  float denom = 0.f;
  for (int v = 0; v <= 4; ++v) {
    ex[v] = expf((float)(v - m));
    denom += (float)cnt[v] * ex[v];
  }
  for (int v = 0; v <= 4; ++v) table[c * 5 + v] = ex[v] / denom;
}

__global__ __launch_bounds__(256) void k_hwrite(const int* __restrict__ cls,
                                                const float* __restrict__ table,
                                                float* __restrict__ H) {
  int j = blockIdx.x * 2 + (threadIdx.x >> 7);
  int c = threadIdx.x & 127;
  if (j >= NN) return;
  int c0 = cls[j], c1 = cls[NN + j], c2 = cls[2 * NN + j], c3 = cls[3 * NN + j];
  int cnt = (c == c0) + (c == c1) + (c == c2) + (c == c3);
  H[(long)j * 128 + c] = table[c * 5 + cnt];
}

// ---------------------------------------------------------------------------
// hyper[c][d] = sum over nodes voting for class c of af2[j][d].
// LDS-accumulated: 250 blocks x 80 nodes.
#define HBLK 250
#define HPER 80
__global__ __launch_bounds__(256) void k_hyper(const int* __restrict__ cls,
                                               const float* __restrict__ af2,
                                               float* __restrict__ hyper) {
  __shared__ float acc[128 * 128];
  const int t = threadIdx.x;
  for (int i = t; i < 128 * 128; i += 256) acc[i] = 0.f;
  __syncthreads();
  const int j0 = blockIdx.x * HPER;
  const int j1 = j0 + HPER;  // NN == HBLK*HPER exactly
  const int d = t & 127;
  const int half = t >> 7;  // 0: slots {0,2}; 1: slots {1,3}
  float v = af2[(long)j0 * 128 + d];
  int c0 = cls[j0], c1 = cls[NN + j0], c2 = cls[2 * NN + j0], c3 = cls[3 * NN + j0];
  for (int j = j0; j < j1; ++j) {
    float vn = 0.f;
    int n0 = 0, n1 = 0, n2 = 0, n3 = 0;
    if (j + 1 < j1) {
      vn = af2[(long)(j + 1) * 128 + d];
      n0 = cls[j + 1];
      n1 = cls[NN + j + 1];
      n2 = cls[2 * NN + j + 1];
      n3 = cls[3 * NN + j + 1];
    }
    if (half == 0) {
      atomicAdd(&acc[c0 * 128 + d], v);  // slot 0 always first occurrence
      if (c2 != c0 && c2 != c1) atomicAdd(&acc[c2 * 128 + d], v);
    } else {
      if (c1 != c0) atomicAdd(&acc[c1 * 128 + d], v);
      if (c3 != c0 && c3 != c1 && c3 != c2) atomicAdd(&acc[c3 * 128 + d], v);
    }
    v = vn;
    c0 = n0;
    c1 = n1;
    c2 = n2;
    c3 = n3;
  }
  __syncthreads();
  for (int i = t; i < 128 * 128; i += 256) {
    float x = acc[i];
    if (x != 0.f) atomAddF(&hyper[i], x);
  }
}

// ---------------------------------------------------------------------------
extern "C" void kernel_launch(void* const* d_in, const int* in_sizes, int n_in,
                              void* d_out, int out_size, void* d_ws, size_t ws_size,
                              hipStream_t stream) {
  (void)in_sizes;
  (void)n_in;
  (void)out_size;
  (void)ws_size;
  const int* ei = (const int*)d_in[0];
  const float* feat = (const float*)d_in[1];
  const float* lin_W = (const float*)d_in[2];
  const float* lin_b = (const float*)d_in[3];
  const float* g1W = (const float*)d_in[4];
  const float* g1b = (const float*)d_in[5];
  const float* g2W = (const float*)d_in[6];
  const float* g2b = (const float*)d_in[7];
  const float* l1W = (const float*)d_in[8];
  const float* l1b = (const float*)d_in[9];

  float* out = (float*)d_out;
  float* H = out;
  float* hyper = out + (size_t)NN * 128;
  float* dots = hyper + 128 * 128;

  float* ws = (float*)d_ws;
  float* A = ws;                          // all_features [(T+1)*NN, 128]
  float* Cb = A + (size_t)NTOT * 128;     // h1 / af2 buffer
  float* Bb = dots;                       // xw buffer aliased onto dots
                                          // (dots written only by final GEMM)
  float* nf = Cb + (size_t)NTOT * 128;    // feature norms [NN]
  float* nt0 = nf + NN;                   // transformed0 norms [NN]
  int* bn = (int*)(nt0 + NN);             // best_nodes [NE]
  int* cls = bn + NE;                     // classes [NTOT]
  int* hist = cls + NTOT;                 // [640]
  float* table = (float*)(hist + 640);    // [640]
  int* count = (int*)(table + 640);       // [NTOT]
  int* startA = count + NTOT;             // [NTOT]
  int* cursor = startA + NTOT;            // [NTOT]  (== end after fill)
  int* bsum = cursor + NTOT;              // [128]
  int2* ent = (int2*)(bsum + 128);        // [2*NE] CSR entries (src, weight)

  const float kScale = 0.08838834764831843f;  // 128^-0.5

  // 1. transformed: per-replica linears -> rows [NN, 4*NN)  (20000 = 125*160)
  gemm128<0, 0, 0><<<dim3(125, 3), 512, 0, stream>>>(
      feat, lin_W, lin_b, A + (size_t)NN * 128, NN, 1.f, 128 * 128, 128,
      (long)NN * 128, nullptr);
  // 2. fused: copy features into A[0..NN) + row norms
  k_norms<<<10000, 256, 0, stream>>>(feat, A, nf, nt0);
  // 3. cosine-sim replica pick (pipelined, 2 edges/wave, 4 iters/wave)
  k_zero_count<<<(NTOT + 255) / 256, 256, 0, stream>>>(count);
  k_sim<<<SIMW / 4, 256, 0, stream>>>(ei, feat, A, nf, nt0, bn);
  // 4. CSR build: count, scan (2 dispatches), fill
  k_count<<<(NE + 255) / 256, 256, 0, stream>>>(ei, bn, count);
  k_scan1<<<NBLK1, 256, 0, stream>>>(count, startA, bsum);
  k_scan3<<<(NTOT + 255) / 256, 256, 0, stream>>>(startA, bsum, cursor);
  k_fill<<<(2 * NE + 255) / 256, 256, 0, stream>>>(ei, bn, count, cursor, ent);
  // 5. GCN1: xw1 = relu(all_features) @ W1; fused aggregate -> h1 in Cb
  gemm128<1, 0, 0><<<dim3(NTOT / 160, 1), 512, 0, stream>>>(A, g1W, nullptr, Bb, NTOT,
                                                            1.f, 0, 0, 0, nullptr);
  k_agg<<<NTOT / 8, 256, 0, stream>>>(ent, startA, cursor, Bb, count, g1b, Cb);
  // 6. GCN2: xw2 = relu(h1) @ W2; fused aggregate -> af2 in Cb
  gemm128<1, 0, 0><<<dim3(NTOT / 160, 1), 512, 0, stream>>>(Cb, g2W, nullptr, Bb, NTOT,
                                                            1.f, 0, 0, 0, nullptr);
  k_agg<<<NTOT / 8, 256, 0, stream>>>(ent, startA, cursor, Bb, count, g2b, Cb);
  // 7. logits GEMM with fused per-row argmax -> classes (no logits store)
  gemm128<1, 0, 1><<<dim3(NTOT / 160, 1), 512, 0, stream>>>(Cb, l1W, l1b, nullptr,
                                                            NTOT, 1.f, 0, 0, 0, cls);
  // 8. zero hyper + hist
  k_zero_small<<<64, 256, 0, stream>>>(hyper, hist);
  // 9. vote histogram (LDS) -> per-class softmax table
  k_hist<<<HISTBLK, 256, 0, stream>>>(cls, hist);
  k_table<<<1, 128, 0, stream>>>(hist, table);
  // 10. H output (softmax over nodes, via count table)
  k_hwrite<<<NN / 2, 256, 0, stream>>>(cls, table, H);
  // 11. hyperedge features (LDS-accumulated)
  k_hyper<<<HBLK, 256, 0, stream>>>(cls, Cb, hyper);
  // 12. dots = all_features @ hyper^T * scale
  gemm128<0, 1, 0><<<dim3(NTOT / 160, 1), 512, 0, stream>>>(A, hyper, nullptr, dots,
                                                            NTOT, kScale, 0, 0, 0,
                                                            nullptr);
}